// Round 2
// baseline (87681.293 us; speedup 1.0000x reference)
//
#include <hip/hip_runtime.h>
#include <math.h>

#define B_ 8
#define S_ 900
#define V_ 11
#define H_ 512
#define NH_ 8
#define HD_ 64
#define INNER_ 1536
#define STEPS_ 2
#define NTOK (B_*S_)
#define EPS_ 1e-5f
#define THETA_ 10000.0f
#define ESCALE_ 22.627416997969522f
#define SCALE_ 0.125f

__device__ inline float wave_sum64(float x) {
#pragma unroll
  for (int off = 32; off > 0; off >>= 1) x += __shfl_xor(x, off, 64);
  return x;
}

// ---------------- small kernels ----------------

__global__ void k_zero(float* p, int n) {
  int i = blockIdx.x * blockDim.x + threadIdx.x;
  if (i < n) p[i] = 0.f;
}

__global__ void k_rope_tables(float* cs, float* sn) {
  int idx = blockIdx.x * blockDim.x + threadIdx.x;
  if (idx >= S_ * 32) return;
  int s = idx >> 5, i = idx & 31;
  float freq = powf(THETA_, -(float)i / 32.0f);
  float ang = (float)s * freq;
  cs[idx] = cosf(ang);
  sn[idx] = sinf(ang);
}

__global__ void k_softmax_logits(const float* __restrict__ logits, float* __restrict__ P) {
  int t = blockIdx.x * blockDim.x + threadIdx.x;
  if (t >= NTOK) return;
  float x[V_];
  float m = -1e30f;
#pragma unroll
  for (int v = 0; v < V_; ++v) { x[v] = logits[t * V_ + v]; m = fmaxf(m, x[v]); }
  float ssum = 0.f;
#pragma unroll
  for (int v = 0; v < V_; ++v) { x[v] = expf(x[v] - m); ssum += x[v]; }
  float inv = 1.f / ssum;
#pragma unroll
  for (int v = 0; v < V_; ++v) P[t * V_ + v] = x[v] * inv;
}

__global__ void k_h0(const float* __restrict__ P, const float* __restrict__ E,
                     const int* __restrict__ inp, float* __restrict__ h0) {
  int t = blockIdx.x;
  int tid = threadIdx.x;
  __shared__ float p[V_];
  __shared__ int iw;
  if (tid < V_) p[tid] = P[t * V_ + tid];
  if (tid == 0) iw = inp[t];
  __syncthreads();
  for (int h = tid; h < H_; h += blockDim.x) {
    float acc = E[iw * H_ + h];
#pragma unroll
    for (int v = 0; v < V_; ++v) acc += p[v] * E[v * H_ + h];
    h0[(size_t)t * H_ + h] = ESCALE_ * acc;
  }
}

__global__ void k_gfill(const float* __restrict__ ew, float* __restrict__ G) {
  int idx = blockIdx.x * blockDim.x + threadIdx.x;
  if (idx < NTOK * H_) G[idx] = ew[idx & (H_ - 1)];
}

// ---------------- GEMM: C[M,N] = A @ B (+D), B optionally transposed (N x K storage),
// A optionally silu-gated pair (gate at k, up at k+INNER_, lda = 2*INNER_) ----------------

template <int TB, int SILU_A, int ADD>
__global__ __launch_bounds__(256) void k_gemm(const float* __restrict__ A,
                                              const float* __restrict__ Bm,
                                              const float* __restrict__ Dm,
                                              float* __restrict__ Cm,
                                              int M, int N, int K, int lda) {
  __shared__ float As[16][68];
  __shared__ float Bs[16][68];
  int tid = threadIdx.x;
  int m0 = blockIdx.y * 64, n0 = blockIdx.x * 64;
  int ty = tid >> 4, tx = tid & 15;
  float acc[4][4] = {};
  for (int k0 = 0; k0 < K; k0 += 16) {
#pragma unroll
    for (int i = tid; i < 64 * 16; i += 256) {
      int r = i >> 4, cc = i & 15;
      int gr = m0 + r;
      float v = 0.f;
      if (gr < M) {
        if (SILU_A) {
          float g = A[(size_t)gr * lda + k0 + cc];
          float u = A[(size_t)gr * lda + INNER_ + k0 + cc];
          v = (g / (1.f + expf(-g))) * u;
        } else {
          v = A[(size_t)gr * lda + k0 + cc];
        }
      }
      As[cc][r] = v;
    }
    if (TB) {
#pragma unroll
      for (int i = tid; i < 16 * 64; i += 256) {
        int r = i & 15, cc = i >> 4;
        Bs[r][cc] = Bm[(size_t)(n0 + cc) * K + k0 + r];
      }
    } else {
#pragma unroll
      for (int i = tid; i < 16 * 64; i += 256) {
        int r = i >> 6, cc = i & 63;
        Bs[r][cc] = Bm[(size_t)(k0 + r) * N + n0 + cc];
      }
    }
    __syncthreads();
#pragma unroll
    for (int kk = 0; kk < 16; ++kk) {
      float a[4], bv[4];
#pragma unroll
      for (int i = 0; i < 4; ++i) a[i] = As[kk][ty * 4 + i];
#pragma unroll
      for (int j = 0; j < 4; ++j) bv[j] = Bs[kk][tx * 4 + j];
#pragma unroll
      for (int i = 0; i < 4; ++i)
#pragma unroll
        for (int j = 0; j < 4; ++j) acc[i][j] += a[i] * bv[j];
    }
    __syncthreads();
  }
#pragma unroll
  for (int i = 0; i < 4; ++i) {
    int gr = m0 + ty * 4 + i;
    if (gr >= M) continue;
#pragma unroll
    for (int j = 0; j < 4; ++j) {
      int gc = n0 + tx * 4 + j;
      float out = acc[i][j];
      if (ADD) out += Dm[(size_t)gr * N + gc];
      Cm[(size_t)gr * N + gc] = out;
    }
  }
}

static void gemm(hipStream_t st, int tb, int silu, int add,
                 const float* A, const float* Bm, const float* Dm, float* Cm,
                 int M, int N, int K, int lda) {
  dim3 grid(N / 64, (M + 63) / 64);
  if (!tb && !silu && !add) k_gemm<0, 0, 0><<<grid, 256, 0, st>>>(A, Bm, Dm, Cm, M, N, K, lda);
  else if (!tb && !silu && add) k_gemm<0, 0, 1><<<grid, 256, 0, st>>>(A, Bm, Dm, Cm, M, N, K, lda);
  else if (!tb && silu && add) k_gemm<0, 1, 1><<<grid, 256, 0, st>>>(A, Bm, Dm, Cm, M, N, K, lda);
  else if (tb && !silu && !add) k_gemm<1, 0, 0><<<grid, 256, 0, st>>>(A, Bm, Dm, Cm, M, N, K, lda);
  else k_gemm<1, 0, 1><<<grid, 256, 0, st>>>(A, Bm, Dm, Cm, M, N, K, lda);
}

// ---------------- RoPE fwd/bwd (in place on qkv buffer, q and k channels) ----------------

template <int BWD>
__global__ void k_rope(float* __restrict__ Q, const float* __restrict__ cs,
                       const float* __restrict__ sn) {
  int idx = blockIdx.x * blockDim.x + threadIdx.x;
  if (idx >= NTOK * NH_ * 2 * 32) return;
  int i = idx & 31;
  int h = (idx >> 5) & (NH_ - 1);
  int part = (idx >> 8) & 1;
  int t = idx >> 9;
  int s = t % S_;
  float c = cs[s * 32 + i], sv = sn[s * 32 + i];
  size_t base = ((size_t)t * 3 * NH_ + part * NH_ + h) * HD_;
  float x1 = Q[base + i], x2 = Q[base + 32 + i];
  if (!BWD) {
    Q[base + i] = x1 * c - x2 * sv;
    Q[base + 32 + i] = x2 * c + x1 * sv;
  } else {
    Q[base + i] = x1 * c + x2 * sv;
    Q[base + 32 + i] = x2 * c - x1 * sv;
  }
}

// ---------------- attention: one wave per row ----------------

__global__ __launch_bounds__(64) void k_attn_fwd(const float* __restrict__ Q,
                                                 float* __restrict__ AO,
                                                 float* __restrict__ mb, float* __restrict__ lb) {
  int q = blockIdx.x, h = blockIdx.y, b = blockIdx.z, d = threadIdx.x;
  size_t tq = (size_t)b * S_ + q;
  float qd = Q[(tq * 3 * NH_ + h) * HD_ + d];
  float m = -1e30f, l = 0.f, acc = 0.f;
  for (int k = 0; k < S_; ++k) {
    size_t tk = (size_t)b * S_ + k;
    size_t koff = (tk * 3 * NH_ + NH_ + h) * HD_ + d;
    float kd = Q[koff];
    float s = wave_sum64(qd * kd) * SCALE_;
    float vd = Q[koff + (size_t)NH_ * HD_];
    float mn = fmaxf(m, s);
    float eo = __expf(m - mn), en = __expf(s - mn);
    l = l * eo + en;
    acc = acc * eo + en * vd;
    m = mn;
  }
  AO[tq * H_ + h * HD_ + d] = acc / l;
  if (d == 0) {
    mb[((size_t)b * NH_ + h) * S_ + q] = m;
    lb[((size_t)b * NH_ + h) * S_ + q] = l;
  }
}

__global__ __launch_bounds__(64) void k_attn_bwd_A(const float* __restrict__ Q,
                                                   const float* __restrict__ dO,
                                                   const float* __restrict__ mb,
                                                   const float* __restrict__ lb,
                                                   float* __restrict__ dQ,
                                                   float* __restrict__ db) {
  int q = blockIdx.x, h = blockIdx.y, b = blockIdx.z, d = threadIdx.x;
  size_t tq = (size_t)b * S_ + q;
  float qd = Q[(tq * 3 * NH_ + h) * HD_ + d];
  float dod = dO[tq * H_ + h * HD_ + d];
  float m = mb[((size_t)b * NH_ + h) * S_ + q];
  float linv = 1.f / lb[((size_t)b * NH_ + h) * S_ + q];
  float acc1 = 0.f, acc2 = 0.f, delta = 0.f;
  for (int k = 0; k < S_; ++k) {
    size_t tk = (size_t)b * S_ + k;
    size_t koff = (tk * 3 * NH_ + NH_ + h) * HD_ + d;
    float kd = Q[koff];
    float vd = Q[koff + (size_t)NH_ * HD_];
    float s = wave_sum64(qd * kd) * SCALE_;
    float p = __expf(s - m) * linv;
    float da = wave_sum64(dod * vd);
    delta += p * da;
    acc1 += p * da * kd;
    acc2 += p * kd;
  }
  dQ[(tq * 3 * NH_ + h) * HD_ + d] = SCALE_ * (acc1 - delta * acc2);
  if (d == 0) db[((size_t)b * NH_ + h) * S_ + q] = delta;
}

__global__ __launch_bounds__(64) void k_attn_bwd_B(const float* __restrict__ Q,
                                                   const float* __restrict__ dO,
                                                   const float* __restrict__ mb,
                                                   const float* __restrict__ lb,
                                                   const float* __restrict__ db,
                                                   float* __restrict__ dQ) {
  int k = blockIdx.x, h = blockIdx.y, b = blockIdx.z, d = threadIdx.x;
  size_t tk = (size_t)b * S_ + k;
  size_t koff = (tk * 3 * NH_ + NH_ + h) * HD_ + d;
  float kd = Q[koff];
  float vd = Q[koff + (size_t)NH_ * HD_];
  float accdk = 0.f, accdv = 0.f;
  size_t statbase = ((size_t)b * NH_ + h) * S_;
  for (int q = 0; q < S_; ++q) {
    size_t tq = (size_t)b * S_ + q;
    float qd = Q[(tq * 3 * NH_ + h) * HD_ + d];
    float dod = dO[tq * H_ + h * HD_ + d];
    float s = wave_sum64(qd * kd) * SCALE_;
    float p = __expf(s - mb[statbase + q]) / lb[statbase + q];
    float da = wave_sum64(dod * vd);
    float ds = SCALE_ * p * (da - db[statbase + q]);
    accdk += ds * qd;
    accdv += p * dod;
  }
  dQ[koff] = accdk;
  dQ[koff + (size_t)NH_ * HD_] = accdv;
}

// ---------------- RMS norm fwd/bwd (row = token, H=512, 256 threads x2) ----------------

__global__ __launch_bounds__(256) void k_rms_fwd(const float* __restrict__ X, float* __restrict__ Y) {
  int t = blockIdx.x, tid = threadIdx.x;
  float x0 = X[(size_t)t * H_ + tid], x1 = X[(size_t)t * H_ + tid + 256];
  __shared__ float red[256];
  red[tid] = x0 * x0 + x1 * x1;
  __syncthreads();
  for (int s = 128; s > 0; s >>= 1) {
    if (tid < s) red[tid] += red[tid + s];
    __syncthreads();
  }
  float r = rsqrtf(red[0] / H_ + EPS_);
  Y[(size_t)t * H_ + tid] = x0 * r;
  Y[(size_t)t * H_ + tid + 256] = x1 * r;
}

__global__ __launch_bounds__(256) void k_rms_bwd(const float* __restrict__ X,
                                                 const float* __restrict__ GY,
                                                 float* __restrict__ GX) {
  int t = blockIdx.x, tid = threadIdx.x;
  float x0 = X[(size_t)t * H_ + tid], x1 = X[(size_t)t * H_ + tid + 256];
  float g0 = GY[(size_t)t * H_ + tid], g1 = GY[(size_t)t * H_ + tid + 256];
  __shared__ float r1[256], r2[256];
  r1[tid] = x0 * x0 + x1 * x1;
  r2[tid] = x0 * g0 + x1 * g1;
  __syncthreads();
  for (int s = 128; s > 0; s >>= 1) {
    if (tid < s) { r1[tid] += r1[tid + s]; r2[tid] += r2[tid + s]; }
    __syncthreads();
  }
  float r = rsqrtf(r1[0] / H_ + EPS_);
  float coef = r * r * r * r2[0] / (float)H_;
  GX[(size_t)t * H_ + tid] = r * g0 - coef * x0;
  GX[(size_t)t * H_ + tid + 256] = r * g1 - coef * x1;
}

// ---------------- SiLU-gate backward, in place on GU (becomes dGU) ----------------

__global__ void k_silu_bwd(float* __restrict__ GU, const float* __restrict__ dact) {
  int idx = blockIdx.x * blockDim.x + threadIdx.x;
  if (idx >= NTOK * INNER_) return;
  int t = idx / INNER_, i = idx % INNER_;
  size_t gb = (size_t)t * 2 * INNER_;
  float g = GU[gb + i], u = GU[gb + INNER_ + i];
  float da = dact[idx];
  float sig = 1.f / (1.f + expf(-g));
  GU[gb + i] = da * u * sig * (1.f + g * (1.f - sig));
  GU[gb + INNER_ + i] = da * g * sig;
}

// ---------------- dprobs -> dlogits -> logits update (one wave per token) ----------------

__global__ __launch_bounds__(64) void k_logits_update(const float* __restrict__ G,
                                                      const float* __restrict__ E,
                                                      const float* __restrict__ P,
                                                      const float* __restrict__ alpha,
                                                      float* __restrict__ logits) {
  int t = blockIdx.x, lane = threadIdx.x;
  float dp[V_];
#pragma unroll
  for (int v = 0; v < V_; ++v) dp[v] = 0.f;
  for (int hh = lane; hh < H_; hh += 64) {
    float gh = G[(size_t)t * H_ + hh];
#pragma unroll
    for (int v = 0; v < V_; ++v) dp[v] += gh * E[v * H_ + hh];
  }
#pragma unroll
  for (int v = 0; v < V_; ++v) dp[v] = wave_sum64(dp[v]) * ESCALE_;
  float dot = 0.f;
  float pv[V_];
#pragma unroll
  for (int v = 0; v < V_; ++v) {
    pv[v] = P[t * V_ + v];
    dot += pv[v] * dp[v];
  }
  float a = fmaxf(alpha[0], 1e-4f);
  if (lane < V_) logits[t * V_ + lane] -= a * pv[lane] * (dp[lane] - dot);
}

// ---------------- host-side orchestration ----------------
// Buffer aliasing (verified by full-sequence liveness trace):
//   dQ == ACT   (dact last read at k_silu_bwd; dQ first write at attn_bwd_A)
//   U == DX == H1 (U dead after down-GEMM; H1 last read at o-GEMM residual of
//                  layer-1 recompute, overwritten by the rms_fwd right after)

struct Ctx {
  float *Q, *dQ, *GU, *ACT, *X1, *X2, *AO, *G, *UDX, *H0, *P, *MB, *LB, *DB, *CS, *SN;
  hipStream_t st;
};

static void block_forward(Ctx& c, const float* hin, float* hout,
                          const float* wqkv, const float* wo, const float* wgu, const float* wd) {
  gemm(c.st, 0, 0, 0, hin, wqkv, nullptr, c.Q, NTOK, 3 * H_, H_, H_);
  k_rope<0><<<(NTOK * NH_ * 2 * 32 + 255) / 256, 256, 0, c.st>>>(c.Q, c.CS, c.SN);
  k_attn_fwd<<<dim3(S_, NH_, B_), 64, 0, c.st>>>(c.Q, c.AO, c.MB, c.LB);
  gemm(c.st, 0, 0, 1, c.AO, wo, hin, c.X1, NTOK, H_, H_, H_);
  k_rms_fwd<<<NTOK, 256, 0, c.st>>>(c.X1, c.UDX);      // U = rms(X1); overwrites hin if hin==UDX (safe: hin dead)
  gemm(c.st, 0, 0, 0, c.UDX, wgu, nullptr, c.GU, NTOK, 2 * INNER_, H_, H_);
  gemm(c.st, 0, 1, 1, c.GU, wd, c.UDX, c.X2, NTOK, H_, INNER_, 2 * INNER_);
  if (hout) k_rms_fwd<<<NTOK, 256, 0, c.st>>>(c.X2, hout);  // hout==UDX ok: U dead after down-GEMM
}

static void block_backward(Ctx& c, const float* hin,
                           const float* wqkv, const float* wo, const float* wgu, const float* wd) {
  // recompute forward internals from checkpoint hin
  block_forward(c, hin, nullptr, wqkv, wo, wgu, wd);
  // dx2 -> DX (==UDX; U dead)
  k_rms_bwd<<<NTOK, 256, 0, c.st>>>(c.X2, c.G, c.UDX);
  // dact = dx2 @ d_w^T  -> ACT (==dQ)
  gemm(c.st, 1, 0, 0, c.UDX, wd, nullptr, c.ACT, NTOK, INNER_, H_, H_);
  // dGU in place
  k_silu_bwd<<<(NTOK * INNER_ + 255) / 256, 256, 0, c.st>>>(c.GU, c.ACT);
  // du = dx2 + dGU @ gu_w^T -> G
  gemm(c.st, 1, 0, 1, c.GU, wgu, c.UDX, c.G, NTOK, H_, 2 * INNER_, 2 * INNER_);
  // dx1 -> DX
  k_rms_bwd<<<NTOK, 256, 0, c.st>>>(c.X1, c.G, c.UDX);
  // d_attn_out = dx1 @ o_w^T  (reuse AO)
  gemm(c.st, 1, 0, 0, c.UDX, wo, nullptr, c.AO, NTOK, H_, H_, H_);
  // attention backward (dQ == ACT buffer; dact dead after silu_bwd)
  k_attn_bwd_A<<<dim3(S_, NH_, B_), 64, 0, c.st>>>(c.Q, c.AO, c.MB, c.LB, c.dQ, c.DB);
  k_attn_bwd_B<<<dim3(S_, NH_, B_), 64, 0, c.st>>>(c.Q, c.AO, c.MB, c.LB, c.DB, c.dQ);
  k_rope<1><<<(NTOK * NH_ * 2 * 32 + 255) / 256, 256, 0, c.st>>>(c.dQ, c.CS, c.SN);
  // dh_in = dx1 + dqkv @ qkv_w^T -> G
  gemm(c.st, 1, 0, 1, c.dQ, wqkv, c.UDX, c.G, NTOK, H_, 3 * H_, 3 * H_);
}

extern "C" void kernel_launch(void* const* d_in, const int* in_sizes, int n_in,
                              void* d_out, int out_size, void* d_ws, size_t ws_size,
                              hipStream_t stream) {
  const int* inputs = (const int*)d_in[0];
  const float* E = (const float*)d_in[2];
  const float* ew = (const float*)d_in[3];
  const float* qkvw = (const float*)d_in[4];
  const float* ow = (const float*)d_in[5];
  const float* guw = (const float*)d_in[6];
  const float* dw = (const float*)d_in[7];
  const float* alpha = (const float*)d_in[8];
  float* logits = (float*)d_out;

  // ---- workspace budget: 66,664,800 floats = 266.66 MB ----
  const size_t NEED =
      ((size_t)NTOK * 3 * H_) +      // Q
      ((size_t)NTOK * 2 * INNER_) +  // GU
      ((size_t)NTOK * 3 * H_) +      // dQ/ACT
      6 * ((size_t)NTOK * H_) +      // X1, X2, AO, G, UDX, H0
      ((size_t)NTOK * V_) +          // P
      3 * ((size_t)B_ * NH_ * S_) +  // MB, LB, DB
      2 * ((size_t)S_ * 32);         // CS, SN
  if (ws_size < NEED * sizeof(float)) {
    // insufficient workspace: emit zeros deterministically instead of faulting
    k_zero<<<(NTOK * V_ + 255) / 256, 256, 0, stream>>>(logits, NTOK * V_);
    return;
  }

  float* f = (float*)d_ws;
  Ctx c;
  c.st = stream;
  c.Q = f;    f += (size_t)NTOK * 3 * H_;
  c.GU = f;   f += (size_t)NTOK * 2 * INNER_;
  c.dQ = f;   c.ACT = f;  f += (size_t)NTOK * 3 * H_;   // aliased
  c.X1 = f;   f += (size_t)NTOK * H_;
  c.X2 = f;   f += (size_t)NTOK * H_;
  c.AO = f;   f += (size_t)NTOK * H_;
  c.G = f;    f += (size_t)NTOK * H_;
  c.UDX = f;  f += (size_t)NTOK * H_;                   // U == DX == H1
  c.H0 = f;   f += (size_t)NTOK * H_;
  c.P = f;    f += (size_t)NTOK * V_;
  c.MB = f;   f += (size_t)B_ * NH_ * S_;
  c.LB = f;   f += (size_t)B_ * NH_ * S_;
  c.DB = f;   f += (size_t)B_ * NH_ * S_;
  c.CS = f;   f += (size_t)S_ * 32;
  c.SN = f;   f += (size_t)S_ * 32;

  const size_t LQKV = (size_t)H_ * 3 * H_;
  const size_t LO = (size_t)H_ * H_;
  const size_t LGU = (size_t)H_ * 2 * INNER_;
  const size_t LD = (size_t)INNER_ * H_;

  k_zero<<<(NTOK * V_ + 255) / 256, 256, 0, stream>>>(logits, NTOK * V_);
  k_rope_tables<<<(S_ * 32 + 255) / 256, 256, 0, stream>>>(c.CS, c.SN);

  for (int step = 0; step < STEPS_; ++step) {
    k_softmax_logits<<<(NTOK + 255) / 256, 256, 0, stream>>>(logits, c.P);
    k_h0<<<NTOK, 256, 0, stream>>>(c.P, E, inputs, c.H0);
    // forward layer 0 only; h1 checkpoint lands in UDX.
    block_forward(c, c.H0, c.UDX, qkvw, ow, guw, dw);
    // dE/dh2 = energy_w broadcast
    k_gfill<<<(NTOK * H_ + 255) / 256, 256, 0, stream>>>(ew, c.G);
    // backward layer 1 (checkpoint h1 == UDX; consumed by its own recompute)
    block_backward(c, c.UDX, qkvw + LQKV, ow + LO, guw + LGU, dw + LD);
    // backward layer 0 (checkpoint h0)
    block_backward(c, c.H0, qkvw, ow, guw, dw);
    // dlogits and in-place logits update
    k_logits_update<<<NTOK, 64, 0, stream>>>(c.G, E, c.P, alpha, logits);
  }
}

// Round 3
// 28257.715 us; speedup vs baseline: 3.1029x; 3.1029x over previous
//
#include <hip/hip_runtime.h>
#include <math.h>

#define B_ 8
#define S_ 900
#define V_ 11
#define H_ 512
#define NH_ 8
#define HD_ 64
#define INNER_ 1536
#define STEPS_ 2
#define NTOK (B_*S_)
#define EPS_ 1e-5f
#define THETA_ 10000.0f
#define ESCALE_ 22.627416997969522f
#define SCALE_ 0.125f

__device__ inline float wave_sum64(float x) {
#pragma unroll
  for (int off = 32; off > 0; off >>= 1) x += __shfl_xor(x, off, 64);
  return x;
}

__device__ inline float dot64(const float4* a, const float4* b) {
  float s = 0.f;
#pragma unroll
  for (int i = 0; i < 16; ++i) {
    float4 x = a[i], y = b[i];
    s += x.x * y.x + x.y * y.y + x.z * y.z + x.w * y.w;
  }
  return s;
}

// ---------------- small kernels ----------------

__global__ void k_zero(float* p, int n) {
  int i = blockIdx.x * blockDim.x + threadIdx.x;
  if (i < n) p[i] = 0.f;
}

__global__ void k_rope_tables(float* cs, float* sn) {
  int idx = blockIdx.x * blockDim.x + threadIdx.x;
  if (idx >= S_ * 32) return;
  int s = idx >> 5, i = idx & 31;
  float freq = powf(THETA_, -(float)i / 32.0f);
  float ang = (float)s * freq;
  cs[idx] = cosf(ang);
  sn[idx] = sinf(ang);
}

__global__ void k_softmax_logits(const float* __restrict__ logits, float* __restrict__ P) {
  int t = blockIdx.x * blockDim.x + threadIdx.x;
  if (t >= NTOK) return;
  float x[V_];
  float m = -1e30f;
#pragma unroll
  for (int v = 0; v < V_; ++v) { x[v] = logits[t * V_ + v]; m = fmaxf(m, x[v]); }
  float ssum = 0.f;
#pragma unroll
  for (int v = 0; v < V_; ++v) { x[v] = expf(x[v] - m); ssum += x[v]; }
  float inv = 1.f / ssum;
#pragma unroll
  for (int v = 0; v < V_; ++v) P[t * V_ + v] = x[v] * inv;
}

__global__ void k_h0(const float* __restrict__ P, const float* __restrict__ E,
                     const int* __restrict__ inp, float* __restrict__ h0) {
  int t = blockIdx.x;
  int tid = threadIdx.x;
  __shared__ float p[V_];
  __shared__ int iw;
  if (tid < V_) p[tid] = P[t * V_ + tid];
  if (tid == 0) iw = inp[t];
  __syncthreads();
  for (int h = tid; h < H_; h += blockDim.x) {
    float acc = E[iw * H_ + h];
#pragma unroll
    for (int v = 0; v < V_; ++v) acc += p[v] * E[v * H_ + h];
    h0[(size_t)t * H_ + h] = ESCALE_ * acc;
  }
}

__global__ void k_gfill(const float* __restrict__ ew, float* __restrict__ G) {
  int idx = blockIdx.x * blockDim.x + threadIdx.x;
  if (idx < NTOK * H_) G[idx] = ew[idx & (H_ - 1)];
}

// ---------------- GEMM: C[M,N] = A @ B (+D), B optionally transposed ----------------

template <int TB, int SILU_A, int ADD>
__global__ __launch_bounds__(256) void k_gemm(const float* __restrict__ A,
                                              const float* __restrict__ Bm,
                                              const float* __restrict__ Dm,
                                              float* __restrict__ Cm,
                                              int M, int N, int K, int lda) {
  __shared__ float As[16][68];
  __shared__ float Bs[16][68];
  int tid = threadIdx.x;
  int m0 = blockIdx.y * 64, n0 = blockIdx.x * 64;
  int ty = tid >> 4, tx = tid & 15;
  float acc[4][4] = {};
  for (int k0 = 0; k0 < K; k0 += 16) {
#pragma unroll
    for (int i = tid; i < 64 * 16; i += 256) {
      int r = i >> 4, cc = i & 15;
      int gr = m0 + r;
      float v = 0.f;
      if (gr < M) {
        if (SILU_A) {
          float g = A[(size_t)gr * lda + k0 + cc];
          float u = A[(size_t)gr * lda + INNER_ + k0 + cc];
          v = (g / (1.f + expf(-g))) * u;
        } else {
          v = A[(size_t)gr * lda + k0 + cc];
        }
      }
      As[cc][r] = v;
    }
    if (TB) {
#pragma unroll
      for (int i = tid; i < 16 * 64; i += 256) {
        int r = i & 15, cc = i >> 4;
        Bs[r][cc] = Bm[(size_t)(n0 + cc) * K + k0 + r];
      }
    } else {
#pragma unroll
      for (int i = tid; i < 16 * 64; i += 256) {
        int r = i >> 6, cc = i & 63;
        Bs[r][cc] = Bm[(size_t)(k0 + r) * N + n0 + cc];
      }
    }
    __syncthreads();
#pragma unroll
    for (int kk = 0; kk < 16; ++kk) {
      float a[4], bv[4];
#pragma unroll
      for (int i = 0; i < 4; ++i) a[i] = As[kk][ty * 4 + i];
#pragma unroll
      for (int j = 0; j < 4; ++j) bv[j] = Bs[kk][tx * 4 + j];
#pragma unroll
      for (int i = 0; i < 4; ++i)
#pragma unroll
        for (int j = 0; j < 4; ++j) acc[i][j] += a[i] * bv[j];
    }
    __syncthreads();
  }
#pragma unroll
  for (int i = 0; i < 4; ++i) {
    int gr = m0 + ty * 4 + i;
    if (gr >= M) continue;
#pragma unroll
    for (int j = 0; j < 4; ++j) {
      int gc = n0 + tx * 4 + j;
      float out = acc[i][j];
      if (ADD) out += Dm[(size_t)gr * N + gc];
      Cm[(size_t)gr * N + gc] = out;
    }
  }
}

static void gemm(hipStream_t st, int tb, int silu, int add,
                 const float* A, const float* Bm, const float* Dm, float* Cm,
                 int M, int N, int K, int lda) {
  dim3 grid(N / 64, (M + 63) / 64);
  if (!tb && !silu && !add) k_gemm<0, 0, 0><<<grid, 256, 0, st>>>(A, Bm, Dm, Cm, M, N, K, lda);
  else if (!tb && !silu && add) k_gemm<0, 0, 1><<<grid, 256, 0, st>>>(A, Bm, Dm, Cm, M, N, K, lda);
  else if (!tb && silu && add) k_gemm<0, 1, 1><<<grid, 256, 0, st>>>(A, Bm, Dm, Cm, M, N, K, lda);
  else if (tb && !silu && !add) k_gemm<1, 0, 0><<<grid, 256, 0, st>>>(A, Bm, Dm, Cm, M, N, K, lda);
  else k_gemm<1, 0, 1><<<grid, 256, 0, st>>>(A, Bm, Dm, Cm, M, N, K, lda);
}

// ---------------- RoPE fwd/bwd (in place on qkv buffer, q and k channels) ----------------

template <int BWD>
__global__ void k_rope(float* __restrict__ Q, const float* __restrict__ cs,
                       const float* __restrict__ sn) {
  int idx = blockIdx.x * blockDim.x + threadIdx.x;
  if (idx >= NTOK * NH_ * 2 * 32) return;
  int i = idx & 31;
  int h = (idx >> 5) & (NH_ - 1);
  int part = (idx >> 8) & 1;
  int t = idx >> 9;
  int s = t % S_;
  float c = cs[s * 32 + i], sv = sn[s * 32 + i];
  size_t base = ((size_t)t * 3 * NH_ + part * NH_ + h) * HD_;
  float x1 = Q[base + i], x2 = Q[base + 32 + i];
  if (!BWD) {
    Q[base + i] = x1 * c - x2 * sv;
    Q[base + 32 + i] = x2 * c + x1 * sv;
  } else {
    Q[base + i] = x1 * c + x2 * sv;
    Q[base + 32 + i] = x2 * c - x1 * sv;
  }
}

// ---------------- attention v2: thread-per-row, LDS-tiled, no cross-lane ops ----------------
// QKV layout: [t][3*NH][64], Q head h at (t*24+h)*64, K at (t*24+8+h)*64, V at (t*24+16+h)*64.

__global__ __launch_bounds__(256, 1) void k_attn_fwd2(const float* __restrict__ QKV,
                                                      float* __restrict__ AO,
                                                      float* __restrict__ MB,
                                                      float* __restrict__ LB) {
  __shared__ float4 Ks[64][16];
  __shared__ float4 Vs[64][16];
  int tid = threadIdx.x;
  int h = blockIdx.y, b = blockIdx.z;
  int r = blockIdx.x * 256 + tid;
  int rr = r < S_ ? r : S_ - 1;
  size_t tq = (size_t)b * S_ + rr;
  const float4* qp = (const float4*)&QKV[(tq * 24 + h) * (size_t)64];
  float4 q4[16];
#pragma unroll
  for (int i = 0; i < 16; ++i) q4[i] = qp[i];
  float m = -1e30f, l = 0.f;
  float4 acc[16];
#pragma unroll
  for (int i = 0; i < 16; ++i) acc[i] = make_float4(0.f, 0.f, 0.f, 0.f);
  for (int kt = 0; kt < S_; kt += 64) {
    __syncthreads();
    for (int j = tid; j < 1024; j += 256) {
      int row = j >> 4, seg = j & 15;
      int src = kt + row;
      float4 kv = make_float4(0.f, 0.f, 0.f, 0.f), vv = kv;
      if (src < S_) {
        size_t tk = (size_t)b * S_ + src;
        kv = ((const float4*)&QKV[(tk * 24 + 8 + h) * (size_t)64])[seg];
        vv = ((const float4*)&QKV[(tk * 24 + 16 + h) * (size_t)64])[seg];
      }
      Ks[row][seg] = kv;
      Vs[row][seg] = vv;
    }
    __syncthreads();
    int kmax = min(64, S_ - kt);
    for (int kk = 0; kk < kmax; ++kk) {
      float s = dot64(q4, Ks[kk]) * SCALE_;
      float p;
      if (s > m) {
        float e = __expf(m - s);
        l *= e;
#pragma unroll
        for (int i = 0; i < 16; ++i) {
          acc[i].x *= e; acc[i].y *= e; acc[i].z *= e; acc[i].w *= e;
        }
        m = s;
        p = 1.f;
      } else {
        p = __expf(s - m);
      }
      l += p;
#pragma unroll
      for (int i = 0; i < 16; ++i) {
        float4 v = Vs[kk][i];
        acc[i].x += p * v.x; acc[i].y += p * v.y; acc[i].z += p * v.z; acc[i].w += p * v.w;
      }
    }
  }
  if (r < S_) {
    float linv = 1.f / l;
    float4* op = (float4*)&AO[tq * H_ + h * 64];
#pragma unroll
    for (int i = 0; i < 16; ++i)
      op[i] = make_float4(acc[i].x * linv, acc[i].y * linv, acc[i].z * linv, acc[i].w * linv);
    MB[((size_t)b * NH_ + h) * S_ + r] = m;
    LB[((size_t)b * NH_ + h) * S_ + r] = linv;
  }
}

// dQ pass: thread owns q-row; delta computed thread-locally from O,dO and saved for dK pass.
__global__ __launch_bounds__(256, 1) void k_attn_bwd_dq(const float* __restrict__ QKV,
                                                        const float* __restrict__ O,
                                                        const float* __restrict__ dO,
                                                        const float* __restrict__ MB,
                                                        const float* __restrict__ LB,
                                                        float* __restrict__ dQKV,
                                                        float* __restrict__ DB) {
  __shared__ float4 Ks[64][16];
  __shared__ float4 Vs[64][16];
  int tid = threadIdx.x;
  int h = blockIdx.y, b = blockIdx.z;
  int r = blockIdx.x * 256 + tid;
  int rr = r < S_ ? r : S_ - 1;
  size_t tq = (size_t)b * S_ + rr;
  const float4* qp = (const float4*)&QKV[(tq * 24 + h) * (size_t)64];
  const float4* dop = (const float4*)&dO[tq * H_ + h * 64];
  const float4* op = (const float4*)&O[tq * H_ + h * 64];
  float4 q4[16], do4[16];
  float delta = 0.f;
#pragma unroll
  for (int i = 0; i < 16; ++i) {
    q4[i] = qp[i];
    do4[i] = dop[i];
    float4 o = op[i];
    delta += do4[i].x * o.x + do4[i].y * o.y + do4[i].z * o.z + do4[i].w * o.w;
  }
  float m = MB[((size_t)b * NH_ + h) * S_ + rr];
  float linv = LB[((size_t)b * NH_ + h) * S_ + rr];
  float4 dq[16];
#pragma unroll
  for (int i = 0; i < 16; ++i) dq[i] = make_float4(0.f, 0.f, 0.f, 0.f);
  for (int kt = 0; kt < S_; kt += 64) {
    __syncthreads();
    for (int j = tid; j < 1024; j += 256) {
      int row = j >> 4, seg = j & 15;
      int src = kt + row;
      float4 kv = make_float4(0.f, 0.f, 0.f, 0.f), vv = kv;
      if (src < S_) {
        size_t tk = (size_t)b * S_ + src;
        kv = ((const float4*)&QKV[(tk * 24 + 8 + h) * (size_t)64])[seg];
        vv = ((const float4*)&QKV[(tk * 24 + 16 + h) * (size_t)64])[seg];
      }
      Ks[row][seg] = kv;
      Vs[row][seg] = vv;
    }
    __syncthreads();
    int kmax = min(64, S_ - kt);
    for (int kk = 0; kk < kmax; ++kk) {
      float s = dot64(q4, Ks[kk]) * SCALE_;
      float p = __expf(s - m) * linv;
      float da = dot64(do4, Vs[kk]);
      float t = p * (da - delta);
#pragma unroll
      for (int i = 0; i < 16; ++i) {
        float4 k4 = Ks[kk][i];
        dq[i].x += t * k4.x; dq[i].y += t * k4.y; dq[i].z += t * k4.z; dq[i].w += t * k4.w;
      }
    }
  }
  if (r < S_) {
    float4* out = (float4*)&dQKV[(tq * 24 + h) * (size_t)64];
#pragma unroll
    for (int i = 0; i < 16; ++i)
      out[i] = make_float4(SCALE_ * dq[i].x, SCALE_ * dq[i].y, SCALE_ * dq[i].z, SCALE_ * dq[i].w);
    DB[((size_t)b * NH_ + h) * S_ + r] = delta;
  }
}

// dV pass: thread owns k-row.
__global__ __launch_bounds__(256, 1) void k_attn_bwd_dv(const float* __restrict__ QKV,
                                                        const float* __restrict__ dO,
                                                        const float* __restrict__ MB,
                                                        const float* __restrict__ LB,
                                                        float* __restrict__ dQKV) {
  __shared__ float4 Qs[64][16];
  __shared__ float4 dOs[64][16];
  __shared__ float sM[64], sL[64];
  int tid = threadIdx.x;
  int h = blockIdx.y, b = blockIdx.z;
  int r = blockIdx.x * 256 + tid;
  int rr = r < S_ ? r : S_ - 1;
  size_t tk = (size_t)b * S_ + rr;
  const float4* kp = (const float4*)&QKV[(tk * 24 + 8 + h) * (size_t)64];
  float4 k4[16];
#pragma unroll
  for (int i = 0; i < 16; ++i) k4[i] = kp[i];
  float4 dv[16];
#pragma unroll
  for (int i = 0; i < 16; ++i) dv[i] = make_float4(0.f, 0.f, 0.f, 0.f);
  size_t statbase = ((size_t)b * NH_ + h) * S_;
  for (int qt = 0; qt < S_; qt += 64) {
    __syncthreads();
    for (int j = tid; j < 1024; j += 256) {
      int row = j >> 4, seg = j & 15;
      int src = qt + row;
      float4 qv = make_float4(0.f, 0.f, 0.f, 0.f), dv4 = qv;
      if (src < S_) {
        size_t ts = (size_t)b * S_ + src;
        qv = ((const float4*)&QKV[(ts * 24 + h) * (size_t)64])[seg];
        dv4 = ((const float4*)&dO[ts * H_ + h * 64])[seg];
      }
      Qs[row][seg] = qv;
      dOs[row][seg] = dv4;
    }
    for (int j = tid; j < 64; j += 256) {
      int src = qt + j;
      int sc = src < S_ ? src : S_ - 1;
      sM[j] = MB[statbase + sc];
      sL[j] = LB[statbase + sc];
    }
    __syncthreads();
    int qmax = min(64, S_ - qt);
    for (int qq = 0; qq < qmax; ++qq) {
      float s = dot64(k4, Qs[qq]) * SCALE_;
      float p = __expf(s - sM[qq]) * sL[qq];
#pragma unroll
      for (int i = 0; i < 16; ++i) {
        float4 d = dOs[qq][i];
        dv[i].x += p * d.x; dv[i].y += p * d.y; dv[i].z += p * d.z; dv[i].w += p * d.w;
      }
    }
  }
  if (r < S_) {
    float4* out = (float4*)&dQKV[(tk * 24 + 16 + h) * (size_t)64];
#pragma unroll
    for (int i = 0; i < 16; ++i) out[i] = dv[i];
  }
}

// dK pass: thread owns k-row (needs V row + delta).
__global__ __launch_bounds__(256, 1) void k_attn_bwd_dk(const float* __restrict__ QKV,
                                                        const float* __restrict__ dO,
                                                        const float* __restrict__ MB,
                                                        const float* __restrict__ LB,
                                                        const float* __restrict__ DB,
                                                        float* __restrict__ dQKV) {
  __shared__ float4 Qs[64][16];
  __shared__ float4 dOs[64][16];
  __shared__ float sM[64], sL[64], sD[64];
  int tid = threadIdx.x;
  int h = blockIdx.y, b = blockIdx.z;
  int r = blockIdx.x * 256 + tid;
  int rr = r < S_ ? r : S_ - 1;
  size_t tk = (size_t)b * S_ + rr;
  const float4* kp = (const float4*)&QKV[(tk * 24 + 8 + h) * (size_t)64];
  const float4* vp = (const float4*)&QKV[(tk * 24 + 16 + h) * (size_t)64];
  float4 k4[16], v4[16];
#pragma unroll
  for (int i = 0; i < 16; ++i) { k4[i] = kp[i]; v4[i] = vp[i]; }
  float4 dk[16];
#pragma unroll
  for (int i = 0; i < 16; ++i) dk[i] = make_float4(0.f, 0.f, 0.f, 0.f);
  size_t statbase = ((size_t)b * NH_ + h) * S_;
  for (int qt = 0; qt < S_; qt += 64) {
    __syncthreads();
    for (int j = tid; j < 1024; j += 256) {
      int row = j >> 4, seg = j & 15;
      int src = qt + row;
      float4 qv = make_float4(0.f, 0.f, 0.f, 0.f), dv4 = qv;
      if (src < S_) {
        size_t ts = (size_t)b * S_ + src;
        qv = ((const float4*)&QKV[(ts * 24 + h) * (size_t)64])[seg];
        dv4 = ((const float4*)&dO[ts * H_ + h * 64])[seg];
      }
      Qs[row][seg] = qv;
      dOs[row][seg] = dv4;
    }
    for (int j = tid; j < 64; j += 256) {
      int src = qt + j;
      int sc = src < S_ ? src : S_ - 1;
      sM[j] = MB[statbase + sc];
      sL[j] = LB[statbase + sc];
      sD[j] = DB[statbase + sc];
    }
    __syncthreads();
    int qmax = min(64, S_ - qt);
    for (int qq = 0; qq < qmax; ++qq) {
      float s = dot64(k4, Qs[qq]) * SCALE_;
      float p = __expf(s - sM[qq]) * sL[qq];
      float da = dot64(v4, dOs[qq]);
      float t = p * (da - sD[qq]);
#pragma unroll
      for (int i = 0; i < 16; ++i) {
        float4 q = Qs[qq][i];
        dk[i].x += t * q.x; dk[i].y += t * q.y; dk[i].z += t * q.z; dk[i].w += t * q.w;
      }
    }
  }
  if (r < S_) {
    float4* out = (float4*)&dQKV[(tk * 24 + 8 + h) * (size_t)64];
#pragma unroll
    for (int i = 0; i < 16; ++i)
      out[i] = make_float4(SCALE_ * dk[i].x, SCALE_ * dk[i].y, SCALE_ * dk[i].z, SCALE_ * dk[i].w);
  }
}

// ---------------- RMS norm fwd/bwd ----------------

__global__ __launch_bounds__(256) void k_rms_fwd(const float* __restrict__ X, float* __restrict__ Y) {
  int t = blockIdx.x, tid = threadIdx.x;
  float x0 = X[(size_t)t * H_ + tid], x1 = X[(size_t)t * H_ + tid + 256];
  __shared__ float red[256];
  red[tid] = x0 * x0 + x1 * x1;
  __syncthreads();
  for (int s = 128; s > 0; s >>= 1) {
    if (tid < s) red[tid] += red[tid + s];
    __syncthreads();
  }
  float r = rsqrtf(red[0] / H_ + EPS_);
  Y[(size_t)t * H_ + tid] = x0 * r;
  Y[(size_t)t * H_ + tid + 256] = x1 * r;
}

__global__ __launch_bounds__(256) void k_rms_bwd(const float* __restrict__ X,
                                                 const float* __restrict__ GY,
                                                 float* __restrict__ GX) {
  int t = blockIdx.x, tid = threadIdx.x;
  float x0 = X[(size_t)t * H_ + tid], x1 = X[(size_t)t * H_ + tid + 256];
  float g0 = GY[(size_t)t * H_ + tid], g1 = GY[(size_t)t * H_ + tid + 256];
  __shared__ float r1[256], r2[256];
  r1[tid] = x0 * x0 + x1 * x1;
  r2[tid] = x0 * g0 + x1 * g1;
  __syncthreads();
  for (int s = 128; s > 0; s >>= 1) {
    if (tid < s) { r1[tid] += r1[tid + s]; r2[tid] += r2[tid + s]; }
    __syncthreads();
  }
  float r = rsqrtf(r1[0] / H_ + EPS_);
  float coef = r * r * r * r2[0] / (float)H_;
  GX[(size_t)t * H_ + tid] = r * g0 - coef * x0;
  GX[(size_t)t * H_ + tid + 256] = r * g1 - coef * x1;
}

// ---------------- SiLU-gate backward, in place on GU ----------------

__global__ void k_silu_bwd(float* __restrict__ GU, const float* __restrict__ dact) {
  int idx = blockIdx.x * blockDim.x + threadIdx.x;
  if (idx >= NTOK * INNER_) return;
  int t = idx / INNER_, i = idx % INNER_;
  size_t gb = (size_t)t * 2 * INNER_;
  float g = GU[gb + i], u = GU[gb + INNER_ + i];
  float da = dact[idx];
  float sig = 1.f / (1.f + expf(-g));
  GU[gb + i] = da * u * sig * (1.f + g * (1.f - sig));
  GU[gb + INNER_ + i] = da * g * sig;
}

// ---------------- logits update ----------------

__global__ __launch_bounds__(64) void k_logits_update(const float* __restrict__ G,
                                                      const float* __restrict__ E,
                                                      const float* __restrict__ P,
                                                      const float* __restrict__ alpha,
                                                      float* __restrict__ logits) {
  int t = blockIdx.x, lane = threadIdx.x;
  float dp[V_];
#pragma unroll
  for (int v = 0; v < V_; ++v) dp[v] = 0.f;
  for (int hh = lane; hh < H_; hh += 64) {
    float gh = G[(size_t)t * H_ + hh];
#pragma unroll
    for (int v = 0; v < V_; ++v) dp[v] += gh * E[v * H_ + hh];
  }
#pragma unroll
  for (int v = 0; v < V_; ++v) dp[v] = wave_sum64(dp[v]) * ESCALE_;
  float dot = 0.f;
  float pv[V_];
#pragma unroll
  for (int v = 0; v < V_; ++v) {
    pv[v] = P[t * V_ + v];
    dot += pv[v] * dp[v];
  }
  float a = fmaxf(alpha[0], 1e-4f);
  if (lane < V_) logits[t * V_ + lane] -= a * pv[lane] * (dp[lane] - dot);
}

// ---------------- host-side orchestration ----------------
// Aliasing: dQ == ACT; U == DX == H1 (UDX). dO lives in X2 during attn bwd (X2 dead there).

struct Ctx {
  float *Q, *dQ, *GU, *ACT, *X1, *X2, *AO, *G, *UDX, *H0, *P, *MB, *LB, *DB, *CS, *SN;
  hipStream_t st;
};

static void block_forward(Ctx& c, const float* hin, float* hout,
                          const float* wqkv, const float* wo, const float* wgu, const float* wd) {
  gemm(c.st, 0, 0, 0, hin, wqkv, nullptr, c.Q, NTOK, 3 * H_, H_, H_);
  k_rope<0><<<(NTOK * NH_ * 2 * 32 + 255) / 256, 256, 0, c.st>>>(c.Q, c.CS, c.SN);
  k_attn_fwd2<<<dim3((S_ + 255) / 256, NH_, B_), 256, 0, c.st>>>(c.Q, c.AO, c.MB, c.LB);
  gemm(c.st, 0, 0, 1, c.AO, wo, hin, c.X1, NTOK, H_, H_, H_);
  k_rms_fwd<<<NTOK, 256, 0, c.st>>>(c.X1, c.UDX);
  gemm(c.st, 0, 0, 0, c.UDX, wgu, nullptr, c.GU, NTOK, 2 * INNER_, H_, H_);
  gemm(c.st, 0, 1, 1, c.GU, wd, c.UDX, c.X2, NTOK, H_, INNER_, 2 * INNER_);
  if (hout) k_rms_fwd<<<NTOK, 256, 0, c.st>>>(c.X2, hout);
}

static void block_backward(Ctx& c, const float* hin,
                           const float* wqkv, const float* wo, const float* wgu, const float* wd) {
  block_forward(c, hin, nullptr, wqkv, wo, wgu, wd);
  k_rms_bwd<<<NTOK, 256, 0, c.st>>>(c.X2, c.G, c.UDX);
  gemm(c.st, 1, 0, 0, c.UDX, wd, nullptr, c.ACT, NTOK, INNER_, H_, H_);
  k_silu_bwd<<<(NTOK * INNER_ + 255) / 256, 256, 0, c.st>>>(c.GU, c.ACT);
  gemm(c.st, 1, 0, 1, c.GU, wgu, c.UDX, c.G, NTOK, H_, 2 * INNER_, 2 * INNER_);
  k_rms_bwd<<<NTOK, 256, 0, c.st>>>(c.X1, c.G, c.UDX);
  // d_attn_out -> X2 (X2 dead; AO must survive as O for the delta trick)
  gemm(c.st, 1, 0, 0, c.UDX, wo, nullptr, c.X2, NTOK, H_, H_, H_);
  dim3 agrid((S_ + 255) / 256, NH_, B_);
  k_attn_bwd_dq<<<agrid, 256, 0, c.st>>>(c.Q, c.AO, c.X2, c.MB, c.LB, c.dQ, c.DB);
  k_attn_bwd_dv<<<agrid, 256, 0, c.st>>>(c.Q, c.X2, c.MB, c.LB, c.dQ);
  k_attn_bwd_dk<<<agrid, 256, 0, c.st>>>(c.Q, c.X2, c.MB, c.LB, c.DB, c.dQ);
  k_rope<1><<<(NTOK * NH_ * 2 * 32 + 255) / 256, 256, 0, c.st>>>(c.dQ, c.CS, c.SN);
  gemm(c.st, 1, 0, 1, c.dQ, wqkv, c.UDX, c.G, NTOK, H_, 3 * H_, 3 * H_);
}

extern "C" void kernel_launch(void* const* d_in, const int* in_sizes, int n_in,
                              void* d_out, int out_size, void* d_ws, size_t ws_size,
                              hipStream_t stream) {
  const int* inputs = (const int*)d_in[0];
  const float* E = (const float*)d_in[2];
  const float* ew = (const float*)d_in[3];
  const float* qkvw = (const float*)d_in[4];
  const float* ow = (const float*)d_in[5];
  const float* guw = (const float*)d_in[6];
  const float* dw = (const float*)d_in[7];
  const float* alpha = (const float*)d_in[8];
  float* logits = (float*)d_out;

  const size_t NEED =
      ((size_t)NTOK * 3 * H_) +      // Q
      ((size_t)NTOK * 2 * INNER_) +  // GU
      ((size_t)NTOK * 3 * H_) +      // dQ/ACT
      6 * ((size_t)NTOK * H_) +      // X1, X2, AO, G, UDX, H0
      ((size_t)NTOK * V_) +          // P
      3 * ((size_t)B_ * NH_ * S_) +  // MB, LB, DB
      2 * ((size_t)S_ * 32);         // CS, SN
  if (ws_size < NEED * sizeof(float)) {
    k_zero<<<(NTOK * V_ + 255) / 256, 256, 0, stream>>>(logits, NTOK * V_);
    return;
  }

  float* f = (float*)d_ws;
  Ctx c;
  c.st = stream;
  c.Q = f;    f += (size_t)NTOK * 3 * H_;
  c.GU = f;   f += (size_t)NTOK * 2 * INNER_;
  c.dQ = f;   c.ACT = f;  f += (size_t)NTOK * 3 * H_;
  c.X1 = f;   f += (size_t)NTOK * H_;
  c.X2 = f;   f += (size_t)NTOK * H_;
  c.AO = f;   f += (size_t)NTOK * H_;
  c.G = f;    f += (size_t)NTOK * H_;
  c.UDX = f;  f += (size_t)NTOK * H_;
  c.H0 = f;   f += (size_t)NTOK * H_;
  c.P = f;    f += (size_t)NTOK * V_;
  c.MB = f;   f += (size_t)B_ * NH_ * S_;
  c.LB = f;   f += (size_t)B_ * NH_ * S_;
  c.DB = f;   f += (size_t)B_ * NH_ * S_;
  c.CS = f;   f += (size_t)S_ * 32;
  c.SN = f;   f += (size_t)S_ * 32;

  const size_t LQKV = (size_t)H_ * 3 * H_;
  const size_t LO = (size_t)H_ * H_;
  const size_t LGU = (size_t)H_ * 2 * INNER_;
  const size_t LD = (size_t)INNER_ * H_;

  k_zero<<<(NTOK * V_ + 255) / 256, 256, 0, stream>>>(logits, NTOK * V_);
  k_rope_tables<<<(S_ * 32 + 255) / 256, 256, 0, stream>>>(c.CS, c.SN);

  for (int step = 0; step < STEPS_; ++step) {
    k_softmax_logits<<<(NTOK + 255) / 256, 256, 0, stream>>>(logits, c.P);
    k_h0<<<NTOK, 256, 0, stream>>>(c.P, E, inputs, c.H0);
    block_forward(c, c.H0, c.UDX, qkvw, ow, guw, dw);
    k_gfill<<<(NTOK * H_ + 255) / 256, 256, 0, stream>>>(ew, c.G);
    block_backward(c, c.UDX, qkvw + LQKV, ow + LO, guw + LGU, dw + LD);
    block_backward(c, c.H0, qkvw, ow, guw, dw);
    k_logits_update<<<NTOK, 64, 0, stream>>>(c.G, E, c.P, alpha, logits);
  }
}

// Round 4
// 18575.194 us; speedup vs baseline: 4.7203x; 1.5213x over previous
//
#include <hip/hip_runtime.h>
#include <math.h>

#define B_ 8
#define S_ 900
#define V_ 11
#define H_ 512
#define NH_ 8
#define HD_ 64
#define INNER_ 1536
#define STEPS_ 2
#define NTOK (B_*S_)
#define EPS_ 1e-5f
#define THETA_ 10000.0f
#define ESCALE_ 22.627416997969522f
#define SCALE_ 0.125f

__device__ inline float wave_sum64(float x) {
#pragma unroll
  for (int off = 32; off > 0; off >>= 1) x += __shfl_xor(x, off, 64);
  return x;
}

__device__ inline float dot16(const float4* a, const float4* b) {
  float s = 0.f;
#pragma unroll
  for (int i = 0; i < 4; ++i) {
    float4 x = a[i], y = b[i];
    s += x.x * y.x + x.y * y.y + x.z * y.z + x.w * y.w;
  }
  return s;
}

// sum across the 4 lanes of a row-quad (lanes 4k..4k+3)
__device__ inline float quad_sum(float x) {
  x += __shfl_xor(x, 1, 64);
  x += __shfl_xor(x, 2, 64);
  return x;
}

// ---------------- small kernels ----------------

__global__ void k_zero(float* p, int n) {
  int i = blockIdx.x * blockDim.x + threadIdx.x;
  if (i < n) p[i] = 0.f;
}

__global__ void k_rope_tables(float* cs, float* sn) {
  int idx = blockIdx.x * blockDim.x + threadIdx.x;
  if (idx >= S_ * 32) return;
  int s = idx >> 5, i = idx & 31;
  float freq = powf(THETA_, -(float)i / 32.0f);
  float ang = (float)s * freq;
  cs[idx] = cosf(ang);
  sn[idx] = sinf(ang);
}

__global__ void k_softmax_logits(const float* __restrict__ logits, float* __restrict__ P) {
  int t = blockIdx.x * blockDim.x + threadIdx.x;
  if (t >= NTOK) return;
  float x[V_];
  float m = -1e30f;
#pragma unroll
  for (int v = 0; v < V_; ++v) { x[v] = logits[t * V_ + v]; m = fmaxf(m, x[v]); }
  float ssum = 0.f;
#pragma unroll
  for (int v = 0; v < V_; ++v) { x[v] = expf(x[v] - m); ssum += x[v]; }
  float inv = 1.f / ssum;
#pragma unroll
  for (int v = 0; v < V_; ++v) P[t * V_ + v] = x[v] * inv;
}

__global__ void k_h0(const float* __restrict__ P, const float* __restrict__ E,
                     const int* __restrict__ inp, float* __restrict__ h0) {
  int t = blockIdx.x;
  int tid = threadIdx.x;
  __shared__ float p[V_];
  __shared__ int iw;
  if (tid < V_) p[tid] = P[t * V_ + tid];
  if (tid == 0) iw = inp[t];
  __syncthreads();
  for (int h = tid; h < H_; h += blockDim.x) {
    float acc = E[iw * H_ + h];
#pragma unroll
    for (int v = 0; v < V_; ++v) acc += p[v] * E[v * H_ + h];
    h0[(size_t)t * H_ + h] = ESCALE_ * acc;
  }
}

__global__ void k_gfill(const float* __restrict__ ew, float* __restrict__ G) {
  int idx = blockIdx.x * blockDim.x + threadIdx.x;
  if (idx < NTOK * H_) G[idx] = ew[idx & (H_ - 1)];
}

// ---------------- GEMM: C[M,N] = A @ B (+D), B optionally transposed ----------------

template <int TB, int SILU_A, int ADD>
__global__ __launch_bounds__(256) void k_gemm(const float* __restrict__ A,
                                              const float* __restrict__ Bm,
                                              const float* __restrict__ Dm,
                                              float* __restrict__ Cm,
                                              int M, int N, int K, int lda) {
  __shared__ float As[16][68];
  __shared__ float Bs[16][68];
  int tid = threadIdx.x;
  int m0 = blockIdx.y * 64, n0 = blockIdx.x * 64;
  int ty = tid >> 4, tx = tid & 15;
  float acc[4][4] = {};
  for (int k0 = 0; k0 < K; k0 += 16) {
#pragma unroll
    for (int i = tid; i < 64 * 16; i += 256) {
      int r = i >> 4, cc = i & 15;
      int gr = m0 + r;
      float v = 0.f;
      if (gr < M) {
        if (SILU_A) {
          float g = A[(size_t)gr * lda + k0 + cc];
          float u = A[(size_t)gr * lda + INNER_ + k0 + cc];
          v = (g / (1.f + expf(-g))) * u;
        } else {
          v = A[(size_t)gr * lda + k0 + cc];
        }
      }
      As[cc][r] = v;
    }
    if (TB) {
#pragma unroll
      for (int i = tid; i < 16 * 64; i += 256) {
        int r = i & 15, cc = i >> 4;
        Bs[r][cc] = Bm[(size_t)(n0 + cc) * K + k0 + r];
      }
    } else {
#pragma unroll
      for (int i = tid; i < 16 * 64; i += 256) {
        int r = i >> 6, cc = i & 63;
        Bs[r][cc] = Bm[(size_t)(k0 + r) * N + n0 + cc];
      }
    }
    __syncthreads();
#pragma unroll
    for (int kk = 0; kk < 16; ++kk) {
      float a[4], bv[4];
#pragma unroll
      for (int i = 0; i < 4; ++i) a[i] = As[kk][ty * 4 + i];
#pragma unroll
      for (int j = 0; j < 4; ++j) bv[j] = Bs[kk][tx * 4 + j];
#pragma unroll
      for (int i = 0; i < 4; ++i)
#pragma unroll
        for (int j = 0; j < 4; ++j) acc[i][j] += a[i] * bv[j];
    }
    __syncthreads();
  }
#pragma unroll
  for (int i = 0; i < 4; ++i) {
    int gr = m0 + ty * 4 + i;
    if (gr >= M) continue;
#pragma unroll
    for (int j = 0; j < 4; ++j) {
      int gc = n0 + tx * 4 + j;
      float out = acc[i][j];
      if (ADD) out += Dm[(size_t)gr * N + gc];
      Cm[(size_t)gr * N + gc] = out;
    }
  }
}

static void gemm(hipStream_t st, int tb, int silu, int add,
                 const float* A, const float* Bm, const float* Dm, float* Cm,
                 int M, int N, int K, int lda) {
  dim3 grid(N / 64, (M + 63) / 64);
  if (!tb && !silu && !add) k_gemm<0, 0, 0><<<grid, 256, 0, st>>>(A, Bm, Dm, Cm, M, N, K, lda);
  else if (!tb && !silu && add) k_gemm<0, 0, 1><<<grid, 256, 0, st>>>(A, Bm, Dm, Cm, M, N, K, lda);
  else if (!tb && silu && add) k_gemm<0, 1, 1><<<grid, 256, 0, st>>>(A, Bm, Dm, Cm, M, N, K, lda);
  else if (tb && !silu && !add) k_gemm<1, 0, 0><<<grid, 256, 0, st>>>(A, Bm, Dm, Cm, M, N, K, lda);
  else k_gemm<1, 0, 1><<<grid, 256, 0, st>>>(A, Bm, Dm, Cm, M, N, K, lda);
}

// ---------------- RoPE fwd/bwd (in place on qkv buffer, q and k channels) ----------------

template <int BWD>
__global__ void k_rope(float* __restrict__ Q, const float* __restrict__ cs,
                       const float* __restrict__ sn) {
  int idx = blockIdx.x * blockDim.x + threadIdx.x;
  if (idx >= NTOK * NH_ * 2 * 32) return;
  int i = idx & 31;
  int h = (idx >> 5) & (NH_ - 1);
  int part = (idx >> 8) & 1;
  int t = idx >> 9;
  int s = t % S_;
  float c = cs[s * 32 + i], sv = sn[s * 32 + i];
  size_t base = ((size_t)t * 3 * NH_ + part * NH_ + h) * HD_;
  float x1 = Q[base + i], x2 = Q[base + 32 + i];
  if (!BWD) {
    Q[base + i] = x1 * c - x2 * sv;
    Q[base + 32 + i] = x2 * c + x1 * sv;
  } else {
    Q[base + i] = x1 * c + x2 * sv;
    Q[base + 32 + i] = x2 * c - x1 * sv;
  }
}

// ---------------- attention v3: 4 threads per row (quarter-row each), LDS-tiled ----------------
// QKV layout: [t][3*NH][64]; Q head h at (t*24+h)*64, K at (t*24+8+h)*64, V at (t*24+16+h)*64.
// Block = 256 threads = 64 rows x 4 lanes; lanes of a row form a quad (shfl_xor 1,2).

__global__ __launch_bounds__(256) void k_attn_fwd2(const float* __restrict__ QKV,
                                                   float* __restrict__ AO,
                                                   float* __restrict__ MB,
                                                   float* __restrict__ LB) {
  __shared__ float4 Ks[64][16];
  __shared__ float4 Vs[64][16];
  int tid = threadIdx.x;
  int h = blockIdx.y, b = blockIdx.z;
  int row = tid >> 2, part = tid & 3;
  int r = blockIdx.x * 64 + row;
  int rr = r < S_ ? r : S_ - 1;
  size_t tq = (size_t)b * S_ + rr;
  const float4* qp = (const float4*)&QKV[(tq * 24 + h) * (size_t)64] + part * 4;
  float4 q4[4];
#pragma unroll
  for (int i = 0; i < 4; ++i) q4[i] = qp[i];
  float m = -1e30f, l = 0.f;
  float4 acc[4];
#pragma unroll
  for (int i = 0; i < 4; ++i) acc[i] = make_float4(0.f, 0.f, 0.f, 0.f);
  for (int kt = 0; kt < S_; kt += 64) {
    __syncthreads();
    for (int j = tid; j < 1024; j += 256) {
      int kr = j >> 4, seg = j & 15;
      int src = kt + kr;
      float4 kv = make_float4(0.f, 0.f, 0.f, 0.f), vv = kv;
      if (src < S_) {
        size_t tk = (size_t)b * S_ + src;
        kv = ((const float4*)&QKV[(tk * 24 + 8 + h) * (size_t)64])[seg];
        vv = ((const float4*)&QKV[(tk * 24 + 16 + h) * (size_t)64])[seg];
      }
      Ks[kr][seg] = kv;
      Vs[kr][seg] = vv;
    }
    __syncthreads();
    int kmax = min(64, S_ - kt);
    for (int kk = 0; kk < kmax; ++kk) {
      float s = quad_sum(dot16(q4, &Ks[kk][part * 4])) * SCALE_;
      float mn = fmaxf(m, s);
      float eo = __expf(m - mn), p = __expf(s - mn);
      l = l * eo + p;
      const float4* vr = &Vs[kk][part * 4];
#pragma unroll
      for (int i = 0; i < 4; ++i) {
        float4 v = vr[i];
        acc[i].x = acc[i].x * eo + p * v.x;
        acc[i].y = acc[i].y * eo + p * v.y;
        acc[i].z = acc[i].z * eo + p * v.z;
        acc[i].w = acc[i].w * eo + p * v.w;
      }
      m = mn;
    }
  }
  if (r < S_) {
    float linv = 1.f / l;
    float4* op = (float4*)&AO[tq * H_ + h * 64] + part * 4;
#pragma unroll
    for (int i = 0; i < 4; ++i)
      op[i] = make_float4(acc[i].x * linv, acc[i].y * linv, acc[i].z * linv, acc[i].w * linv);
    if (part == 0) {
      MB[((size_t)b * NH_ + h) * S_ + r] = m;
      LB[((size_t)b * NH_ + h) * S_ + r] = linv;
    }
  }
}

// dQ pass: quad owns q-row; delta computed locally from O,dO and saved for dK pass.
__global__ __launch_bounds__(256) void k_attn_bwd_dq(const float* __restrict__ QKV,
                                                     const float* __restrict__ O,
                                                     const float* __restrict__ dO,
                                                     const float* __restrict__ MB,
                                                     const float* __restrict__ LB,
                                                     float* __restrict__ dQKV,
                                                     float* __restrict__ DB) {
  __shared__ float4 Ks[64][16];
  __shared__ float4 Vs[64][16];
  int tid = threadIdx.x;
  int h = blockIdx.y, b = blockIdx.z;
  int row = tid >> 2, part = tid & 3;
  int r = blockIdx.x * 64 + row;
  int rr = r < S_ ? r : S_ - 1;
  size_t tq = (size_t)b * S_ + rr;
  const float4* qp = (const float4*)&QKV[(tq * 24 + h) * (size_t)64] + part * 4;
  const float4* dop = (const float4*)&dO[tq * H_ + h * 64] + part * 4;
  const float4* op = (const float4*)&O[tq * H_ + h * 64] + part * 4;
  float4 q4[4], do4[4];
  float dpart = 0.f;
#pragma unroll
  for (int i = 0; i < 4; ++i) {
    q4[i] = qp[i];
    do4[i] = dop[i];
    float4 o = op[i];
    dpart += do4[i].x * o.x + do4[i].y * o.y + do4[i].z * o.z + do4[i].w * o.w;
  }
  float delta = quad_sum(dpart);
  float m = MB[((size_t)b * NH_ + h) * S_ + rr];
  float linv = LB[((size_t)b * NH_ + h) * S_ + rr];
  float4 dq[4];
#pragma unroll
  for (int i = 0; i < 4; ++i) dq[i] = make_float4(0.f, 0.f, 0.f, 0.f);
  for (int kt = 0; kt < S_; kt += 64) {
    __syncthreads();
    for (int j = tid; j < 1024; j += 256) {
      int kr = j >> 4, seg = j & 15;
      int src = kt + kr;
      float4 kv = make_float4(0.f, 0.f, 0.f, 0.f), vv = kv;
      if (src < S_) {
        size_t tk = (size_t)b * S_ + src;
        kv = ((const float4*)&QKV[(tk * 24 + 8 + h) * (size_t)64])[seg];
        vv = ((const float4*)&QKV[(tk * 24 + 16 + h) * (size_t)64])[seg];
      }
      Ks[kr][seg] = kv;
      Vs[kr][seg] = vv;
    }
    __syncthreads();
    int kmax = min(64, S_ - kt);
    for (int kk = 0; kk < kmax; ++kk) {
      float sp = dot16(q4, &Ks[kk][part * 4]);
      float dap = dot16(do4, &Vs[kk][part * 4]);
      float s = quad_sum(sp) * SCALE_;
      float da = quad_sum(dap);
      float p = __expf(s - m) * linv;
      float t = p * (da - delta);
      const float4* kr4 = &Ks[kk][part * 4];
#pragma unroll
      for (int i = 0; i < 4; ++i) {
        float4 k4 = kr4[i];
        dq[i].x += t * k4.x; dq[i].y += t * k4.y; dq[i].z += t * k4.z; dq[i].w += t * k4.w;
      }
    }
  }
  if (r < S_) {
    float4* out = (float4*)&dQKV[(tq * 24 + h) * (size_t)64] + part * 4;
#pragma unroll
    for (int i = 0; i < 4; ++i)
      out[i] = make_float4(SCALE_ * dq[i].x, SCALE_ * dq[i].y, SCALE_ * dq[i].z, SCALE_ * dq[i].w);
    if (part == 0) DB[((size_t)b * NH_ + h) * S_ + r] = delta;
  }
}

// dV pass: quad owns k-row.
__global__ __launch_bounds__(256) void k_attn_bwd_dv(const float* __restrict__ QKV,
                                                     const float* __restrict__ dO,
                                                     const float* __restrict__ MB,
                                                     const float* __restrict__ LB,
                                                     float* __restrict__ dQKV) {
  __shared__ float4 Qs[64][16];
  __shared__ float4 dOs[64][16];
  __shared__ float sM[64], sL[64];
  int tid = threadIdx.x;
  int h = blockIdx.y, b = blockIdx.z;
  int row = tid >> 2, part = tid & 3;
  int r = blockIdx.x * 64 + row;
  int rr = r < S_ ? r : S_ - 1;
  size_t tk = (size_t)b * S_ + rr;
  const float4* kp = (const float4*)&QKV[(tk * 24 + 8 + h) * (size_t)64] + part * 4;
  float4 k4[4];
#pragma unroll
  for (int i = 0; i < 4; ++i) k4[i] = kp[i];
  float4 dv[4];
#pragma unroll
  for (int i = 0; i < 4; ++i) dv[i] = make_float4(0.f, 0.f, 0.f, 0.f);
  size_t statbase = ((size_t)b * NH_ + h) * S_;
  for (int qt = 0; qt < S_; qt += 64) {
    __syncthreads();
    for (int j = tid; j < 1024; j += 256) {
      int qr = j >> 4, seg = j & 15;
      int src = qt + qr;
      float4 qv = make_float4(0.f, 0.f, 0.f, 0.f), dv4 = qv;
      if (src < S_) {
        size_t ts = (size_t)b * S_ + src;
        qv = ((const float4*)&QKV[(ts * 24 + h) * (size_t)64])[seg];
        dv4 = ((const float4*)&dO[ts * H_ + h * 64])[seg];
      }
      Qs[qr][seg] = qv;
      dOs[qr][seg] = dv4;
    }
    if (tid < 64) {
      int src = qt + tid;
      int sc = src < S_ ? src : S_ - 1;
      sM[tid] = MB[statbase + sc];
      sL[tid] = LB[statbase + sc];
    }
    __syncthreads();
    int qmax = min(64, S_ - qt);
    for (int qq = 0; qq < qmax; ++qq) {
      float s = quad_sum(dot16(k4, &Qs[qq][part * 4])) * SCALE_;
      float p = __expf(s - sM[qq]) * sL[qq];
      const float4* dr = &dOs[qq][part * 4];
#pragma unroll
      for (int i = 0; i < 4; ++i) {
        float4 d = dr[i];
        dv[i].x += p * d.x; dv[i].y += p * d.y; dv[i].z += p * d.z; dv[i].w += p * d.w;
      }
    }
  }
  if (r < S_) {
    float4* out = (float4*)&dQKV[(tk * 24 + 16 + h) * (size_t)64] + part * 4;
#pragma unroll
    for (int i = 0; i < 4; ++i) out[i] = dv[i];
  }
}

// dK pass: quad owns k-row (needs V row + delta).
__global__ __launch_bounds__(256) void k_attn_bwd_dk(const float* __restrict__ QKV,
                                                     const float* __restrict__ dO,
                                                     const float* __restrict__ MB,
                                                     const float* __restrict__ LB,
                                                     const float* __restrict__ DB,
                                                     float* __restrict__ dQKV) {
  __shared__ float4 Qs[64][16];
  __shared__ float4 dOs[64][16];
  __shared__ float sM[64], sL[64], sD[64];
  int tid = threadIdx.x;
  int h = blockIdx.y, b = blockIdx.z;
  int row = tid >> 2, part = tid & 3;
  int r = blockIdx.x * 64 + row;
  int rr = r < S_ ? r : S_ - 1;
  size_t tk = (size_t)b * S_ + rr;
  const float4* kp = (const float4*)&QKV[(tk * 24 + 8 + h) * (size_t)64] + part * 4;
  const float4* vp = (const float4*)&QKV[(tk * 24 + 16 + h) * (size_t)64] + part * 4;
  float4 k4[4], v4[4];
#pragma unroll
  for (int i = 0; i < 4; ++i) { k4[i] = kp[i]; v4[i] = vp[i]; }
  float4 dk[4];
#pragma unroll
  for (int i = 0; i < 4; ++i) dk[i] = make_float4(0.f, 0.f, 0.f, 0.f);
  size_t statbase = ((size_t)b * NH_ + h) * S_;
  for (int qt = 0; qt < S_; qt += 64) {
    __syncthreads();
    for (int j = tid; j < 1024; j += 256) {
      int qr = j >> 4, seg = j & 15;
      int src = qt + qr;
      float4 qv = make_float4(0.f, 0.f, 0.f, 0.f), dv4 = qv;
      if (src < S_) {
        size_t ts = (size_t)b * S_ + src;
        qv = ((const float4*)&QKV[(ts * 24 + h) * (size_t)64])[seg];
        dv4 = ((const float4*)&dO[ts * H_ + h * 64])[seg];
      }
      Qs[qr][seg] = qv;
      dOs[qr][seg] = dv4;
    }
    if (tid < 64) {
      int src = qt + tid;
      int sc = src < S_ ? src : S_ - 1;
      sM[tid] = MB[statbase + sc];
      sL[tid] = LB[statbase + sc];
      sD[tid] = DB[statbase + sc];
    }
    __syncthreads();
    int qmax = min(64, S_ - qt);
    for (int qq = 0; qq < qmax; ++qq) {
      float sp = dot16(k4, &Qs[qq][part * 4]);
      float dap = dot16(v4, &dOs[qq][part * 4]);
      float s = quad_sum(sp) * SCALE_;
      float da = quad_sum(dap);
      float p = __expf(s - sM[qq]) * sL[qq];
      float t = p * (da - sD[qq]);
      const float4* qr4 = &Qs[qq][part * 4];
#pragma unroll
      for (int i = 0; i < 4; ++i) {
        float4 q = qr4[i];
        dk[i].x += t * q.x; dk[i].y += t * q.y; dk[i].z += t * q.z; dk[i].w += t * q.w;
      }
    }
  }
  if (r < S_) {
    float4* out = (float4*)&dQKV[(tk * 24 + 8 + h) * (size_t)64] + part * 4;
#pragma unroll
    for (int i = 0; i < 4; ++i)
      out[i] = make_float4(SCALE_ * dk[i].x, SCALE_ * dk[i].y, SCALE_ * dk[i].z, SCALE_ * dk[i].w);
  }
}

// ---------------- RMS norm fwd/bwd ----------------

__global__ __launch_bounds__(256) void k_rms_fwd(const float* __restrict__ X, float* __restrict__ Y) {
  int t = blockIdx.x, tid = threadIdx.x;
  float x0 = X[(size_t)t * H_ + tid], x1 = X[(size_t)t * H_ + tid + 256];
  __shared__ float red[256];
  red[tid] = x0 * x0 + x1 * x1;
  __syncthreads();
  for (int s = 128; s > 0; s >>= 1) {
    if (tid < s) red[tid] += red[tid + s];
    __syncthreads();
  }
  float r = rsqrtf(red[0] / H_ + EPS_);
  Y[(size_t)t * H_ + tid] = x0 * r;
  Y[(size_t)t * H_ + tid + 256] = x1 * r;
}

__global__ __launch_bounds__(256) void k_rms_bwd(const float* __restrict__ X,
                                                 const float* __restrict__ GY,
                                                 float* __restrict__ GX) {
  int t = blockIdx.x, tid = threadIdx.x;
  float x0 = X[(size_t)t * H_ + tid], x1 = X[(size_t)t * H_ + tid + 256];
  float g0 = GY[(size_t)t * H_ + tid], g1 = GY[(size_t)t * H_ + tid + 256];
  __shared__ float r1[256], r2[256];
  r1[tid] = x0 * x0 + x1 * x1;
  r2[tid] = x0 * g0 + x1 * g1;
  __syncthreads();
  for (int s = 128; s > 0; s >>= 1) {
    if (tid < s) { r1[tid] += r1[tid + s]; r2[tid] += r2[tid + s]; }
    __syncthreads();
  }
  float r = rsqrtf(r1[0] / H_ + EPS_);
  float coef = r * r * r * r2[0] / (float)H_;
  GX[(size_t)t * H_ + tid] = r * g0 - coef * x0;
  GX[(size_t)t * H_ + tid + 256] = r * g1 - coef * x1;
}

// ---------------- SiLU-gate backward, in place on GU ----------------

__global__ void k_silu_bwd(float* __restrict__ GU, const float* __restrict__ dact) {
  int idx = blockIdx.x * blockDim.x + threadIdx.x;
  if (idx >= NTOK * INNER_) return;
  int t = idx / INNER_, i = idx % INNER_;
  size_t gb = (size_t)t * 2 * INNER_;
  float g = GU[gb + i], u = GU[gb + INNER_ + i];
  float da = dact[idx];
  float sig = 1.f / (1.f + expf(-g));
  GU[gb + i] = da * u * sig * (1.f + g * (1.f - sig));
  GU[gb + INNER_ + i] = da * g * sig;
}

// ---------------- logits update ----------------

__global__ __launch_bounds__(64) void k_logits_update(const float* __restrict__ G,
                                                      const float* __restrict__ E,
                                                      const float* __restrict__ P,
                                                      const float* __restrict__ alpha,
                                                      float* __restrict__ logits) {
  int t = blockIdx.x, lane = threadIdx.x;
  float dp[V_];
#pragma unroll
  for (int v = 0; v < V_; ++v) dp[v] = 0.f;
  for (int hh = lane; hh < H_; hh += 64) {
    float gh = G[(size_t)t * H_ + hh];
#pragma unroll
    for (int v = 0; v < V_; ++v) dp[v] += gh * E[v * H_ + hh];
  }
#pragma unroll
  for (int v = 0; v < V_; ++v) dp[v] = wave_sum64(dp[v]) * ESCALE_;
  float dot = 0.f;
  float pv[V_];
#pragma unroll
  for (int v = 0; v < V_; ++v) {
    pv[v] = P[t * V_ + v];
    dot += pv[v] * dp[v];
  }
  float a = fmaxf(alpha[0], 1e-4f);
  if (lane < V_) logits[t * V_ + lane] -= a * pv[lane] * (dp[lane] - dot);
}

// ---------------- host-side orchestration ----------------
// Aliasing: dQ == ACT; U == DX == H1 (UDX). dO lives in X2 during attn bwd (X2 dead there).

struct Ctx {
  float *Q, *dQ, *GU, *ACT, *X1, *X2, *AO, *G, *UDX, *H0, *P, *MB, *LB, *DB, *CS, *SN;
  hipStream_t st;
};

static void block_forward(Ctx& c, const float* hin, float* hout,
                          const float* wqkv, const float* wo, const float* wgu, const float* wd) {
  gemm(c.st, 0, 0, 0, hin, wqkv, nullptr, c.Q, NTOK, 3 * H_, H_, H_);
  k_rope<0><<<(NTOK * NH_ * 2 * 32 + 255) / 256, 256, 0, c.st>>>(c.Q, c.CS, c.SN);
  k_attn_fwd2<<<dim3((S_ + 63) / 64, NH_, B_), 256, 0, c.st>>>(c.Q, c.AO, c.MB, c.LB);
  gemm(c.st, 0, 0, 1, c.AO, wo, hin, c.X1, NTOK, H_, H_, H_);
  k_rms_fwd<<<NTOK, 256, 0, c.st>>>(c.X1, c.UDX);
  gemm(c.st, 0, 0, 0, c.UDX, wgu, nullptr, c.GU, NTOK, 2 * INNER_, H_, H_);
  gemm(c.st, 0, 1, 1, c.GU, wd, c.UDX, c.X2, NTOK, H_, INNER_, 2 * INNER_);
  if (hout) k_rms_fwd<<<NTOK, 256, 0, c.st>>>(c.X2, hout);
}

static void block_backward(Ctx& c, const float* hin,
                           const float* wqkv, const float* wo, const float* wgu, const float* wd) {
  block_forward(c, hin, nullptr, wqkv, wo, wgu, wd);
  k_rms_bwd<<<NTOK, 256, 0, c.st>>>(c.X2, c.G, c.UDX);
  gemm(c.st, 1, 0, 0, c.UDX, wd, nullptr, c.ACT, NTOK, INNER_, H_, H_);
  k_silu_bwd<<<(NTOK * INNER_ + 255) / 256, 256, 0, c.st>>>(c.GU, c.ACT);
  gemm(c.st, 1, 0, 1, c.GU, wgu, c.UDX, c.G, NTOK, H_, 2 * INNER_, 2 * INNER_);
  k_rms_bwd<<<NTOK, 256, 0, c.st>>>(c.X1, c.G, c.UDX);
  // d_attn_out -> X2 (X2 dead; AO must survive as O for the delta trick)
  gemm(c.st, 1, 0, 0, c.UDX, wo, nullptr, c.X2, NTOK, H_, H_, H_);
  dim3 agrid((S_ + 63) / 64, NH_, B_);
  k_attn_bwd_dq<<<agrid, 256, 0, c.st>>>(c.Q, c.AO, c.X2, c.MB, c.LB, c.dQ, c.DB);
  k_attn_bwd_dv<<<agrid, 256, 0, c.st>>>(c.Q, c.X2, c.MB, c.LB, c.dQ);
  k_attn_bwd_dk<<<agrid, 256, 0, c.st>>>(c.Q, c.X2, c.MB, c.LB, c.DB, c.dQ);
  k_rope<1><<<(NTOK * NH_ * 2 * 32 + 255) / 256, 256, 0, c.st>>>(c.dQ, c.CS, c.SN);
  gemm(c.st, 1, 0, 1, c.dQ, wqkv, c.UDX, c.G, NTOK, H_, 3 * H_, 3 * H_);
}

extern "C" void kernel_launch(void* const* d_in, const int* in_sizes, int n_in,
                              void* d_out, int out_size, void* d_ws, size_t ws_size,
                              hipStream_t stream) {
  const int* inputs = (const int*)d_in[0];
  const float* E = (const float*)d_in[2];
  const float* ew = (const float*)d_in[3];
  const float* qkvw = (const float*)d_in[4];
  const float* ow = (const float*)d_in[5];
  const float* guw = (const float*)d_in[6];
  const float* dw = (const float*)d_in[7];
  const float* alpha = (const float*)d_in[8];
  float* logits = (float*)d_out;

  const size_t NEED =
      ((size_t)NTOK * 3 * H_) +      // Q
      ((size_t)NTOK * 2 * INNER_) +  // GU
      ((size_t)NTOK * 3 * H_) +      // dQ/ACT
      6 * ((size_t)NTOK * H_) +      // X1, X2, AO, G, UDX, H0
      ((size_t)NTOK * V_) +          // P
      3 * ((size_t)B_ * NH_ * S_) +  // MB, LB, DB
      2 * ((size_t)S_ * 32);         // CS, SN
  if (ws_size < NEED * sizeof(float)) {
    k_zero<<<(NTOK * V_ + 255) / 256, 256, 0, stream>>>(logits, NTOK * V_);
    return;
  }

  float* f = (float*)d_ws;
  Ctx c;
  c.st = stream;
  c.Q = f;    f += (size_t)NTOK * 3 * H_;
  c.GU = f;   f += (size_t)NTOK * 2 * INNER_;
  c.dQ = f;   c.ACT = f;  f += (size_t)NTOK * 3 * H_;
  c.X1 = f;   f += (size_t)NTOK * H_;
  c.X2 = f;   f += (size_t)NTOK * H_;
  c.AO = f;   f += (size_t)NTOK * H_;
  c.G = f;    f += (size_t)NTOK * H_;
  c.UDX = f;  f += (size_t)NTOK * H_;
  c.H0 = f;   f += (size_t)NTOK * H_;
  c.P = f;    f += (size_t)NTOK * V_;
  c.MB = f;   f += (size_t)B_ * NH_ * S_;
  c.LB = f;   f += (size_t)B_ * NH_ * S_;
  c.DB = f;   f += (size_t)B_ * NH_ * S_;
  c.CS = f;   f += (size_t)S_ * 32;
  c.SN = f;   f += (size_t)S_ * 32;

  const size_t LQKV = (size_t)H_ * 3 * H_;
  const size_t LO = (size_t)H_ * H_;
  const size_t LGU = (size_t)H_ * 2 * INNER_;
  const size_t LD = (size_t)INNER_ * H_;

  k_zero<<<(NTOK * V_ + 255) / 256, 256, 0, stream>>>(logits, NTOK * V_);
  k_rope_tables<<<(S_ * 32 + 255) / 256, 256, 0, stream>>>(c.CS, c.SN);

  for (int step = 0; step < STEPS_; ++step) {
    k_softmax_logits<<<(NTOK + 255) / 256, 256, 0, stream>>>(logits, c.P);
    k_h0<<<NTOK, 256, 0, stream>>>(c.P, E, inputs, c.H0);
    block_forward(c, c.H0, c.UDX, qkvw, ow, guw, dw);
    k_gfill<<<(NTOK * H_ + 255) / 256, 256, 0, stream>>>(ew, c.G);
    block_backward(c, c.UDX, qkvw + LQKV, ow + LO, guw + LGU, dw + LD);
    block_backward(c, c.H0, qkvw, ow, guw, dw);
    k_logits_update<<<NTOK, 64, 0, stream>>>(c.G, E, c.P, alpha, logits);
  }
}

// Round 5
// 11722.047 us; speedup vs baseline: 7.4800x; 1.5846x over previous
//
#include <hip/hip_runtime.h>
#include <math.h>

#define B_ 8
#define S_ 900
#define V_ 11
#define H_ 512
#define NH_ 8
#define HD_ 64
#define INNER_ 1536
#define STEPS_ 2
#define NTOK (B_*S_)
#define EPS_ 1e-5f
#define THETA_ 10000.0f
#define ESCALE_ 22.627416997969522f
#define SCALE_ 0.125f

typedef __attribute__((ext_vector_type(8))) short bh8;
typedef __attribute__((ext_vector_type(4))) float f32x4;

__device__ inline unsigned short f2bf(float x) {
  unsigned u = __builtin_bit_cast(unsigned, x);
  return (unsigned short)((u + 0x7FFFu + ((u >> 16) & 1u)) >> 16);
}

__device__ inline float wave_sum64(float x) {
#pragma unroll
  for (int off = 32; off > 0; off >>= 1) x += __shfl_xor(x, off, 64);
  return x;
}

__device__ inline float dot16(const float4* a, const float4* b) {
  float s = 0.f;
#pragma unroll
  for (int i = 0; i < 4; ++i) {
    float4 x = a[i], y = b[i];
    s += x.x * y.x + x.y * y.y + x.z * y.z + x.w * y.w;
  }
  return s;
}

__device__ inline float quad_sum(float x) {
  x += __shfl_xor(x, 1, 64);
  x += __shfl_xor(x, 2, 64);
  return x;
}

// ---------------- small kernels ----------------

__global__ void k_zero(float* p, int n) {
  int i = blockIdx.x * blockDim.x + threadIdx.x;
  if (i < n) p[i] = 0.f;
}

__global__ void k_rope_tables(float* cs, float* sn) {
  int idx = blockIdx.x * blockDim.x + threadIdx.x;
  if (idx >= S_ * 32) return;
  int s = idx >> 5, i = idx & 31;
  float freq = powf(THETA_, -(float)i / 32.0f);
  float ang = (float)s * freq;
  cs[idx] = cosf(ang);
  sn[idx] = sinf(ang);
}

__global__ void k_softmax_logits(const float* __restrict__ logits, float* __restrict__ P) {
  int t = blockIdx.x * blockDim.x + threadIdx.x;
  if (t >= NTOK) return;
  float x[V_];
  float m = -1e30f;
#pragma unroll
  for (int v = 0; v < V_; ++v) { x[v] = logits[t * V_ + v]; m = fmaxf(m, x[v]); }
  float ssum = 0.f;
#pragma unroll
  for (int v = 0; v < V_; ++v) { x[v] = expf(x[v] - m); ssum += x[v]; }
  float inv = 1.f / ssum;
#pragma unroll
  for (int v = 0; v < V_; ++v) P[t * V_ + v] = x[v] * inv;
}

__global__ void k_h0(const float* __restrict__ P, const float* __restrict__ E,
                     const int* __restrict__ inp, float* __restrict__ h0) {
  int t = blockIdx.x;
  int tid = threadIdx.x;
  __shared__ float p[V_];
  __shared__ int iw;
  if (tid < V_) p[tid] = P[t * V_ + tid];
  if (tid == 0) iw = inp[t];
  __syncthreads();
  for (int h = tid; h < H_; h += blockDim.x) {
    float acc = E[iw * H_ + h];
#pragma unroll
    for (int v = 0; v < V_; ++v) acc += p[v] * E[v * H_ + h];
    h0[(size_t)t * H_ + h] = ESCALE_ * acc;
  }
}

__global__ void k_gfill(const float* __restrict__ ew, float* __restrict__ G) {
  int idx = blockIdx.x * blockDim.x + threadIdx.x;
  if (idx < NTOK * H_) G[idx] = ew[idx & (H_ - 1)];
}

// ---------------- weight transpose-convert: W[K][N] fp32 -> WT[N][K] bf16 ----------------
// K, N multiples of 32.

__global__ void k_wt(const float* __restrict__ W, unsigned short* __restrict__ WT, int K, int N) {
  __shared__ float t[32][33];
  int k0 = blockIdx.y * 32, n0 = blockIdx.x * 32;
  int tx = threadIdx.x, ty = threadIdx.y;  // 32 x 8
#pragma unroll
  for (int i = 0; i < 4; ++i)
    t[ty + 8 * i][tx] = W[(size_t)(k0 + ty + 8 * i) * N + n0 + tx];
  __syncthreads();
#pragma unroll
  for (int i = 0; i < 4; ++i)
    WT[(size_t)(n0 + ty + 8 * i) * K + k0 + tx] = f2bf(t[tx][ty + 8 * i]);
}

// ---------------- MFMA GEMM: C[M,N] = A[M,K] @ B^T where B stored [N][K] ----------------
// BSRC=0: B fp32 [N][K] (backward, weight as stored). BSRC=1: B bf16 [N][K] (pre-transposed).
// SILU_A: A rows are silu(gate)*up from GU (lda = 2*INNER_, gate at k, up at k+INNER_).
// ADD: C = acc + D.
// Tile 128x128, BK=32, 4 waves (2x2), wave = 64x64 = 4x4 frags of 16x16x32.

template <int BSRC, int SILU_A, int ADD>
__global__ __launch_bounds__(256) void k_gemm(const float* __restrict__ A,
                                              const float* __restrict__ Bf,
                                              const unsigned short* __restrict__ Bt,
                                              const float* __restrict__ Dm,
                                              float* __restrict__ Cm,
                                              int M, int N, int K, int lda) {
  __shared__ unsigned short As[128][40];  // pitch 80B = 5*16B: aligned b128, bank-stride 20 (2-way = free)
  __shared__ unsigned short Bs[128][40];
  int tid = threadIdx.x;
  int m0 = blockIdx.y * 128, n0 = blockIdx.x * 128;
  int wid = tid >> 6, lane = tid & 63;
  int wr = (wid >> 1) * 64, wc = (wid & 1) * 64;
  int lr = lane & 15, lg = lane >> 4;
  f32x4 acc[4][4] = {};
  for (int k0 = 0; k0 < K; k0 += 32) {
    __syncthreads();
#pragma unroll
    for (int i = 0; i < 2; ++i) {
      int cidx = tid + 256 * i;          // 0..511
      int row = cidx >> 2, ck = (cidx & 3) * 8;
      int gr = m0 + row; gr = gr < M ? gr : M - 1;
      const float* src = &A[(size_t)gr * lda + k0 + ck];
      union { bh8 v; unsigned short s[8]; } pa;
      if (SILU_A) {
#pragma unroll
        for (int j = 0; j < 8; ++j) {
          float g = src[j], u = src[INNER_ + j];
          pa.s[j] = f2bf((g / (1.f + __expf(-g))) * u);
        }
      } else {
#pragma unroll
        for (int j = 0; j < 8; ++j) pa.s[j] = f2bf(src[j]);
      }
      *(bh8*)&As[row][ck] = pa.v;
      if (BSRC == 0) {
        const float* bs = &Bf[(size_t)(n0 + row) * K + k0 + ck];
        union { bh8 v; unsigned short s[8]; } pb;
#pragma unroll
        for (int j = 0; j < 8; ++j) pb.s[j] = f2bf(bs[j]);
        *(bh8*)&Bs[row][ck] = pb.v;
      } else {
        *(bh8*)&Bs[row][ck] = *(const bh8*)&Bt[(size_t)(n0 + row) * K + k0 + ck];
      }
    }
    __syncthreads();
    bh8 av[4], bv[4];
#pragma unroll
    for (int f = 0; f < 4; ++f) {
      av[f] = *(const bh8*)&As[wr + f * 16 + lr][lg * 8];
      bv[f] = *(const bh8*)&Bs[wc + f * 16 + lr][lg * 8];
    }
#pragma unroll
    for (int fr = 0; fr < 4; ++fr)
#pragma unroll
      for (int fc = 0; fc < 4; ++fc)
        acc[fr][fc] = __builtin_amdgcn_mfma_f32_16x16x32_bf16(av[fr], bv[fc], acc[fr][fc], 0, 0, 0);
  }
#pragma unroll
  for (int fr = 0; fr < 4; ++fr) {
    int r0 = m0 + wr + fr * 16 + lg * 4;
#pragma unroll
    for (int i = 0; i < 4; ++i) {
      int gr = r0 + i;
      if (gr >= M) continue;
#pragma unroll
      for (int fc = 0; fc < 4; ++fc) {
        int gc = n0 + wc + fc * 16 + lr;
        float out = acc[fr][fc][i];
        if (ADD) out += Dm[(size_t)gr * N + gc];
        Cm[(size_t)gr * N + gc] = out;
      }
    }
  }
}

static void gemm(hipStream_t st, int bsrc, int silu, int add,
                 const float* A, const float* Bf, const unsigned short* Bt,
                 const float* Dm, float* Cm, int M, int N, int K, int lda) {
  dim3 grid(N / 128, (M + 127) / 128);
  if (bsrc == 1 && !silu && !add) k_gemm<1, 0, 0><<<grid, 256, 0, st>>>(A, Bf, Bt, Dm, Cm, M, N, K, lda);
  else if (bsrc == 1 && !silu && add) k_gemm<1, 0, 1><<<grid, 256, 0, st>>>(A, Bf, Bt, Dm, Cm, M, N, K, lda);
  else if (bsrc == 1 && silu && add) k_gemm<1, 1, 1><<<grid, 256, 0, st>>>(A, Bf, Bt, Dm, Cm, M, N, K, lda);
  else if (bsrc == 0 && !silu && !add) k_gemm<0, 0, 0><<<grid, 256, 0, st>>>(A, Bf, Bt, Dm, Cm, M, N, K, lda);
  else k_gemm<0, 0, 1><<<grid, 256, 0, st>>>(A, Bf, Bt, Dm, Cm, M, N, K, lda);
}

// ---------------- RoPE fwd/bwd (in place on qkv buffer, q and k channels) ----------------

template <int BWD>
__global__ void k_rope(float* __restrict__ Q, const float* __restrict__ cs,
                       const float* __restrict__ sn) {
  int idx = blockIdx.x * blockDim.x + threadIdx.x;
  if (idx >= NTOK * NH_ * 2 * 32) return;
  int i = idx & 31;
  int h = (idx >> 5) & (NH_ - 1);
  int part = (idx >> 8) & 1;
  int t = idx >> 9;
  int s = t % S_;
  float c = cs[s * 32 + i], sv = sn[s * 32 + i];
  size_t base = ((size_t)t * 3 * NH_ + part * NH_ + h) * HD_;
  float x1 = Q[base + i], x2 = Q[base + 32 + i];
  if (!BWD) {
    Q[base + i] = x1 * c - x2 * sv;
    Q[base + 32 + i] = x2 * c + x1 * sv;
  } else {
    Q[base + i] = x1 * c + x2 * sv;
    Q[base + 32 + i] = x2 * c - x1 * sv;
  }
}

// ---------------- attention: 4 threads per row (quarter-row each), LDS-tiled ----------------
// QKV layout: [t][3*NH][64]; Q head h at (t*24+h)*64, K at (t*24+8+h)*64, V at (t*24+16+h)*64.

__global__ __launch_bounds__(256) void k_attn_fwd2(const float* __restrict__ QKV,
                                                   float* __restrict__ AO,
                                                   float* __restrict__ MB,
                                                   float* __restrict__ LB) {
  __shared__ float4 Ks[64][16];
  __shared__ float4 Vs[64][16];
  int tid = threadIdx.x;
  int h = blockIdx.y, b = blockIdx.z;
  int row = tid >> 2, part = tid & 3;
  int r = blockIdx.x * 64 + row;
  int rr = r < S_ ? r : S_ - 1;
  size_t tq = (size_t)b * S_ + rr;
  const float4* qp = (const float4*)&QKV[(tq * 24 + h) * (size_t)64] + part * 4;
  float4 q4[4];
#pragma unroll
  for (int i = 0; i < 4; ++i) q4[i] = qp[i];
  float m = -1e30f, l = 0.f;
  float4 acc[4];
#pragma unroll
  for (int i = 0; i < 4; ++i) acc[i] = make_float4(0.f, 0.f, 0.f, 0.f);
  for (int kt = 0; kt < S_; kt += 64) {
    __syncthreads();
    for (int j = tid; j < 1024; j += 256) {
      int kr = j >> 4, seg = j & 15;
      int src = kt + kr;
      float4 kv = make_float4(0.f, 0.f, 0.f, 0.f), vv = kv;
      if (src < S_) {
        size_t tk = (size_t)b * S_ + src;
        kv = ((const float4*)&QKV[(tk * 24 + 8 + h) * (size_t)64])[seg];
        vv = ((const float4*)&QKV[(tk * 24 + 16 + h) * (size_t)64])[seg];
      }
      Ks[kr][seg] = kv;
      Vs[kr][seg] = vv;
    }
    __syncthreads();
    int kmax = min(64, S_ - kt);
    for (int kk = 0; kk < kmax; ++kk) {
      float s = quad_sum(dot16(q4, &Ks[kk][part * 4])) * SCALE_;
      float mn = fmaxf(m, s);
      float eo = __expf(m - mn), p = __expf(s - mn);
      l = l * eo + p;
      const float4* vr = &Vs[kk][part * 4];
#pragma unroll
      for (int i = 0; i < 4; ++i) {
        float4 v = vr[i];
        acc[i].x = acc[i].x * eo + p * v.x;
        acc[i].y = acc[i].y * eo + p * v.y;
        acc[i].z = acc[i].z * eo + p * v.z;
        acc[i].w = acc[i].w * eo + p * v.w;
      }
      m = mn;
    }
  }
  if (r < S_) {
    float linv = 1.f / l;
    float4* op = (float4*)&AO[tq * H_ + h * 64] + part * 4;
#pragma unroll
    for (int i = 0; i < 4; ++i)
      op[i] = make_float4(acc[i].x * linv, acc[i].y * linv, acc[i].z * linv, acc[i].w * linv);
    if (part == 0) {
      MB[((size_t)b * NH_ + h) * S_ + r] = m;
      LB[((size_t)b * NH_ + h) * S_ + r] = linv;
    }
  }
}

__global__ __launch_bounds__(256) void k_attn_bwd_dq(const float* __restrict__ QKV,
                                                     const float* __restrict__ O,
                                                     const float* __restrict__ dO,
                                                     const float* __restrict__ MB,
                                                     const float* __restrict__ LB,
                                                     float* __restrict__ dQKV,
                                                     float* __restrict__ DB) {
  __shared__ float4 Ks[64][16];
  __shared__ float4 Vs[64][16];
  int tid = threadIdx.x;
  int h = blockIdx.y, b = blockIdx.z;
  int row = tid >> 2, part = tid & 3;
  int r = blockIdx.x * 64 + row;
  int rr = r < S_ ? r : S_ - 1;
  size_t tq = (size_t)b * S_ + rr;
  const float4* qp = (const float4*)&QKV[(tq * 24 + h) * (size_t)64] + part * 4;
  const float4* dop = (const float4*)&dO[tq * H_ + h * 64] + part * 4;
  const float4* op = (const float4*)&O[tq * H_ + h * 64] + part * 4;
  float4 q4[4], do4[4];
  float dpart = 0.f;
#pragma unroll
  for (int i = 0; i < 4; ++i) {
    q4[i] = qp[i];
    do4[i] = dop[i];
    float4 o = op[i];
    dpart += do4[i].x * o.x + do4[i].y * o.y + do4[i].z * o.z + do4[i].w * o.w;
  }
  float delta = quad_sum(dpart);
  float m = MB[((size_t)b * NH_ + h) * S_ + rr];
  float linv = LB[((size_t)b * NH_ + h) * S_ + rr];
  float4 dq[4];
#pragma unroll
  for (int i = 0; i < 4; ++i) dq[i] = make_float4(0.f, 0.f, 0.f, 0.f);
  for (int kt = 0; kt < S_; kt += 64) {
    __syncthreads();
    for (int j = tid; j < 1024; j += 256) {
      int kr = j >> 4, seg = j & 15;
      int src = kt + kr;
      float4 kv = make_float4(0.f, 0.f, 0.f, 0.f), vv = kv;
      if (src < S_) {
        size_t tk = (size_t)b * S_ + src;
        kv = ((const float4*)&QKV[(tk * 24 + 8 + h) * (size_t)64])[seg];
        vv = ((const float4*)&QKV[(tk * 24 + 16 + h) * (size_t)64])[seg];
      }
      Ks[kr][seg] = kv;
      Vs[kr][seg] = vv;
    }
    __syncthreads();
    int kmax = min(64, S_ - kt);
    for (int kk = 0; kk < kmax; ++kk) {
      float sp = dot16(q4, &Ks[kk][part * 4]);
      float dap = dot16(do4, &Vs[kk][part * 4]);
      float s = quad_sum(sp) * SCALE_;
      float da = quad_sum(dap);
      float p = __expf(s - m) * linv;
      float t = p * (da - delta);
      const float4* kr4 = &Ks[kk][part * 4];
#pragma unroll
      for (int i = 0; i < 4; ++i) {
        float4 k4 = kr4[i];
        dq[i].x += t * k4.x; dq[i].y += t * k4.y; dq[i].z += t * k4.z; dq[i].w += t * k4.w;
      }
    }
  }
  if (r < S_) {
    float4* out = (float4*)&dQKV[(tq * 24 + h) * (size_t)64] + part * 4;
#pragma unroll
    for (int i = 0; i < 4; ++i)
      out[i] = make_float4(SCALE_ * dq[i].x, SCALE_ * dq[i].y, SCALE_ * dq[i].z, SCALE_ * dq[i].w);
    if (part == 0) DB[((size_t)b * NH_ + h) * S_ + r] = delta;
  }
}

__global__ __launch_bounds__(256) void k_attn_bwd_dv(const float* __restrict__ QKV,
                                                     const float* __restrict__ dO,
                                                     const float* __restrict__ MB,
                                                     const float* __restrict__ LB,
                                                     float* __restrict__ dQKV) {
  __shared__ float4 Qs[64][16];
  __shared__ float4 dOs[64][16];
  __shared__ float sM[64], sL[64];
  int tid = threadIdx.x;
  int h = blockIdx.y, b = blockIdx.z;
  int row = tid >> 2, part = tid & 3;
  int r = blockIdx.x * 64 + row;
  int rr = r < S_ ? r : S_ - 1;
  size_t tk = (size_t)b * S_ + rr;
  const float4* kp = (const float4*)&QKV[(tk * 24 + 8 + h) * (size_t)64] + part * 4;
  float4 k4[4];
#pragma unroll
  for (int i = 0; i < 4; ++i) k4[i] = kp[i];
  float4 dv[4];
#pragma unroll
  for (int i = 0; i < 4; ++i) dv[i] = make_float4(0.f, 0.f, 0.f, 0.f);
  size_t statbase = ((size_t)b * NH_ + h) * S_;
  for (int qt = 0; qt < S_; qt += 64) {
    __syncthreads();
    for (int j = tid; j < 1024; j += 256) {
      int qr = j >> 4, seg = j & 15;
      int src = qt + qr;
      float4 qv = make_float4(0.f, 0.f, 0.f, 0.f), dv4 = qv;
      if (src < S_) {
        size_t ts = (size_t)b * S_ + src;
        qv = ((const float4*)&QKV[(ts * 24 + h) * (size_t)64])[seg];
        dv4 = ((const float4*)&dO[ts * H_ + h * 64])[seg];
      }
      Qs[qr][seg] = qv;
      dOs[qr][seg] = dv4;
    }
    if (tid < 64) {
      int src = qt + tid;
      int sc = src < S_ ? src : S_ - 1;
      sM[tid] = MB[statbase + sc];
      sL[tid] = LB[statbase + sc];
    }
    __syncthreads();
    int qmax = min(64, S_ - qt);
    for (int qq = 0; qq < qmax; ++qq) {
      float s = quad_sum(dot16(k4, &Qs[qq][part * 4])) * SCALE_;
      float p = __expf(s - sM[qq]) * sL[qq];
      const float4* dr = &dOs[qq][part * 4];
#pragma unroll
      for (int i = 0; i < 4; ++i) {
        float4 d = dr[i];
        dv[i].x += p * d.x; dv[i].y += p * d.y; dv[i].z += p * d.z; dv[i].w += p * d.w;
      }
    }
  }
  if (r < S_) {
    float4* out = (float4*)&dQKV[(tk * 24 + 16 + h) * (size_t)64] + part * 4;
#pragma unroll
    for (int i = 0; i < 4; ++i) out[i] = dv[i];
  }
}

__global__ __launch_bounds__(256) void k_attn_bwd_dk(const float* __restrict__ QKV,
                                                     const float* __restrict__ dO,
                                                     const float* __restrict__ MB,
                                                     const float* __restrict__ LB,
                                                     const float* __restrict__ DB,
                                                     float* __restrict__ dQKV) {
  __shared__ float4 Qs[64][16];
  __shared__ float4 dOs[64][16];
  __shared__ float sM[64], sL[64], sD[64];
  int tid = threadIdx.x;
  int h = blockIdx.y, b = blockIdx.z;
  int row = tid >> 2, part = tid & 3;
  int r = blockIdx.x * 64 + row;
  int rr = r < S_ ? r : S_ - 1;
  size_t tk = (size_t)b * S_ + rr;
  const float4* kp = (const float4*)&QKV[(tk * 24 + 8 + h) * (size_t)64] + part * 4;
  const float4* vp = (const float4*)&QKV[(tk * 24 + 16 + h) * (size_t)64] + part * 4;
  float4 k4[4], v4[4];
#pragma unroll
  for (int i = 0; i < 4; ++i) { k4[i] = kp[i]; v4[i] = vp[i]; }
  float4 dk[4];
#pragma unroll
  for (int i = 0; i < 4; ++i) dk[i] = make_float4(0.f, 0.f, 0.f, 0.f);
  size_t statbase = ((size_t)b * NH_ + h) * S_;
  for (int qt = 0; qt < S_; qt += 64) {
    __syncthreads();
    for (int j = tid; j < 1024; j += 256) {
      int qr = j >> 4, seg = j & 15;
      int src = qt + qr;
      float4 qv = make_float4(0.f, 0.f, 0.f, 0.f), dv4 = qv;
      if (src < S_) {
        size_t ts = (size_t)b * S_ + src;
        qv = ((const float4*)&QKV[(ts * 24 + h) * (size_t)64])[seg];
        dv4 = ((const float4*)&dO[ts * H_ + h * 64])[seg];
      }
      Qs[qr][seg] = qv;
      dOs[qr][seg] = dv4;
    }
    if (tid < 64) {
      int src = qt + tid;
      int sc = src < S_ ? src : S_ - 1;
      sM[tid] = MB[statbase + sc];
      sL[tid] = LB[statbase + sc];
      sD[tid] = DB[statbase + sc];
    }
    __syncthreads();
    int qmax = min(64, S_ - qt);
    for (int qq = 0; qq < qmax; ++qq) {
      float sp = dot16(k4, &Qs[qq][part * 4]);
      float dap = dot16(v4, &dOs[qq][part * 4]);
      float s = quad_sum(sp) * SCALE_;
      float da = quad_sum(dap);
      float p = __expf(s - sM[qq]) * sL[qq];
      float t = p * (da - sD[qq]);
      const float4* qr4 = &Qs[qq][part * 4];
#pragma unroll
      for (int i = 0; i < 4; ++i) {
        float4 q = qr4[i];
        dk[i].x += t * q.x; dk[i].y += t * q.y; dk[i].z += t * q.z; dk[i].w += t * q.w;
      }
    }
  }
  if (r < S_) {
    float4* out = (float4*)&dQKV[(tk * 24 + 8 + h) * (size_t)64] + part * 4;
#pragma unroll
    for (int i = 0; i < 4; ++i)
      out[i] = make_float4(SCALE_ * dk[i].x, SCALE_ * dk[i].y, SCALE_ * dk[i].z, SCALE_ * dk[i].w);
  }
}

// ---------------- RMS norm fwd/bwd ----------------

__global__ __launch_bounds__(256) void k_rms_fwd(const float* __restrict__ X, float* __restrict__ Y) {
  int t = blockIdx.x, tid = threadIdx.x;
  float x0 = X[(size_t)t * H_ + tid], x1 = X[(size_t)t * H_ + tid + 256];
  __shared__ float red[256];
  red[tid] = x0 * x0 + x1 * x1;
  __syncthreads();
  for (int s = 128; s > 0; s >>= 1) {
    if (tid < s) red[tid] += red[tid + s];
    __syncthreads();
  }
  float r = rsqrtf(red[0] / H_ + EPS_);
  Y[(size_t)t * H_ + tid] = x0 * r;
  Y[(size_t)t * H_ + tid + 256] = x1 * r;
}

__global__ __launch_bounds__(256) void k_rms_bwd(const float* __restrict__ X,
                                                 const float* __restrict__ GY,
                                                 float* __restrict__ GX) {
  int t = blockIdx.x, tid = threadIdx.x;
  float x0 = X[(size_t)t * H_ + tid], x1 = X[(size_t)t * H_ + tid + 256];
  float g0 = GY[(size_t)t * H_ + tid], g1 = GY[(size_t)t * H_ + tid + 256];
  __shared__ float r1[256], r2[256];
  r1[tid] = x0 * x0 + x1 * x1;
  r2[tid] = x0 * g0 + x1 * g1;
  __syncthreads();
  for (int s = 128; s > 0; s >>= 1) {
    if (tid < s) { r1[tid] += r1[tid + s]; r2[tid] += r2[tid + s]; }
    __syncthreads();
  }
  float r = rsqrtf(r1[0] / H_ + EPS_);
  float coef = r * r * r * r2[0] / (float)H_;
  GX[(size_t)t * H_ + tid] = r * g0 - coef * x0;
  GX[(size_t)t * H_ + tid + 256] = r * g1 - coef * x1;
}

// ---------------- SiLU-gate backward, in place on GU ----------------

__global__ void k_silu_bwd(float* __restrict__ GU, const float* __restrict__ dact) {
  int idx = blockIdx.x * blockDim.x + threadIdx.x;
  if (idx >= NTOK * INNER_) return;
  int t = idx / INNER_, i = idx % INNER_;
  size_t gb = (size_t)t * 2 * INNER_;
  float g = GU[gb + i], u = GU[gb + INNER_ + i];
  float da = dact[idx];
  float sig = 1.f / (1.f + expf(-g));
  GU[gb + i] = da * u * sig * (1.f + g * (1.f - sig));
  GU[gb + INNER_ + i] = da * g * sig;
}

// ---------------- logits update ----------------

__global__ __launch_bounds__(64) void k_logits_update(const float* __restrict__ G,
                                                      const float* __restrict__ E,
                                                      const float* __restrict__ P,
                                                      const float* __restrict__ alpha,
                                                      float* __restrict__ logits) {
  int t = blockIdx.x, lane = threadIdx.x;
  float dp[V_];
#pragma unroll
  for (int v = 0; v < V_; ++v) dp[v] = 0.f;
  for (int hh = lane; hh < H_; hh += 64) {
    float gh = G[(size_t)t * H_ + hh];
#pragma unroll
    for (int v = 0; v < V_; ++v) dp[v] += gh * E[v * H_ + hh];
  }
#pragma unroll
  for (int v = 0; v < V_; ++v) dp[v] = wave_sum64(dp[v]) * ESCALE_;
  float dot = 0.f;
  float pv[V_];
#pragma unroll
  for (int v = 0; v < V_; ++v) {
    pv[v] = P[t * V_ + v];
    dot += pv[v] * dp[v];
  }
  float a = fmaxf(alpha[0], 1e-4f);
  if (lane < V_) logits[t * V_ + lane] -= a * pv[lane] * (dp[lane] - dot);
}

// ---------------- host-side orchestration ----------------
// Aliasing: dQ == ACT; U == DX == H1 (UDX); h0 lives in X1 (recomputed on demand by k_h0).
// dO lives in X2 during attn bwd (X2 dead there); O (AO) survives for the delta trick.

struct Ctx {
  float *Q, *dQ, *GU, *ACT, *X1, *X2, *AO, *G, *UDX, *P, *MB, *LB, *DB, *CS, *SN;
  const unsigned short *WTqkv[2], *WTo[2], *WTgu[2], *WTd[2];
  hipStream_t st;
};

static void block_forward(Ctx& c, int l, const float* hin, float* hout,
                          const float* wqkv, const float* wo, const float* wgu, const float* wd) {
  gemm(c.st, 1, 0, 0, hin, nullptr, c.WTqkv[l], nullptr, c.Q, NTOK, 3 * H_, H_, H_);
  k_rope<0><<<(NTOK * NH_ * 2 * 32 + 255) / 256, 256, 0, c.st>>>(c.Q, c.CS, c.SN);
  k_attn_fwd2<<<dim3((S_ + 63) / 64, NH_, B_), 256, 0, c.st>>>(c.Q, c.AO, c.MB, c.LB);
  gemm(c.st, 1, 0, 1, c.AO, nullptr, c.WTo[l], hin, c.X1, NTOK, H_, H_, H_);  // in-place safe if hin==X1
  k_rms_fwd<<<NTOK, 256, 0, c.st>>>(c.X1, c.UDX);
  gemm(c.st, 1, 0, 0, c.UDX, nullptr, c.WTgu[l], nullptr, c.GU, NTOK, 2 * INNER_, H_, H_);
  gemm(c.st, 1, 1, 1, c.GU, nullptr, c.WTd[l], c.UDX, c.X2, NTOK, H_, INNER_, 2 * INNER_);
  if (hout) k_rms_fwd<<<NTOK, 256, 0, c.st>>>(c.X2, hout);
}

static void block_backward(Ctx& c, int l, const float* hin,
                           const float* wqkv, const float* wo, const float* wgu, const float* wd) {
  block_forward(c, l, hin, nullptr, wqkv, wo, wgu, wd);
  k_rms_bwd<<<NTOK, 256, 0, c.st>>>(c.X2, c.G, c.UDX);
  gemm(c.st, 0, 0, 0, c.UDX, wd, nullptr, nullptr, c.ACT, NTOK, INNER_, H_, H_);
  k_silu_bwd<<<(NTOK * INNER_ + 255) / 256, 256, 0, c.st>>>(c.GU, c.ACT);
  gemm(c.st, 0, 0, 1, c.GU, wgu, nullptr, c.UDX, c.G, NTOK, H_, 2 * INNER_, 2 * INNER_);
  k_rms_bwd<<<NTOK, 256, 0, c.st>>>(c.X1, c.G, c.UDX);
  gemm(c.st, 0, 0, 0, c.UDX, wo, nullptr, nullptr, c.X2, NTOK, H_, H_, H_);
  dim3 agrid((S_ + 63) / 64, NH_, B_);
  k_attn_bwd_dq<<<agrid, 256, 0, c.st>>>(c.Q, c.AO, c.X2, c.MB, c.LB, c.dQ, c.DB);
  k_attn_bwd_dv<<<agrid, 256, 0, c.st>>>(c.Q, c.X2, c.MB, c.LB, c.dQ);
  k_attn_bwd_dk<<<agrid, 256, 0, c.st>>>(c.Q, c.X2, c.MB, c.LB, c.DB, c.dQ);
  k_rope<1><<<(NTOK * NH_ * 2 * 32 + 255) / 256, 256, 0, c.st>>>(c.dQ, c.CS, c.SN);
  gemm(c.st, 0, 0, 1, c.dQ, wqkv, nullptr, c.UDX, c.G, NTOK, H_, 3 * H_, 3 * H_);
}

extern "C" void kernel_launch(void* const* d_in, const int* in_sizes, int n_in,
                              void* d_out, int out_size, void* d_ws, size_t ws_size,
                              hipStream_t stream) {
  const int* inputs = (const int*)d_in[0];
  const float* E = (const float*)d_in[2];
  const float* ew = (const float*)d_in[3];
  const float* qkvw = (const float*)d_in[4];
  const float* ow = (const float*)d_in[5];
  const float* guw = (const float*)d_in[6];
  const float* dw = (const float*)d_in[7];
  const float* alpha = (const float*)d_in[8];
  float* logits = (float*)d_out;

  // workspace budget (floats): 66,386,272 = 265.5 MB
  const size_t WT_FLOATS = 3407872;  // 6,815,744 bf16 per... (both layers total, in float units)
  const size_t NEED =
      ((size_t)NTOK * 3 * H_) +      // Q
      ((size_t)NTOK * 2 * INNER_) +  // GU
      ((size_t)NTOK * 3 * H_) +      // dQ/ACT
      5 * ((size_t)NTOK * H_) +      // X1, X2, AO, G, UDX
      ((size_t)NTOK * V_) +          // P
      3 * ((size_t)B_ * NH_ * S_) +  // MB, LB, DB
      2 * ((size_t)S_ * 32) +        // CS, SN
      WT_FLOATS;                     // bf16 transposed weights (both layers)
  if (ws_size < NEED * sizeof(float)) {
    k_zero<<<(NTOK * V_ + 255) / 256, 256, 0, stream>>>(logits, NTOK * V_);
    return;
  }

  float* f = (float*)d_ws;
  Ctx c;
  c.st = stream;
  c.Q = f;    f += (size_t)NTOK * 3 * H_;
  c.GU = f;   f += (size_t)NTOK * 2 * INNER_;
  c.dQ = f;   c.ACT = f;  f += (size_t)NTOK * 3 * H_;
  c.X1 = f;   f += (size_t)NTOK * H_;
  c.X2 = f;   f += (size_t)NTOK * H_;
  c.AO = f;   f += (size_t)NTOK * H_;
  c.G = f;    f += (size_t)NTOK * H_;
  c.UDX = f;  f += (size_t)NTOK * H_;
  c.P = f;    f += (size_t)NTOK * V_;
  c.MB = f;   f += (size_t)B_ * NH_ * S_;
  c.LB = f;   f += (size_t)B_ * NH_ * S_;
  c.DB = f;   f += (size_t)B_ * NH_ * S_;
  c.CS = f;   f += (size_t)S_ * 32;
  c.SN = f;   f += (size_t)S_ * 32;
  unsigned short* wt = (unsigned short*)f;

  const size_t LQKV = (size_t)H_ * 3 * H_;
  const size_t LO = (size_t)H_ * H_;
  const size_t LGU = (size_t)H_ * 2 * INNER_;
  const size_t LD = (size_t)INNER_ * H_;

  // one-time transposed bf16 weights: WT[N][K] from W[K][N]
  for (int l = 0; l < 2; ++l) {
    c.WTqkv[l] = wt;
    k_wt<<<dim3(3 * H_ / 32, H_ / 32), dim3(32, 8), 0, stream>>>(qkvw + l * LQKV, wt, H_, 3 * H_);
    wt += LQKV;
    c.WTo[l] = wt;
    k_wt<<<dim3(H_ / 32, H_ / 32), dim3(32, 8), 0, stream>>>(ow + l * LO, wt, H_, H_);
    wt += LO;
    c.WTgu[l] = wt;
    k_wt<<<dim3(2 * INNER_ / 32, H_ / 32), dim3(32, 8), 0, stream>>>(guw + l * LGU, wt, H_, 2 * INNER_);
    wt += LGU;
    c.WTd[l] = wt;
    k_wt<<<dim3(H_ / 32, INNER_ / 32), dim3(32, 8), 0, stream>>>(dw + l * LD, wt, INNER_, H_);
    wt += LD;
  }

  k_zero<<<(NTOK * V_ + 255) / 256, 256, 0, stream>>>(logits, NTOK * V_);
  k_rope_tables<<<(S_ * 32 + 255) / 256, 256, 0, stream>>>(c.CS, c.SN);

  for (int step = 0; step < STEPS_; ++step) {
    k_softmax_logits<<<(NTOK + 255) / 256, 256, 0, stream>>>(logits, c.P);
    // h0 -> X1
    k_h0<<<NTOK, 256, 0, stream>>>(c.P, E, inputs, c.X1);
    // forward layer 0; h1 checkpoint -> UDX
    block_forward(c, 0, c.X1, c.UDX, qkvw, ow, guw, dw);
    // dE/dh2 = energy_w broadcast
    k_gfill<<<(NTOK * H_ + 255) / 256, 256, 0, stream>>>(ew, c.G);
    // backward layer 1 (checkpoint h1 == UDX)
    block_backward(c, 1, c.UDX, qkvw + LQKV, ow + LO, guw + LGU, dw + LD);
    // recompute h0 (X1 was clobbered by layer-1 recompute), then backward layer 0
    k_h0<<<NTOK, 256, 0, stream>>>(c.P, E, inputs, c.X1);
    block_backward(c, 0, c.X1, qkvw, ow, guw, dw);
    // dlogits and in-place logits update
    k_logits_update<<<NTOK, 64, 0, stream>>>(c.G, E, c.P, alpha, logits);
  }
}

// Round 6
// 5890.778 us; speedup vs baseline: 14.8845x; 1.9899x over previous
//
#include <hip/hip_runtime.h>
#include <math.h>

#define B_ 8
#define S_ 900
#define V_ 11
#define H_ 512
#define NH_ 8
#define HD_ 64
#define INNER_ 1536
#define STEPS_ 2
#define NTOK (B_*S_)
#define EPS_ 1e-5f
#define THETA_ 10000.0f
#define ESCALE_ 22.627416997969522f
#define SCALE_ 0.125f
#define PT_ 68  // LDS row pitch in ushorts (136B: 8B-aligned rows, ~4-way bank alias on b64 reads)

typedef __attribute__((ext_vector_type(8))) short bh8;
typedef __attribute__((ext_vector_type(4))) float f32x4;
typedef __attribute__((ext_vector_type(4))) unsigned short us4;

union bfu { bh8 v; unsigned short s[8]; us4 q[2]; };

__device__ inline unsigned short f2bf(float x) {
  unsigned u = __builtin_bit_cast(unsigned, x);
  return (unsigned short)((u + 0x7FFFu + ((u >> 16) & 1u)) >> 16);
}

__device__ inline bh8 lds16(const unsigned short* p) {  // 8B-aligned LDS 16B read
  bfu u;
  u.q[0] = *(const us4*)p;
  u.q[1] = *(const us4*)(p + 4);
  return u.v;
}
__device__ inline void sts16(unsigned short* p, bfu u) {  // 8B-aligned LDS 16B write
  *(us4*)p = u.q[0];
  *(us4*)(p + 4) = u.q[1];
}

__device__ inline float wave_sum64(float x) {
#pragma unroll
  for (int off = 32; off > 0; off >>= 1) x += __shfl_xor(x, off, 64);
  return x;
}

__device__ inline float quad_sum(float x) {
  x += __shfl_xor(x, 1, 64);
  x += __shfl_xor(x, 2, 64);
  return x;
}

// ---------------- small kernels ----------------

__global__ void k_zero(float* p, int n) {
  int i = blockIdx.x * blockDim.x + threadIdx.x;
  if (i < n) p[i] = 0.f;
}

__global__ void k_rope_tables(float* cs, float* sn) {
  int idx = blockIdx.x * blockDim.x + threadIdx.x;
  if (idx >= S_ * 32) return;
  int s = idx >> 5, i = idx & 31;
  float freq = powf(THETA_, -(float)i / 32.0f);
  float ang = (float)s * freq;
  cs[idx] = cosf(ang);
  sn[idx] = sinf(ang);
}

__global__ void k_softmax_logits(const float* __restrict__ logits, float* __restrict__ P) {
  int t = blockIdx.x * blockDim.x + threadIdx.x;
  if (t >= NTOK) return;
  float x[V_];
  float m = -1e30f;
#pragma unroll
  for (int v = 0; v < V_; ++v) { x[v] = logits[t * V_ + v]; m = fmaxf(m, x[v]); }
  float ssum = 0.f;
#pragma unroll
  for (int v = 0; v < V_; ++v) { x[v] = expf(x[v] - m); ssum += x[v]; }
  float inv = 1.f / ssum;
#pragma unroll
  for (int v = 0; v < V_; ++v) P[t * V_ + v] = x[v] * inv;
}

__global__ void k_h0(const float* __restrict__ P, const float* __restrict__ E,
                     const int* __restrict__ inp, float* __restrict__ h0) {
  int t = blockIdx.x;
  int tid = threadIdx.x;
  __shared__ float p[V_];
  __shared__ int iw;
  if (tid < V_) p[tid] = P[t * V_ + tid];
  if (tid == 0) iw = inp[t];
  __syncthreads();
  for (int h = tid; h < H_; h += blockDim.x) {
    float acc = E[iw * H_ + h];
#pragma unroll
    for (int v = 0; v < V_; ++v) acc += p[v] * E[v * H_ + h];
    h0[(size_t)t * H_ + h] = ESCALE_ * acc;
  }
}

__global__ void k_gfill(const float* __restrict__ ew, float* __restrict__ G) {
  int idx = blockIdx.x * blockDim.x + threadIdx.x;
  if (idx < NTOK * H_) G[idx] = ew[idx & (H_ - 1)];
}

// ---------------- weight transpose-convert: W[K][N] fp32 -> WT[N][K] bf16 ----------------

__global__ void k_wt(const float* __restrict__ W, unsigned short* __restrict__ WT, int K, int N) {
  __shared__ float t[32][33];
  int k0 = blockIdx.y * 32, n0 = blockIdx.x * 32;
  int tx = threadIdx.x, ty = threadIdx.y;  // 32 x 8
#pragma unroll
  for (int i = 0; i < 4; ++i)
    t[ty + 8 * i][tx] = W[(size_t)(k0 + ty + 8 * i) * N + n0 + tx];
  __syncthreads();
#pragma unroll
  for (int i = 0; i < 4; ++i)
    WT[(size_t)(n0 + ty + 8 * i) * K + k0 + tx] = f2bf(t[tx][ty + 8 * i]);
}

// ---------------- MFMA GEMM (unchanged from round 5) ----------------

template <int BSRC, int SILU_A, int ADD>
__global__ __launch_bounds__(256) void k_gemm(const float* __restrict__ A,
                                              const float* __restrict__ Bf,
                                              const unsigned short* __restrict__ Bt,
                                              const float* __restrict__ Dm,
                                              float* __restrict__ Cm,
                                              int M, int N, int K, int lda) {
  __shared__ unsigned short As[128][40];
  __shared__ unsigned short Bs[128][40];
  int tid = threadIdx.x;
  int m0 = blockIdx.y * 128, n0 = blockIdx.x * 128;
  int wid = tid >> 6, lane = tid & 63;
  int wr = (wid >> 1) * 64, wc = (wid & 1) * 64;
  int lr = lane & 15, lg = lane >> 4;
  f32x4 acc[4][4] = {};
  for (int k0 = 0; k0 < K; k0 += 32) {
    __syncthreads();
#pragma unroll
    for (int i = 0; i < 2; ++i) {
      int cidx = tid + 256 * i;
      int row = cidx >> 2, ck = (cidx & 3) * 8;
      int gr = m0 + row; gr = gr < M ? gr : M - 1;
      const float* src = &A[(size_t)gr * lda + k0 + ck];
      union { bh8 v; unsigned short s[8]; } pa;
      if (SILU_A) {
#pragma unroll
        for (int j = 0; j < 8; ++j) {
          float g = src[j], u = src[INNER_ + j];
          pa.s[j] = f2bf((g / (1.f + __expf(-g))) * u);
        }
      } else {
#pragma unroll
        for (int j = 0; j < 8; ++j) pa.s[j] = f2bf(src[j]);
      }
      *(bh8*)&As[row][ck] = pa.v;
      if (BSRC == 0) {
        const float* bs = &Bf[(size_t)(n0 + row) * K + k0 + ck];
        union { bh8 v; unsigned short s[8]; } pb;
#pragma unroll
        for (int j = 0; j < 8; ++j) pb.s[j] = f2bf(bs[j]);
        *(bh8*)&Bs[row][ck] = pb.v;
      } else {
        *(bh8*)&Bs[row][ck] = *(const bh8*)&Bt[(size_t)(n0 + row) * K + k0 + ck];
      }
    }
    __syncthreads();
    bh8 av[4], bv[4];
#pragma unroll
    for (int f = 0; f < 4; ++f) {
      av[f] = *(const bh8*)&As[wr + f * 16 + lr][lg * 8];
      bv[f] = *(const bh8*)&Bs[wc + f * 16 + lr][lg * 8];
    }
#pragma unroll
    for (int fr = 0; fr < 4; ++fr)
#pragma unroll
      for (int fc = 0; fc < 4; ++fc)
        acc[fr][fc] = __builtin_amdgcn_mfma_f32_16x16x32_bf16(av[fr], bv[fc], acc[fr][fc], 0, 0, 0);
  }
#pragma unroll
  for (int fr = 0; fr < 4; ++fr) {
    int r0 = m0 + wr + fr * 16 + lg * 4;
#pragma unroll
    for (int i = 0; i < 4; ++i) {
      int gr = r0 + i;
      if (gr >= M) continue;
#pragma unroll
      for (int fc = 0; fc < 4; ++fc) {
        int gc = n0 + wc + fc * 16 + lr;
        float out = acc[fr][fc][i];
        if (ADD) out += Dm[(size_t)gr * N + gc];
        Cm[(size_t)gr * N + gc] = out;
      }
    }
  }
}

static void gemm(hipStream_t st, int bsrc, int silu, int add,
                 const float* A, const float* Bf, const unsigned short* Bt,
                 const float* Dm, float* Cm, int M, int N, int K, int lda) {
  dim3 grid(N / 128, (M + 127) / 128);
  if (bsrc == 1 && !silu && !add) k_gemm<1, 0, 0><<<grid, 256, 0, st>>>(A, Bf, Bt, Dm, Cm, M, N, K, lda);
  else if (bsrc == 1 && !silu && add) k_gemm<1, 0, 1><<<grid, 256, 0, st>>>(A, Bf, Bt, Dm, Cm, M, N, K, lda);
  else if (bsrc == 1 && silu && add) k_gemm<1, 1, 1><<<grid, 256, 0, st>>>(A, Bf, Bt, Dm, Cm, M, N, K, lda);
  else if (bsrc == 0 && !silu && !add) k_gemm<0, 0, 0><<<grid, 256, 0, st>>>(A, Bf, Bt, Dm, Cm, M, N, K, lda);
  else k_gemm<0, 0, 1><<<grid, 256, 0, st>>>(A, Bf, Bt, Dm, Cm, M, N, K, lda);
}

// ---------------- RoPE fwd/bwd ----------------

template <int BWD>
__global__ void k_rope(float* __restrict__ Q, const float* __restrict__ cs,
                       const float* __restrict__ sn) {
  int idx = blockIdx.x * blockDim.x + threadIdx.x;
  if (idx >= NTOK * NH_ * 2 * 32) return;
  int i = idx & 31;
  int h = (idx >> 5) & (NH_ - 1);
  int part = (idx >> 8) & 1;
  int t = idx >> 9;
  int s = t % S_;
  float c = cs[s * 32 + i], sv = sn[s * 32 + i];
  size_t base = ((size_t)t * 3 * NH_ + part * NH_ + h) * HD_;
  float x1 = Q[base + i], x2 = Q[base + 32 + i];
  if (!BWD) {
    Q[base + i] = x1 * c - x2 * sv;
    Q[base + 32 + i] = x2 * c + x1 * sv;
  } else {
    Q[base + i] = x1 * c + x2 * sv;
    Q[base + 32 + i] = x2 * c - x1 * sv;
  }
}

// ---------------- MFMA flash attention ----------------
// QKV layout: [t][24][64]: Q at slot h, K at 8+h, V at 16+h.
// 16x16x32 bf16 layouts (validated by GEMM): A/B-frag row = lane&15, contract = (lane>>4)*8+j.
// C: row = (lane>>4)*4+i, col = lane&15.

__global__ __launch_bounds__(256) void k_attn_fwd3(const float* __restrict__ QKV,
                                                   float* __restrict__ AO,
                                                   float* __restrict__ MB,
                                                   float* __restrict__ LB) {
  __shared__ unsigned short Ks[64][PT_];
  __shared__ unsigned short VT[64][PT_];
  __shared__ unsigned short Ps[4][16][PT_];
  int tid = threadIdx.x;
  int h = blockIdx.y, b = blockIdx.z;
  int w = tid >> 6, lane = tid & 63;
  int lr = lane & 15, lg = lane >> 4;
  int q0 = blockIdx.x * 64 + w * 16;

  // Q fragments (A): row lr, contract lg*8+j (+32 for 2nd k-step)
  bh8 qf[2];
  {
    int qr = q0 + lr; if (qr >= S_) qr = S_ - 1;
    const float* qp = &QKV[((size_t)(b * S_ + qr) * 24 + h) * 64 + lg * 8];
    bfu t0, t1;
#pragma unroll
    for (int j = 0; j < 8; ++j) { t0.s[j] = f2bf(qp[j]); t1.s[j] = f2bf(qp[32 + j]); }
    qf[0] = t0.v; qf[1] = t1.v;
  }
  f32x4 accO[4] = {};
  float m[4], lsum[4];
#pragma unroll
  for (int i = 0; i < 4; ++i) { m[i] = -1e30f; lsum[i] = 0.f; }

  for (int kt = 0; kt < S_; kt += 64) {
    __syncthreads();
    {  // stage K rows (bf16), clamp
      int r = tid >> 2, c0 = (tid & 3) * 16;
      int src = kt + r;
      size_t ts = (size_t)b * S_ + (src < S_ ? src : S_ - 1);
      const float* gp = &QKV[(ts * 24 + 8 + h) * 64 + c0];
      bfu p0, p1;
#pragma unroll
      for (int j = 0; j < 8; ++j) { p0.s[j] = f2bf(gp[j]); p1.s[j] = f2bf(gp[8 + j]); }
      sts16(&Ks[r][c0], p0);
      sts16(&Ks[r][c0 + 8], p1);
    }
    {  // stage V^T (bf16), clamp
      int d0 = (tid & 15) * 4, k0r = (tid >> 4) * 4;
      float vv[4][4];
#pragma unroll
      for (int j = 0; j < 4; ++j) {
        int src = kt + k0r + j;
        size_t ts = (size_t)b * S_ + (src < S_ ? src : S_ - 1);
        float4 t4 = *(const float4*)&QKV[(ts * 24 + 16 + h) * 64 + d0];
        vv[j][0] = t4.x; vv[j][1] = t4.y; vv[j][2] = t4.z; vv[j][3] = t4.w;
      }
#pragma unroll
      for (int dd = 0; dd < 4; ++dd) {
        us4 pk = {f2bf(vv[0][dd]), f2bf(vv[1][dd]), f2bf(vv[2][dd]), f2bf(vv[3][dd])};
        *(us4*)&VT[d0 + dd][k0r] = pk;
      }
    }
    __syncthreads();
    // QK^T
    f32x4 accS[4] = {};
#pragma unroll
    for (int ks = 0; ks < 2; ++ks)
#pragma unroll
      for (int fk = 0; fk < 4; ++fk)
        accS[fk] = __builtin_amdgcn_mfma_f32_16x16x32_bf16(qf[ks], lds16(&Ks[fk * 16 + lr][ks * 32 + lg * 8]), accS[fk], 0, 0, 0);
    // scale + mask + online softmax
    float sc[4][4], pmax[4];
#pragma unroll
    for (int i = 0; i < 4; ++i) pmax[i] = -1e30f;
#pragma unroll
    for (int fk = 0; fk < 4; ++fk)
#pragma unroll
      for (int i = 0; i < 4; ++i) {
        float s = accS[fk][i] * SCALE_;
        if (kt + fk * 16 + lr >= S_) s = -1e30f;
        sc[fk][i] = s;
        pmax[i] = fmaxf(pmax[i], s);
      }
#pragma unroll
    for (int i = 0; i < 4; ++i) {
      float v = pmax[i];
      v = fmaxf(v, __shfl_xor(v, 1, 64));
      v = fmaxf(v, __shfl_xor(v, 2, 64));
      v = fmaxf(v, __shfl_xor(v, 4, 64));
      v = fmaxf(v, __shfl_xor(v, 8, 64));
      pmax[i] = v;
    }
    float psum[4];
#pragma unroll
    for (int i = 0; i < 4; ++i) {
      float mn = fmaxf(m[i], pmax[i]);
      float eo = __expf(m[i] - mn);
      m[i] = mn;
      lsum[i] *= eo;
#pragma unroll
      for (int fd = 0; fd < 4; ++fd) accO[fd][i] *= eo;
      psum[i] = 0.f;
    }
#pragma unroll
    for (int fk = 0; fk < 4; ++fk)
#pragma unroll
      for (int i = 0; i < 4; ++i) {
        float p = __expf(sc[fk][i] - m[i]);
        sc[fk][i] = p;
        psum[i] += p;
      }
#pragma unroll
    for (int i = 0; i < 4; ++i) {
      float v = psum[i];
      v += __shfl_xor(v, 1, 64);
      v += __shfl_xor(v, 2, 64);
      v += __shfl_xor(v, 4, 64);
      v += __shfl_xor(v, 8, 64);
      lsum[i] += v;
    }
    // P -> bf16 LDS (per-wave buffer)
#pragma unroll
    for (int fk = 0; fk < 4; ++fk)
#pragma unroll
      for (int i = 0; i < 4; ++i)
        Ps[w][lg * 4 + i][fk * 16 + lr] = f2bf(sc[fk][i]);
    // P . V^T
#pragma unroll
    for (int ks = 0; ks < 2; ++ks) {
      bh8 ap = lds16(&Ps[w][lr][ks * 32 + lg * 8]);
#pragma unroll
      for (int fd = 0; fd < 4; ++fd)
        accO[fd] = __builtin_amdgcn_mfma_f32_16x16x32_bf16(ap, lds16(&VT[fd * 16 + lr][ks * 32 + lg * 8]), accO[fd], 0, 0, 0);
    }
  }
#pragma unroll
  for (int i = 0; i < 4; ++i) {
    int q = q0 + lg * 4 + i;
    if (q < S_) {
      float linv = 1.f / lsum[i];
      size_t obase = (size_t)(b * S_ + q) * H_ + h * 64;
#pragma unroll
      for (int fd = 0; fd < 4; ++fd) AO[obase + fd * 16 + lr] = accO[fd][i] * linv;
      if (lr == 0) {
        MB[((size_t)b * NH_ + h) * S_ + q] = m[i];
        LB[((size_t)b * NH_ + h) * S_ + q] = linv;
      }
    }
  }
}

// delta[b,h,q] = dot(dO_row, O_row)
__global__ __launch_bounds__(256) void k_delta(const float* __restrict__ O,
                                               const float* __restrict__ dO,
                                               float* __restrict__ DB) {
  int tid = threadIdx.x;
  int h = blockIdx.y, b = blockIdx.z;
  int r = blockIdx.x * 64 + (tid >> 2), part = tid & 3;
  if (r >= S_) return;
  size_t base = (size_t)(b * S_ + r) * H_ + h * 64 + part * 16;
  const float4* op = (const float4*)&O[base];
  const float4* dp = (const float4*)&dO[base];
  float s = 0.f;
#pragma unroll
  for (int i = 0; i < 4; ++i) {
    float4 a = op[i], d = dp[i];
    s += a.x * d.x + a.y * d.y + a.z * d.z + a.w * d.w;
  }
  s = quad_sum(s);
  if (part == 0) DB[((size_t)b * NH_ + h) * S_ + r] = s;
}

// dQ: wave owns 16 q-rows (Q, dO as A-frags in regs); loop k-tiles.
__global__ __launch_bounds__(256) void k_attn_bwd_dq3(const float* __restrict__ QKV,
                                                      const float* __restrict__ dO,
                                                      const float* __restrict__ MB,
                                                      const float* __restrict__ LB,
                                                      const float* __restrict__ DB,
                                                      float* __restrict__ dQKV) {
  __shared__ unsigned short Ks[64][PT_];
  __shared__ unsigned short Vs[64][PT_];
  __shared__ unsigned short KT[64][PT_];
  __shared__ unsigned short Ps[4][16][PT_];
  int tid = threadIdx.x;
  int h = blockIdx.y, b = blockIdx.z;
  int w = tid >> 6, lane = tid & 63;
  int lr = lane & 15, lg = lane >> 4;
  int q0 = blockIdx.x * 64 + w * 16;
  size_t sbase = ((size_t)b * NH_ + h) * S_;

  bh8 qf[2], dof[2];
  {
    int qr = q0 + lr; if (qr >= S_) qr = S_ - 1;
    const float* qp = &QKV[((size_t)(b * S_ + qr) * 24 + h) * 64 + lg * 8];
    const float* dp = &dO[(size_t)(b * S_ + qr) * H_ + h * 64 + lg * 8];
    bfu t0, t1, t2, t3;
#pragma unroll
    for (int j = 0; j < 8; ++j) {
      t0.s[j] = f2bf(qp[j]); t1.s[j] = f2bf(qp[32 + j]);
      t2.s[j] = f2bf(dp[j]); t3.s[j] = f2bf(dp[32 + j]);
    }
    qf[0] = t0.v; qf[1] = t1.v; dof[0] = t2.v; dof[1] = t3.v;
  }
  float mrow[4], lrow[4], drow[4];
#pragma unroll
  for (int i = 0; i < 4; ++i) {
    int q = q0 + lg * 4 + i; if (q >= S_) q = S_ - 1;
    mrow[i] = MB[sbase + q];
    lrow[i] = LB[sbase + q];
    drow[i] = DB[sbase + q];
  }
  f32x4 accQ[4] = {};

  for (int kt = 0; kt < S_; kt += 64) {
    __syncthreads();
    {  // stage K, V rows (zeroed past S_)
      int r = tid >> 2, c0 = (tid & 3) * 16;
      int src = kt + r;
      bool vld = src < S_;
      size_t ts = (size_t)b * S_ + (vld ? src : S_ - 1);
      const float* kp = &QKV[(ts * 24 + 8 + h) * 64 + c0];
      bfu p0, p1, p2, p3;
#pragma unroll
      for (int j = 0; j < 8; ++j) {
        p0.s[j] = vld ? f2bf(kp[j]) : 0;
        p1.s[j] = vld ? f2bf(kp[8 + j]) : 0;
        p2.s[j] = vld ? f2bf(kp[512 + j]) : 0;        // V = slot+8 => +512 floats
        p3.s[j] = vld ? f2bf(kp[512 + 8 + j]) : 0;
      }
      sts16(&Ks[r][c0], p0); sts16(&Ks[r][c0 + 8], p1);
      sts16(&Vs[r][c0], p2); sts16(&Vs[r][c0 + 8], p3);
    }
    {  // stage K^T (zeroed past S_)
      int d0 = (tid & 15) * 4, k0r = (tid >> 4) * 4;
      float kv[4][4];
#pragma unroll
      for (int j = 0; j < 4; ++j) {
        int src = kt + k0r + j;
        bool vld = src < S_;
        size_t ts = (size_t)b * S_ + (vld ? src : S_ - 1);
        float4 t4 = *(const float4*)&QKV[(ts * 24 + 8 + h) * 64 + d0];
        kv[j][0] = vld ? t4.x : 0.f; kv[j][1] = vld ? t4.y : 0.f;
        kv[j][2] = vld ? t4.z : 0.f; kv[j][3] = vld ? t4.w : 0.f;
      }
#pragma unroll
      for (int dd = 0; dd < 4; ++dd) {
        us4 pk = {f2bf(kv[0][dd]), f2bf(kv[1][dd]), f2bf(kv[2][dd]), f2bf(kv[3][dd])};
        *(us4*)&KT[d0 + dd][k0r] = pk;
      }
    }
    __syncthreads();
    f32x4 aS[4] = {}, aD[4] = {};
#pragma unroll
    for (int ks = 0; ks < 2; ++ks)
#pragma unroll
      for (int fk = 0; fk < 4; ++fk) {
        aS[fk] = __builtin_amdgcn_mfma_f32_16x16x32_bf16(qf[ks], lds16(&Ks[fk * 16 + lr][ks * 32 + lg * 8]), aS[fk], 0, 0, 0);
        aD[fk] = __builtin_amdgcn_mfma_f32_16x16x32_bf16(dof[ks], lds16(&Vs[fk * 16 + lr][ks * 32 + lg * 8]), aD[fk], 0, 0, 0);
      }
#pragma unroll
    for (int fk = 0; fk < 4; ++fk)
#pragma unroll
      for (int i = 0; i < 4; ++i) {
        float p = __expf(aS[fk][i] * SCALE_ - mrow[i]) * lrow[i];
        float ds = p * (aD[fk][i] - drow[i]);
        Ps[w][lg * 4 + i][fk * 16 + lr] = f2bf(ds);
      }
#pragma unroll
    for (int ks = 0; ks < 2; ++ks) {
      bh8 ap = lds16(&Ps[w][lr][ks * 32 + lg * 8]);
#pragma unroll
      for (int fd = 0; fd < 4; ++fd)
        accQ[fd] = __builtin_amdgcn_mfma_f32_16x16x32_bf16(ap, lds16(&KT[fd * 16 + lr][ks * 32 + lg * 8]), accQ[fd], 0, 0, 0);
    }
  }
#pragma unroll
  for (int i = 0; i < 4; ++i) {
    int q = q0 + lg * 4 + i;
    if (q < S_) {
      size_t obase = ((size_t)(b * S_ + q) * 24 + h) * 64;
#pragma unroll
      for (int fd = 0; fd < 4; ++fd) dQKV[obase + fd * 16 + lr] = SCALE_ * accQ[fd][i];
    }
  }
}

// dK + dV: wave owns 16 k-rows (K, V as A-frags in regs); loop q-tiles.
__global__ __launch_bounds__(256) void k_attn_bwd_kv3(const float* __restrict__ QKV,
                                                      const float* __restrict__ dO,
                                                      const float* __restrict__ MB,
                                                      const float* __restrict__ LB,
                                                      const float* __restrict__ DB,
                                                      float* __restrict__ dQKV) {
  __shared__ unsigned short Qs[64][PT_];
  __shared__ unsigned short dOs[64][PT_];
  __shared__ unsigned short QT[64][PT_];
  __shared__ unsigned short dOT[64][PT_];
  __shared__ unsigned short Ps[4][16][PT_];
  __shared__ float sM[64], sL[64], sD[64];
  int tid = threadIdx.x;
  int h = blockIdx.y, b = blockIdx.z;
  int w = tid >> 6, lane = tid & 63;
  int lr = lane & 15, lg = lane >> 4;
  int k0w = blockIdx.x * 64 + w * 16;
  size_t sbase = ((size_t)b * NH_ + h) * S_;

  bh8 kf[2], vf[2];
  {
    int kr = k0w + lr; if (kr >= S_) kr = S_ - 1;
    const float* kp = &QKV[((size_t)(b * S_ + kr) * 24 + 8 + h) * 64 + lg * 8];
    bfu t0, t1, t2, t3;
#pragma unroll
    for (int j = 0; j < 8; ++j) {
      t0.s[j] = f2bf(kp[j]); t1.s[j] = f2bf(kp[32 + j]);
      t2.s[j] = f2bf(kp[512 + j]); t3.s[j] = f2bf(kp[512 + 32 + j]);
    }
    kf[0] = t0.v; kf[1] = t1.v; vf[0] = t2.v; vf[1] = t3.v;
  }
  f32x4 accK[4] = {}, accV[4] = {};

  for (int qt = 0; qt < S_; qt += 64) {
    __syncthreads();
    {  // stage Q (clamp), dO (zeroed past S_)
      int r = tid >> 2, c0 = (tid & 3) * 16;
      int src = qt + r;
      bool vld = src < S_;
      size_t ts = (size_t)b * S_ + (vld ? src : S_ - 1);
      const float* qp = &QKV[(ts * 24 + h) * 64 + c0];
      const float* dp = &dO[ts * H_ + h * 64 + c0];
      bfu p0, p1, p2, p3;
#pragma unroll
      for (int j = 0; j < 8; ++j) {
        p0.s[j] = f2bf(qp[j]);
        p1.s[j] = f2bf(qp[8 + j]);
        p2.s[j] = vld ? f2bf(dp[j]) : 0;
        p3.s[j] = vld ? f2bf(dp[8 + j]) : 0;
      }
      sts16(&Qs[r][c0], p0); sts16(&Qs[r][c0 + 8], p1);
      sts16(&dOs[r][c0], p2); sts16(&dOs[r][c0 + 8], p3);
    }
    {  // stage Q^T (clamp), dO^T (zeroed)
      int d0 = (tid & 15) * 4, q0r = (tid >> 4) * 4;
      float qv[4][4], dv[4][4];
#pragma unroll
      for (int j = 0; j < 4; ++j) {
        int src = qt + q0r + j;
        bool vld = src < S_;
        size_t ts = (size_t)b * S_ + (vld ? src : S_ - 1);
        float4 tq = *(const float4*)&QKV[(ts * 24 + h) * 64 + d0];
        float4 td = *(const float4*)&dO[ts * H_ + h * 64 + d0];
        qv[j][0] = tq.x; qv[j][1] = tq.y; qv[j][2] = tq.z; qv[j][3] = tq.w;
        dv[j][0] = vld ? td.x : 0.f; dv[j][1] = vld ? td.y : 0.f;
        dv[j][2] = vld ? td.z : 0.f; dv[j][3] = vld ? td.w : 0.f;
      }
#pragma unroll
      for (int dd = 0; dd < 4; ++dd) {
        us4 pq = {f2bf(qv[0][dd]), f2bf(qv[1][dd]), f2bf(qv[2][dd]), f2bf(qv[3][dd])};
        us4 pd = {f2bf(dv[0][dd]), f2bf(dv[1][dd]), f2bf(dv[2][dd]), f2bf(dv[3][dd])};
        *(us4*)&QT[d0 + dd][q0r] = pq;
        *(us4*)&dOT[d0 + dd][q0r] = pd;
      }
    }
    if (tid < 64) {  // stats (delta zeroed past S_)
      int src = qt + tid;
      bool vld = src < S_;
      int sc = vld ? src : S_ - 1;
      sM[tid] = MB[sbase + sc];
      sL[tid] = LB[sbase + sc];
      sD[tid] = vld ? DB[sbase + sc] : 0.f;
    }
    __syncthreads();
    // S^T = K.Q^T, dP^T = V.dO^T
    f32x4 aS[4] = {}, aD[4] = {};
#pragma unroll
    for (int ks = 0; ks < 2; ++ks)
#pragma unroll
      for (int fq = 0; fq < 4; ++fq) {
        aS[fq] = __builtin_amdgcn_mfma_f32_16x16x32_bf16(kf[ks], lds16(&Qs[fq * 16 + lr][ks * 32 + lg * 8]), aS[fq], 0, 0, 0);
        aD[fq] = __builtin_amdgcn_mfma_f32_16x16x32_bf16(vf[ks], lds16(&dOs[fq * 16 + lr][ks * 32 + lg * 8]), aD[fq], 0, 0, 0);
      }
    // P^T -> LDS; dV += P^T . dO^T
    float pv[4][4];
#pragma unroll
    for (int fq = 0; fq < 4; ++fq) {
      float mq = sM[fq * 16 + lr], lq = sL[fq * 16 + lr];
#pragma unroll
      for (int i = 0; i < 4; ++i) {
        float p = __expf(aS[fq][i] * SCALE_ - mq) * lq;
        pv[fq][i] = p;
        Ps[w][lg * 4 + i][fq * 16 + lr] = f2bf(p);
      }
    }
#pragma unroll
    for (int qs = 0; qs < 2; ++qs) {
      bh8 ap = lds16(&Ps[w][lr][qs * 32 + lg * 8]);
#pragma unroll
      for (int fd = 0; fd < 4; ++fd)
        accV[fd] = __builtin_amdgcn_mfma_f32_16x16x32_bf16(ap, lds16(&dOT[fd * 16 + lr][qs * 32 + lg * 8]), accV[fd], 0, 0, 0);
    }
    // dS^T -> LDS (overwrite); dK += dS^T . Q^T
#pragma unroll
    for (int fq = 0; fq < 4; ++fq) {
      float dq = sD[fq * 16 + lr];
#pragma unroll
      for (int i = 0; i < 4; ++i)
        Ps[w][lg * 4 + i][fq * 16 + lr] = f2bf(pv[fq][i] * (aD[fq][i] - dq));
    }
#pragma unroll
    for (int qs = 0; qs < 2; ++qs) {
      bh8 ap = lds16(&Ps[w][lr][qs * 32 + lg * 8]);
#pragma unroll
      for (int fd = 0; fd < 4; ++fd)
        accK[fd] = __builtin_amdgcn_mfma_f32_16x16x32_bf16(ap, lds16(&QT[fd * 16 + lr][qs * 32 + lg * 8]), accK[fd], 0, 0, 0);
    }
  }
#pragma unroll
  for (int i = 0; i < 4; ++i) {
    int k = k0w + lg * 4 + i;
    if (k < S_) {
      size_t obase = ((size_t)(b * S_ + k) * 24 + 8 + h) * 64;
#pragma unroll
      for (int fd = 0; fd < 4; ++fd) {
        dQKV[obase + fd * 16 + lr] = SCALE_ * accK[fd][i];
        dQKV[obase + 512 + fd * 16 + lr] = accV[fd][i];
      }
    }
  }
}

// ---------------- RMS norm fwd/bwd ----------------

__global__ __launch_bounds__(256) void k_rms_fwd(const float* __restrict__ X, float* __restrict__ Y) {
  int t = blockIdx.x, tid = threadIdx.x;
  float x0 = X[(size_t)t * H_ + tid], x1 = X[(size_t)t * H_ + tid + 256];
  __shared__ float red[256];
  red[tid] = x0 * x0 + x1 * x1;
  __syncthreads();
  for (int s = 128; s > 0; s >>= 1) {
    if (tid < s) red[tid] += red[tid + s];
    __syncthreads();
  }
  float r = rsqrtf(red[0] / H_ + EPS_);
  Y[(size_t)t * H_ + tid] = x0 * r;
  Y[(size_t)t * H_ + tid + 256] = x1 * r;
}

__global__ __launch_bounds__(256) void k_rms_bwd(const float* __restrict__ X,
                                                 const float* __restrict__ GY,
                                                 float* __restrict__ GX) {
  int t = blockIdx.x, tid = threadIdx.x;
  float x0 = X[(size_t)t * H_ + tid], x1 = X[(size_t)t * H_ + tid + 256];
  float g0 = GY[(size_t)t * H_ + tid], g1 = GY[(size_t)t * H_ + tid + 256];
  __shared__ float r1[256], r2[256];
  r1[tid] = x0 * x0 + x1 * x1;
  r2[tid] = x0 * g0 + x1 * g1;
  __syncthreads();
  for (int s = 128; s > 0; s >>= 1) {
    if (tid < s) { r1[tid] += r1[tid + s]; r2[tid] += r2[tid + s]; }
    __syncthreads();
  }
  float r = rsqrtf(r1[0] / H_ + EPS_);
  float coef = r * r * r * r2[0] / (float)H_;
  GX[(size_t)t * H_ + tid] = r * g0 - coef * x0;
  GX[(size_t)t * H_ + tid + 256] = r * g1 - coef * x1;
}

// ---------------- SiLU-gate backward, in place on GU ----------------

__global__ void k_silu_bwd(float* __restrict__ GU, const float* __restrict__ dact) {
  int idx = blockIdx.x * blockDim.x + threadIdx.x;
  if (idx >= NTOK * INNER_) return;
  int t = idx / INNER_, i = idx % INNER_;
  size_t gb = (size_t)t * 2 * INNER_;
  float g = GU[gb + i], u = GU[gb + INNER_ + i];
  float da = dact[idx];
  float sig = 1.f / (1.f + expf(-g));
  GU[gb + i] = da * u * sig * (1.f + g * (1.f - sig));
  GU[gb + INNER_ + i] = da * g * sig;
}

// ---------------- logits update ----------------

__global__ __launch_bounds__(64) void k_logits_update(const float* __restrict__ G,
                                                      const float* __restrict__ E,
                                                      const float* __restrict__ P,
                                                      const float* __restrict__ alpha,
                                                      float* __restrict__ logits) {
  int t = blockIdx.x, lane = threadIdx.x;
  float dp[V_];
#pragma unroll
  for (int v = 0; v < V_; ++v) dp[v] = 0.f;
  for (int hh = lane; hh < H_; hh += 64) {
    float gh = G[(size_t)t * H_ + hh];
#pragma unroll
    for (int v = 0; v < V_; ++v) dp[v] += gh * E[v * H_ + hh];
  }
#pragma unroll
  for (int v = 0; v < V_; ++v) dp[v] = wave_sum64(dp[v]) * ESCALE_;
  float dot = 0.f;
  float pv[V_];
#pragma unroll
  for (int v = 0; v < V_; ++v) {
    pv[v] = P[t * V_ + v];
    dot += pv[v] * dp[v];
  }
  float a = fmaxf(alpha[0], 1e-4f);
  if (lane < V_) logits[t * V_ + lane] -= a * pv[lane] * (dp[lane] - dot);
}

// ---------------- host-side orchestration ----------------

struct Ctx {
  float *Q, *dQ, *GU, *ACT, *X1, *X2, *AO, *G, *UDX, *P, *MB, *LB, *DB, *CS, *SN;
  const unsigned short *WTqkv[2], *WTo[2], *WTgu[2], *WTd[2];
  hipStream_t st;
};

static void block_forward(Ctx& c, int l, const float* hin, float* hout,
                          const float* wqkv, const float* wo, const float* wgu, const float* wd) {
  gemm(c.st, 1, 0, 0, hin, nullptr, c.WTqkv[l], nullptr, c.Q, NTOK, 3 * H_, H_, H_);
  k_rope<0><<<(NTOK * NH_ * 2 * 32 + 255) / 256, 256, 0, c.st>>>(c.Q, c.CS, c.SN);
  k_attn_fwd3<<<dim3((S_ + 63) / 64, NH_, B_), 256, 0, c.st>>>(c.Q, c.AO, c.MB, c.LB);
  gemm(c.st, 1, 0, 1, c.AO, nullptr, c.WTo[l], hin, c.X1, NTOK, H_, H_, H_);
  k_rms_fwd<<<NTOK, 256, 0, c.st>>>(c.X1, c.UDX);
  gemm(c.st, 1, 0, 0, c.UDX, nullptr, c.WTgu[l], nullptr, c.GU, NTOK, 2 * INNER_, H_, H_);
  gemm(c.st, 1, 1, 1, c.GU, nullptr, c.WTd[l], c.UDX, c.X2, NTOK, H_, INNER_, 2 * INNER_);
  if (hout) k_rms_fwd<<<NTOK, 256, 0, c.st>>>(c.X2, hout);
}

static void block_backward(Ctx& c, int l, const float* hin,
                           const float* wqkv, const float* wo, const float* wgu, const float* wd) {
  block_forward(c, l, hin, nullptr, wqkv, wo, wgu, wd);
  k_rms_bwd<<<NTOK, 256, 0, c.st>>>(c.X2, c.G, c.UDX);
  gemm(c.st, 0, 0, 0, c.UDX, wd, nullptr, nullptr, c.ACT, NTOK, INNER_, H_, H_);
  k_silu_bwd<<<(NTOK * INNER_ + 255) / 256, 256, 0, c.st>>>(c.GU, c.ACT);
  gemm(c.st, 0, 0, 1, c.GU, wgu, nullptr, c.UDX, c.G, NTOK, H_, 2 * INNER_, 2 * INNER_);
  k_rms_bwd<<<NTOK, 256, 0, c.st>>>(c.X1, c.G, c.UDX);
  gemm(c.st, 0, 0, 0, c.UDX, wo, nullptr, nullptr, c.X2, NTOK, H_, H_, H_);
  dim3 agrid((S_ + 63) / 64, NH_, B_);
  k_delta<<<agrid, 256, 0, c.st>>>(c.AO, c.X2, c.DB);
  k_attn_bwd_dq3<<<agrid, 256, 0, c.st>>>(c.Q, c.X2, c.MB, c.LB, c.DB, c.dQ);
  k_attn_bwd_kv3<<<agrid, 256, 0, c.st>>>(c.Q, c.X2, c.MB, c.LB, c.DB, c.dQ);
  k_rope<1><<<(NTOK * NH_ * 2 * 32 + 255) / 256, 256, 0, c.st>>>(c.dQ, c.CS, c.SN);
  gemm(c.st, 0, 0, 1, c.dQ, wqkv, nullptr, c.UDX, c.G, NTOK, H_, 3 * H_, 3 * H_);
}

extern "C" void kernel_launch(void* const* d_in, const int* in_sizes, int n_in,
                              void* d_out, int out_size, void* d_ws, size_t ws_size,
                              hipStream_t stream) {
  const int* inputs = (const int*)d_in[0];
  const float* E = (const float*)d_in[2];
  const float* ew = (const float*)d_in[3];
  const float* qkvw = (const float*)d_in[4];
  const float* ow = (const float*)d_in[5];
  const float* guw = (const float*)d_in[6];
  const float* dw = (const float*)d_in[7];
  const float* alpha = (const float*)d_in[8];
  float* logits = (float*)d_out;

  const size_t WT_FLOATS = 3407872;
  const size_t NEED =
      ((size_t)NTOK * 3 * H_) +
      ((size_t)NTOK * 2 * INNER_) +
      ((size_t)NTOK * 3 * H_) +
      5 * ((size_t)NTOK * H_) +
      ((size_t)NTOK * V_) +
      3 * ((size_t)B_ * NH_ * S_) +
      2 * ((size_t)S_ * 32) +
      WT_FLOATS;
  if (ws_size < NEED * sizeof(float)) {
    k_zero<<<(NTOK * V_ + 255) / 256, 256, 0, stream>>>(logits, NTOK * V_);
    return;
  }

  float* f = (float*)d_ws;
  Ctx c;
  c.st = stream;
  c.Q = f;    f += (size_t)NTOK * 3 * H_;
  c.GU = f;   f += (size_t)NTOK * 2 * INNER_;
  c.dQ = f;   c.ACT = f;  f += (size_t)NTOK * 3 * H_;
  c.X1 = f;   f += (size_t)NTOK * H_;
  c.X2 = f;   f += (size_t)NTOK * H_;
  c.AO = f;   f += (size_t)NTOK * H_;
  c.G = f;    f += (size_t)NTOK * H_;
  c.UDX = f;  f += (size_t)NTOK * H_;
  c.P = f;    f += (size_t)NTOK * V_;
  c.MB = f;   f += (size_t)B_ * NH_ * S_;
  c.LB = f;   f += (size_t)B_ * NH_ * S_;
  c.DB = f;   f += (size_t)B_ * NH_ * S_;
  c.CS = f;   f += (size_t)S_ * 32;
  c.SN = f;   f += (size_t)S_ * 32;
  unsigned short* wt = (unsigned short*)f;

  const size_t LQKV = (size_t)H_ * 3 * H_;
  const size_t LO = (size_t)H_ * H_;
  const size_t LGU = (size_t)H_ * 2 * INNER_;
  const size_t LD = (size_t)INNER_ * H_;

  for (int l = 0; l < 2; ++l) {
    c.WTqkv[l] = wt;
    k_wt<<<dim3(3 * H_ / 32, H_ / 32), dim3(32, 8), 0, stream>>>(qkvw + l * LQKV, wt, H_, 3 * H_);
    wt += LQKV;
    c.WTo[l] = wt;
    k_wt<<<dim3(H_ / 32, H_ / 32), dim3(32, 8), 0, stream>>>(ow + l * LO, wt, H_, H_);
    wt += LO;
    c.WTgu[l] = wt;
    k_wt<<<dim3(2 * INNER_ / 32, H_ / 32), dim3(32, 8), 0, stream>>>(guw + l * LGU, wt, H_, 2 * INNER_);
    wt += LGU;
    c.WTd[l] = wt;
    k_wt<<<dim3(H_ / 32, INNER_ / 32), dim3(32, 8), 0, stream>>>(dw + l * LD, wt, INNER_, H_);
    wt += LD;
  }

  k_zero<<<(NTOK * V_ + 255) / 256, 256, 0, stream>>>(logits, NTOK * V_);
  k_rope_tables<<<(S_ * 32 + 255) / 256, 256, 0, stream>>>(c.CS, c.SN);

  for (int step = 0; step < STEPS_; ++step) {
    k_softmax_logits<<<(NTOK + 255) / 256, 256, 0, stream>>>(logits, c.P);
    k_h0<<<NTOK, 256, 0, stream>>>(c.P, E, inputs, c.X1);
    block_forward(c, 0, c.X1, c.UDX, qkvw, ow, guw, dw);
    k_gfill<<<(NTOK * H_ + 255) / 256, 256, 0, stream>>>(ew, c.G);
    block_backward(c, 1, c.UDX, qkvw + LQKV, ow + LO, guw + LGU, dw + LD);
    k_h0<<<NTOK, 256, 0, stream>>>(c.P, E, inputs, c.X1);
    block_backward(c, 0, c.X1, qkvw, ow, guw, dw);
    k_logits_update<<<NTOK, 64, 0, stream>>>(c.G, E, c.P, alpha, logits);
  }
}

// Round 7
// 3489.849 us; speedup vs baseline: 25.1247x; 1.6880x over previous
//
#include <hip/hip_runtime.h>
#include <math.h>

#define B_ 8
#define S_ 900
#define V_ 11
#define H_ 512
#define NH_ 8
#define HD_ 64
#define INNER_ 1536
#define STEPS_ 2
#define NTOK (B_*S_)
#define EPS_ 1e-5f
#define THETA_ 10000.0f
#define ESCALE_ 22.627416997969522f
#define SCALE_ 0.125f
#define PT_ 68

typedef __attribute__((ext_vector_type(8))) short bh8;
typedef __attribute__((ext_vector_type(4))) float f32x4;
typedef __attribute__((ext_vector_type(4))) unsigned short us4;
typedef unsigned short ushort_t;

union bfu { bh8 v; unsigned short s[8]; us4 q[2]; };

__device__ inline unsigned short f2bf(float x) {
  unsigned u = __builtin_bit_cast(unsigned, x);
  return (unsigned short)((u + 0x7FFFu + ((u >> 16) & 1u)) >> 16);
}
__device__ inline float b2f(unsigned short s) {
  return __builtin_bit_cast(float, (unsigned)s << 16);
}

__device__ inline bh8 lds16(const unsigned short* p) {
  bfu u;
  u.q[0] = *(const us4*)p;
  u.q[1] = *(const us4*)(p + 4);
  return u.v;
}
__device__ inline void sts16(unsigned short* p, bfu u) {
  *(us4*)p = u.q[0];
  *(us4*)(p + 4) = u.q[1];
}

__device__ inline float wave_sum64(float x) {
#pragma unroll
  for (int off = 32; off > 0; off >>= 1) x += __shfl_xor(x, off, 64);
  return x;
}

__device__ inline float quad_sum(float x) {
  x += __shfl_xor(x, 1, 64);
  x += __shfl_xor(x, 2, 64);
  return x;
}

// ---------------- small kernels ----------------

__global__ void k_zero(float* p, int n) {
  int i = blockIdx.x * blockDim.x + threadIdx.x;
  if (i < n) p[i] = 0.f;
}

__global__ void k_rope_tables(float* cs, float* sn) {
  int idx = blockIdx.x * blockDim.x + threadIdx.x;
  if (idx >= S_ * 32) return;
  int s = idx >> 5, i = idx & 31;
  float freq = powf(THETA_, -(float)i / 32.0f);
  float ang = (float)s * freq;
  cs[idx] = cosf(ang);
  sn[idx] = sinf(ang);
}

__global__ void k_softmax_logits(const float* __restrict__ logits, float* __restrict__ P) {
  int t = blockIdx.x * blockDim.x + threadIdx.x;
  if (t >= NTOK) return;
  float x[V_];
  float m = -1e30f;
#pragma unroll
  for (int v = 0; v < V_; ++v) { x[v] = logits[t * V_ + v]; m = fmaxf(m, x[v]); }
  float ssum = 0.f;
#pragma unroll
  for (int v = 0; v < V_; ++v) { x[v] = expf(x[v] - m); ssum += x[v]; }
  float inv = 1.f / ssum;
#pragma unroll
  for (int v = 0; v < V_; ++v) P[t * V_ + v] = x[v] * inv;
}

__global__ void k_h0(const float* __restrict__ P, const float* __restrict__ E,
                     const int* __restrict__ inp, float* __restrict__ h0) {
  int t = blockIdx.x;
  int tid = threadIdx.x;
  __shared__ float p[V_];
  __shared__ int iw;
  if (tid < V_) p[tid] = P[t * V_ + tid];
  if (tid == 0) iw = inp[t];
  __syncthreads();
  for (int h = tid; h < H_; h += blockDim.x) {
    float acc = E[iw * H_ + h];
#pragma unroll
    for (int v = 0; v < V_; ++v) acc += p[v] * E[v * H_ + h];
    h0[(size_t)t * H_ + h] = ESCALE_ * acc;
  }
}

__global__ void k_gfill(const float* __restrict__ ew, float* __restrict__ G) {
  int idx = blockIdx.x * blockDim.x + threadIdx.x;
  if (idx < NTOK * H_) G[idx] = ew[idx & (H_ - 1)];
}

// fp32 -> bf16 cast, 8 elems/thread
__global__ void k_cast8(const float* __restrict__ X, unsigned short* __restrict__ Y, int n8) {
  int i = blockIdx.x * blockDim.x + threadIdx.x;
  if (i >= n8) return;
  const float4* p = (const float4*)(X + (size_t)i * 8);
  float4 a = p[0], b = p[1];
  bfu o;
  o.s[0] = f2bf(a.x); o.s[1] = f2bf(a.y); o.s[2] = f2bf(a.z); o.s[3] = f2bf(a.w);
  o.s[4] = f2bf(b.x); o.s[5] = f2bf(b.y); o.s[6] = f2bf(b.z); o.s[7] = f2bf(b.w);
  *(bh8*)(Y + (size_t)i * 8) = o.v;
}

// ---------------- weight transpose-convert: W[K][N] fp32 -> WT[N][K] bf16 ----------------

__global__ void k_wt(const float* __restrict__ W, unsigned short* __restrict__ WT, int K, int N) {
  __shared__ float t[32][33];
  int k0 = blockIdx.y * 32, n0 = blockIdx.x * 32;
  int tx = threadIdx.x, ty = threadIdx.y;
#pragma unroll
  for (int i = 0; i < 4; ++i)
    t[ty + 8 * i][tx] = W[(size_t)(k0 + ty + 8 * i) * N + n0 + tx];
  __syncthreads();
#pragma unroll
  for (int i = 0; i < 4; ++i)
    WT[(size_t)(n0 + ty + 8 * i) * K + k0 + tx] = f2bf(t[tx][ty + 8 * i]);
}

// ---------------- MFMA GEMM: C[M,N] = A[M,K] @ B^T (B stored [N][K]) ----------------
// BSRC: 1 = B bf16 (pre-transposed weights), 0 = B fp32 (weights as stored).
// ABF: A is bf16. SILU_A: A = silu(gate)*up pairs (requires ABF). ADD: += D. CBF: C bf16.

template <int BSRC, int ABF, int SILU_A, int ADD, int CBF>
__global__ __launch_bounds__(256) void k_gemm(const float* __restrict__ Af,
                                              const unsigned short* __restrict__ A16,
                                              const float* __restrict__ Bf,
                                              const unsigned short* __restrict__ Bt,
                                              const float* __restrict__ Dm,
                                              float* __restrict__ Cf,
                                              unsigned short* __restrict__ C16,
                                              int M, int N, int K, int lda) {
  __shared__ unsigned short As[128][40];
  __shared__ unsigned short Bs[128][40];
  int tid = threadIdx.x;
  int m0 = blockIdx.y * 128, n0 = blockIdx.x * 128;
  int wid = tid >> 6, lane = tid & 63;
  int wr = (wid >> 1) * 64, wc = (wid & 1) * 64;
  int lr = lane & 15, lg = lane >> 4;
  f32x4 acc[4][4] = {};
  for (int k0 = 0; k0 < K; k0 += 32) {
    __syncthreads();
#pragma unroll
    for (int i = 0; i < 2; ++i) {
      int cidx = tid + 256 * i;
      int row = cidx >> 2, ck = (cidx & 3) * 8;
      int gr = m0 + row; gr = gr < M ? gr : M - 1;
      if (ABF) {
        const unsigned short* src = &A16[(size_t)gr * lda + k0 + ck];
        if (SILU_A) {
          bfu pa;
#pragma unroll
          for (int j = 0; j < 8; ++j) {
            float g = b2f(src[j]), u = b2f(src[INNER_ + j]);
            pa.s[j] = f2bf((g / (1.f + __expf(-g))) * u);
          }
          *(bh8*)&As[row][ck] = pa.v;
        } else {
          *(bh8*)&As[row][ck] = *(const bh8*)src;
        }
      } else {
        const float* src = &Af[(size_t)gr * lda + k0 + ck];
        bfu pa;
#pragma unroll
        for (int j = 0; j < 8; ++j) pa.s[j] = f2bf(src[j]);
        *(bh8*)&As[row][ck] = pa.v;
      }
      if (BSRC == 0) {
        const float* bs = &Bf[(size_t)(n0 + row) * K + k0 + ck];
        bfu pb;
#pragma unroll
        for (int j = 0; j < 8; ++j) pb.s[j] = f2bf(bs[j]);
        *(bh8*)&Bs[row][ck] = pb.v;
      } else {
        *(bh8*)&Bs[row][ck] = *(const bh8*)&Bt[(size_t)(n0 + row) * K + k0 + ck];
      }
    }
    __syncthreads();
    bh8 av[4], bv[4];
#pragma unroll
    for (int f = 0; f < 4; ++f) {
      av[f] = *(const bh8*)&As[wr + f * 16 + lr][lg * 8];
      bv[f] = *(const bh8*)&Bs[wc + f * 16 + lr][lg * 8];
    }
#pragma unroll
    for (int fr = 0; fr < 4; ++fr)
#pragma unroll
      for (int fc = 0; fc < 4; ++fc)
        acc[fr][fc] = __builtin_amdgcn_mfma_f32_16x16x32_bf16(av[fr], bv[fc], acc[fr][fc], 0, 0, 0);
  }
#pragma unroll
  for (int fr = 0; fr < 4; ++fr) {
    int r0 = m0 + wr + fr * 16 + lg * 4;
#pragma unroll
    for (int i = 0; i < 4; ++i) {
      int gr = r0 + i;
      if (gr >= M) continue;
#pragma unroll
      for (int fc = 0; fc < 4; ++fc) {
        int gc = n0 + wc + fc * 16 + lr;
        float out = acc[fr][fc][i];
        if (ADD) out += Dm[(size_t)gr * N + gc];
        if (CBF) C16[(size_t)gr * N + gc] = f2bf(out);
        else Cf[(size_t)gr * N + gc] = out;
      }
    }
  }
}

// ---------------- RoPE fwd/bwd on bf16 qkv ----------------

template <int BWD>
__global__ void k_rope(unsigned short* __restrict__ Q, const float* __restrict__ cs,
                       const float* __restrict__ sn) {
  int idx = blockIdx.x * blockDim.x + threadIdx.x;
  if (idx >= NTOK * NH_ * 2 * 32) return;
  int i = idx & 31;
  int h = (idx >> 5) & (NH_ - 1);
  int part = (idx >> 8) & 1;
  int t = idx >> 9;
  int s = t % S_;
  float c = cs[s * 32 + i], sv = sn[s * 32 + i];
  size_t base = ((size_t)t * 3 * NH_ + part * NH_ + h) * HD_;
  float x1 = b2f(Q[base + i]), x2 = b2f(Q[base + 32 + i]);
  if (!BWD) {
    Q[base + i] = f2bf(x1 * c - x2 * sv);
    Q[base + 32 + i] = f2bf(x2 * c + x1 * sv);
  } else {
    Q[base + i] = f2bf(x1 * c + x2 * sv);
    Q[base + 32 + i] = f2bf(x2 * c - x1 * sv);
  }
}

// ---------------- MFMA flash attention (bf16 QKV) ----------------
// QKV16 layout [t][24][64] ushorts: Q at slot h, K at 8+h, V at 16+h.

__global__ __launch_bounds__(256) void k_attn_fwd3(const unsigned short* __restrict__ QKV,
                                                   float* __restrict__ AO,
                                                   float* __restrict__ MB,
                                                   float* __restrict__ LB) {
  __shared__ unsigned short Ks[64][PT_];
  __shared__ unsigned short VT[64][PT_];
  __shared__ unsigned short Ps[4][16][PT_];
  int tid = threadIdx.x;
  int h = blockIdx.y, b = blockIdx.z;
  int w = tid >> 6, lane = tid & 63;
  int lr = lane & 15, lg = lane >> 4;
  int q0 = blockIdx.x * 64 + w * 16;

  bh8 qf[2];
  {
    int qr = q0 + lr; if (qr >= S_) qr = S_ - 1;
    const unsigned short* qp = &QKV[((size_t)(b * S_ + qr) * 24 + h) * 64 + lg * 8];
    qf[0] = *(const bh8*)qp;
    qf[1] = *(const bh8*)(qp + 32);
  }
  f32x4 accO[4] = {};
  float m[4], lsum[4];
#pragma unroll
  for (int i = 0; i < 4; ++i) { m[i] = -1e30f; lsum[i] = 0.f; }

  for (int kt = 0; kt < S_; kt += 64) {
    __syncthreads();
    {  // stage K rows (clamped)
      int r = tid >> 2, c0 = (tid & 3) * 16;
      int src = kt + r;
      size_t ts = (size_t)b * S_ + (src < S_ ? src : S_ - 1);
      const unsigned short* gp = &QKV[(ts * 24 + 8 + h) * 64 + c0];
      bfu p0, p1;
      p0.v = *(const bh8*)gp;
      p1.v = *(const bh8*)(gp + 8);
      sts16(&Ks[r][c0], p0);
      sts16(&Ks[r][c0 + 8], p1);
    }
    {  // stage V^T (clamped)
      int d0 = (tid & 15) * 4, k0r = (tid >> 4) * 4;
      us4 rv[4];
#pragma unroll
      for (int j = 0; j < 4; ++j) {
        int src = kt + k0r + j;
        size_t ts = (size_t)b * S_ + (src < S_ ? src : S_ - 1);
        rv[j] = *(const us4*)&QKV[(ts * 24 + 16 + h) * 64 + d0];
      }
#pragma unroll
      for (int dd = 0; dd < 4; ++dd) {
        us4 pk = {rv[0][dd], rv[1][dd], rv[2][dd], rv[3][dd]};
        *(us4*)&VT[d0 + dd][k0r] = pk;
      }
    }
    __syncthreads();
    f32x4 accS[4] = {};
#pragma unroll
    for (int ks = 0; ks < 2; ++ks)
#pragma unroll
      for (int fk = 0; fk < 4; ++fk)
        accS[fk] = __builtin_amdgcn_mfma_f32_16x16x32_bf16(qf[ks], lds16(&Ks[fk * 16 + lr][ks * 32 + lg * 8]), accS[fk], 0, 0, 0);
    float sc[4][4], pmax[4];
#pragma unroll
    for (int i = 0; i < 4; ++i) pmax[i] = -1e30f;
#pragma unroll
    for (int fk = 0; fk < 4; ++fk)
#pragma unroll
      for (int i = 0; i < 4; ++i) {
        float s = accS[fk][i] * SCALE_;
        if (kt + fk * 16 + lr >= S_) s = -1e30f;
        sc[fk][i] = s;
        pmax[i] = fmaxf(pmax[i], s);
      }
#pragma unroll
    for (int i = 0; i < 4; ++i) {
      float v = pmax[i];
      v = fmaxf(v, __shfl_xor(v, 1, 64));
      v = fmaxf(v, __shfl_xor(v, 2, 64));
      v = fmaxf(v, __shfl_xor(v, 4, 64));
      v = fmaxf(v, __shfl_xor(v, 8, 64));
      pmax[i] = v;
    }
    float psum[4];
#pragma unroll
    for (int i = 0; i < 4; ++i) {
      float mn = fmaxf(m[i], pmax[i]);
      float eo = __expf(m[i] - mn);
      m[i] = mn;
      lsum[i] *= eo;
#pragma unroll
      for (int fd = 0; fd < 4; ++fd) accO[fd][i] *= eo;
      psum[i] = 0.f;
    }
#pragma unroll
    for (int fk = 0; fk < 4; ++fk)
#pragma unroll
      for (int i = 0; i < 4; ++i) {
        float p = __expf(sc[fk][i] - m[i]);
        sc[fk][i] = p;
        psum[i] += p;
      }
#pragma unroll
    for (int i = 0; i < 4; ++i) {
      float v = psum[i];
      v += __shfl_xor(v, 1, 64);
      v += __shfl_xor(v, 2, 64);
      v += __shfl_xor(v, 4, 64);
      v += __shfl_xor(v, 8, 64);
      lsum[i] += v;
    }
#pragma unroll
    for (int fk = 0; fk < 4; ++fk)
#pragma unroll
      for (int i = 0; i < 4; ++i)
        Ps[w][lg * 4 + i][fk * 16 + lr] = f2bf(sc[fk][i]);
#pragma unroll
    for (int ks = 0; ks < 2; ++ks) {
      bh8 ap = lds16(&Ps[w][lr][ks * 32 + lg * 8]);
#pragma unroll
      for (int fd = 0; fd < 4; ++fd)
        accO[fd] = __builtin_amdgcn_mfma_f32_16x16x32_bf16(ap, lds16(&VT[fd * 16 + lr][ks * 32 + lg * 8]), accO[fd], 0, 0, 0);
    }
  }
#pragma unroll
  for (int i = 0; i < 4; ++i) {
    int q = q0 + lg * 4 + i;
    if (q < S_) {
      float linv = 1.f / lsum[i];
      size_t obase = (size_t)(b * S_ + q) * H_ + h * 64;
#pragma unroll
      for (int fd = 0; fd < 4; ++fd) AO[obase + fd * 16 + lr] = accO[fd][i] * linv;
      if (lr == 0) {
        MB[((size_t)b * NH_ + h) * S_ + q] = m[i];
        LB[((size_t)b * NH_ + h) * S_ + q] = linv;
      }
    }
  }
}

__global__ __launch_bounds__(256) void k_delta(const float* __restrict__ O,
                                               const float* __restrict__ dO,
                                               float* __restrict__ DB) {
  int tid = threadIdx.x;
  int h = blockIdx.y, b = blockIdx.z;
  int r = blockIdx.x * 64 + (tid >> 2), part = tid & 3;
  if (r >= S_) return;
  size_t base = (size_t)(b * S_ + r) * H_ + h * 64 + part * 16;
  const float4* op = (const float4*)&O[base];
  const float4* dp = (const float4*)&dO[base];
  float s = 0.f;
#pragma unroll
  for (int i = 0; i < 4; ++i) {
    float4 a = op[i], d = dp[i];
    s += a.x * d.x + a.y * d.y + a.z * d.z + a.w * d.w;
  }
  s = quad_sum(s);
  if (part == 0) DB[((size_t)b * NH_ + h) * S_ + r] = s;
}

// dQ pass (bf16 QKV, bf16 dO, bf16 dQKV out)
__global__ __launch_bounds__(256) void k_attn_bwd_dq3(const unsigned short* __restrict__ QKV,
                                                      const unsigned short* __restrict__ dO,
                                                      const float* __restrict__ MB,
                                                      const float* __restrict__ LB,
                                                      const float* __restrict__ DB,
                                                      unsigned short* __restrict__ dQKV) {
  __shared__ unsigned short Ks[64][PT_];
  __shared__ unsigned short Vs[64][PT_];
  __shared__ unsigned short KT[64][PT_];
  __shared__ unsigned short Ps[4][16][PT_];
  int tid = threadIdx.x;
  int h = blockIdx.y, b = blockIdx.z;
  int w = tid >> 6, lane = tid & 63;
  int lr = lane & 15, lg = lane >> 4;
  int q0 = blockIdx.x * 64 + w * 16;
  size_t sbase = ((size_t)b * NH_ + h) * S_;

  bh8 qf[2], dof[2];
  {
    int qr = q0 + lr; if (qr >= S_) qr = S_ - 1;
    const unsigned short* qp = &QKV[((size_t)(b * S_ + qr) * 24 + h) * 64 + lg * 8];
    const unsigned short* dp = &dO[(size_t)(b * S_ + qr) * H_ + h * 64 + lg * 8];
    qf[0] = *(const bh8*)qp;  qf[1] = *(const bh8*)(qp + 32);
    dof[0] = *(const bh8*)dp; dof[1] = *(const bh8*)(dp + 32);
  }
  float mrow[4], lrow[4], drow[4];
#pragma unroll
  for (int i = 0; i < 4; ++i) {
    int q = q0 + lg * 4 + i; if (q >= S_) q = S_ - 1;
    mrow[i] = MB[sbase + q];
    lrow[i] = LB[sbase + q];
    drow[i] = DB[sbase + q];
  }
  f32x4 accQ[4] = {};

  for (int kt = 0; kt < S_; kt += 64) {
    __syncthreads();
    {  // stage K, V rows (zeroed past S_)
      int r = tid >> 2, c0 = (tid & 3) * 16;
      int src = kt + r;
      bool vld = src < S_;
      size_t ts = (size_t)b * S_ + (vld ? src : S_ - 1);
      const unsigned short* kp = &QKV[(ts * 24 + 8 + h) * 64 + c0];
      bfu p0{}, p1{}, p2{}, p3{};
      if (vld) {
        p0.v = *(const bh8*)kp;
        p1.v = *(const bh8*)(kp + 8);
        p2.v = *(const bh8*)(kp + 512);
        p3.v = *(const bh8*)(kp + 520);
      }
      sts16(&Ks[r][c0], p0); sts16(&Ks[r][c0 + 8], p1);
      sts16(&Vs[r][c0], p2); sts16(&Vs[r][c0 + 8], p3);
    }
    {  // stage K^T (zeroed past S_)
      int d0 = (tid & 15) * 4, k0r = (tid >> 4) * 4;
      us4 rv[4];
#pragma unroll
      for (int j = 0; j < 4; ++j) {
        int src = kt + k0r + j;
        bool vld = src < S_;
        size_t ts = (size_t)b * S_ + (vld ? src : S_ - 1);
        us4 t = *(const us4*)&QKV[(ts * 24 + 8 + h) * 64 + d0];
        if (!vld) t = us4{0, 0, 0, 0};
        rv[j] = t;
      }
#pragma unroll
      for (int dd = 0; dd < 4; ++dd) {
        us4 pk = {rv[0][dd], rv[1][dd], rv[2][dd], rv[3][dd]};
        *(us4*)&KT[d0 + dd][k0r] = pk;
      }
    }
    __syncthreads();
    f32x4 aS[4] = {}, aD[4] = {};
#pragma unroll
    for (int ks = 0; ks < 2; ++ks)
#pragma unroll
      for (int fk = 0; fk < 4; ++fk) {
        aS[fk] = __builtin_amdgcn_mfma_f32_16x16x32_bf16(qf[ks], lds16(&Ks[fk * 16 + lr][ks * 32 + lg * 8]), aS[fk], 0, 0, 0);
        aD[fk] = __builtin_amdgcn_mfma_f32_16x16x32_bf16(dof[ks], lds16(&Vs[fk * 16 + lr][ks * 32 + lg * 8]), aD[fk], 0, 0, 0);
      }
#pragma unroll
    for (int fk = 0; fk < 4; ++fk)
#pragma unroll
      for (int i = 0; i < 4; ++i) {
        float p = __expf(aS[fk][i] * SCALE_ - mrow[i]) * lrow[i];
        float ds = p * (aD[fk][i] - drow[i]);
        Ps[w][lg * 4 + i][fk * 16 + lr] = f2bf(ds);
      }
#pragma unroll
    for (int ks = 0; ks < 2; ++ks) {
      bh8 ap = lds16(&Ps[w][lr][ks * 32 + lg * 8]);
#pragma unroll
      for (int fd = 0; fd < 4; ++fd)
        accQ[fd] = __builtin_amdgcn_mfma_f32_16x16x32_bf16(ap, lds16(&KT[fd * 16 + lr][ks * 32 + lg * 8]), accQ[fd], 0, 0, 0);
    }
  }
#pragma unroll
  for (int i = 0; i < 4; ++i) {
    int q = q0 + lg * 4 + i;
    if (q < S_) {
      size_t obase = ((size_t)(b * S_ + q) * 24 + h) * 64;
#pragma unroll
      for (int fd = 0; fd < 4; ++fd) dQKV[obase + fd * 16 + lr] = f2bf(SCALE_ * accQ[fd][i]);
    }
  }
}

// dK + dV pass
__global__ __launch_bounds__(256) void k_attn_bwd_kv3(const unsigned short* __restrict__ QKV,
                                                      const unsigned short* __restrict__ dO,
                                                      const float* __restrict__ MB,
                                                      const float* __restrict__ LB,
                                                      const float* __restrict__ DB,
                                                      unsigned short* __restrict__ dQKV) {
  __shared__ unsigned short Qs[64][PT_];
  __shared__ unsigned short dOs[64][PT_];
  __shared__ unsigned short QT[64][PT_];
  __shared__ unsigned short dOT[64][PT_];
  __shared__ unsigned short Ps[4][16][PT_];
  __shared__ float sM[64], sL[64], sD[64];
  int tid = threadIdx.x;
  int h = blockIdx.y, b = blockIdx.z;
  int w = tid >> 6, lane = tid & 63;
  int lr = lane & 15, lg = lane >> 4;
  int k0w = blockIdx.x * 64 + w * 16;
  size_t sbase = ((size_t)b * NH_ + h) * S_;

  bh8 kf[2], vf[2];
  {
    int kr = k0w + lr; if (kr >= S_) kr = S_ - 1;
    const unsigned short* kp = &QKV[((size_t)(b * S_ + kr) * 24 + 8 + h) * 64 + lg * 8];
    kf[0] = *(const bh8*)kp;        kf[1] = *(const bh8*)(kp + 32);
    vf[0] = *(const bh8*)(kp + 512); vf[1] = *(const bh8*)(kp + 544);
  }
  f32x4 accK[4] = {}, accV[4] = {};

  for (int qt = 0; qt < S_; qt += 64) {
    __syncthreads();
    {  // stage Q (clamped), dO (zeroed)
      int r = tid >> 2, c0 = (tid & 3) * 16;
      int src = qt + r;
      bool vld = src < S_;
      size_t ts = (size_t)b * S_ + (vld ? src : S_ - 1);
      const unsigned short* qp = &QKV[(ts * 24 + h) * 64 + c0];
      const unsigned short* dp = &dO[ts * H_ + h * 64 + c0];
      bfu p0, p1, p2{}, p3{};
      p0.v = *(const bh8*)qp;
      p1.v = *(const bh8*)(qp + 8);
      if (vld) {
        p2.v = *(const bh8*)dp;
        p3.v = *(const bh8*)(dp + 8);
      }
      sts16(&Qs[r][c0], p0);  sts16(&Qs[r][c0 + 8], p1);
      sts16(&dOs[r][c0], p2); sts16(&dOs[r][c0 + 8], p3);
    }
    {  // stage Q^T (clamped), dO^T (zeroed)
      int d0 = (tid & 15) * 4, q0r = (tid >> 4) * 4;
      us4 rq[4], rd[4];
#pragma unroll
      for (int j = 0; j < 4; ++j) {
        int src = qt + q0r + j;
        bool vld = src < S_;
        size_t ts = (size_t)b * S_ + (vld ? src : S_ - 1);
        rq[j] = *(const us4*)&QKV[(ts * 24 + h) * 64 + d0];
        us4 td = *(const us4*)&dO[ts * H_ + h * 64 + d0];
        if (!vld) td = us4{0, 0, 0, 0};
        rd[j] = td;
      }
#pragma unroll
      for (int dd = 0; dd < 4; ++dd) {
        us4 pq = {rq[0][dd], rq[1][dd], rq[2][dd], rq[3][dd]};
        us4 pd = {rd[0][dd], rd[1][dd], rd[2][dd], rd[3][dd]};
        *(us4*)&QT[d0 + dd][q0r] = pq;
        *(us4*)&dOT[d0 + dd][q0r] = pd;
      }
    }
    if (tid < 64) {
      int src = qt + tid;
      bool vld = src < S_;
      int sc = vld ? src : S_ - 1;
      sM[tid] = MB[sbase + sc];
      sL[tid] = LB[sbase + sc];
      sD[tid] = vld ? DB[sbase + sc] : 0.f;
    }
    __syncthreads();
    f32x4 aS[4] = {}, aD[4] = {};
#pragma unroll
    for (int ks = 0; ks < 2; ++ks)
#pragma unroll
      for (int fq = 0; fq < 4; ++fq) {
        aS[fq] = __builtin_amdgcn_mfma_f32_16x16x32_bf16(kf[ks], lds16(&Qs[fq * 16 + lr][ks * 32 + lg * 8]), aS[fq], 0, 0, 0);
        aD[fq] = __builtin_amdgcn_mfma_f32_16x16x32_bf16(vf[ks], lds16(&dOs[fq * 16 + lr][ks * 32 + lg * 8]), aD[fq], 0, 0, 0);
      }
    float pv[4][4];
#pragma unroll
    for (int fq = 0; fq < 4; ++fq) {
      float mq = sM[fq * 16 + lr], lq = sL[fq * 16 + lr];
#pragma unroll
      for (int i = 0; i < 4; ++i) {
        float p = __expf(aS[fq][i] * SCALE_ - mq) * lq;
        pv[fq][i] = p;
        Ps[w][lg * 4 + i][fq * 16 + lr] = f2bf(p);
      }
    }
#pragma unroll
    for (int qs = 0; qs < 2; ++qs) {
      bh8 ap = lds16(&Ps[w][lr][qs * 32 + lg * 8]);
#pragma unroll
      for (int fd = 0; fd < 4; ++fd)
        accV[fd] = __builtin_amdgcn_mfma_f32_16x16x32_bf16(ap, lds16(&dOT[fd * 16 + lr][qs * 32 + lg * 8]), accV[fd], 0, 0, 0);
    }
#pragma unroll
    for (int fq = 0; fq < 4; ++fq) {
      float dq = sD[fq * 16 + lr];
#pragma unroll
      for (int i = 0; i < 4; ++i)
        Ps[w][lg * 4 + i][fq * 16 + lr] = f2bf(pv[fq][i] * (aD[fq][i] - dq));
    }
#pragma unroll
    for (int qs = 0; qs < 2; ++qs) {
      bh8 ap = lds16(&Ps[w][lr][qs * 32 + lg * 8]);
#pragma unroll
      for (int fd = 0; fd < 4; ++fd)
        accK[fd] = __builtin_amdgcn_mfma_f32_16x16x32_bf16(ap, lds16(&QT[fd * 16 + lr][qs * 32 + lg * 8]), accK[fd], 0, 0, 0);
    }
  }
#pragma unroll
  for (int i = 0; i < 4; ++i) {
    int k = k0w + lg * 4 + i;
    if (k < S_) {
      size_t obase = ((size_t)(b * S_ + k) * 24 + 8 + h) * 64;
#pragma unroll
      for (int fd = 0; fd < 4; ++fd) {
        dQKV[obase + fd * 16 + lr] = f2bf(SCALE_ * accK[fd][i]);
        dQKV[obase + 512 + fd * 16 + lr] = f2bf(accV[fd][i]);
      }
    }
  }
}

// ---------------- RMS norm fwd/bwd ----------------

__global__ __launch_bounds__(256) void k_rms_fwd(const float* __restrict__ X, float* __restrict__ Y) {
  int t = blockIdx.x, tid = threadIdx.x;
  float x0 = X[(size_t)t * H_ + tid], x1 = X[(size_t)t * H_ + tid + 256];
  __shared__ float red[256];
  red[tid] = x0 * x0 + x1 * x1;
  __syncthreads();
  for (int s = 128; s > 0; s >>= 1) {
    if (tid < s) red[tid] += red[tid + s];
    __syncthreads();
  }
  float r = rsqrtf(red[0] / H_ + EPS_);
  Y[(size_t)t * H_ + tid] = x0 * r;
  Y[(size_t)t * H_ + tid + 256] = x1 * r;
}

__global__ __launch_bounds__(256) void k_rms_bwd(const float* __restrict__ X,
                                                 const float* __restrict__ GY,
                                                 float* __restrict__ GX) {
  int t = blockIdx.x, tid = threadIdx.x;
  float x0 = X[(size_t)t * H_ + tid], x1 = X[(size_t)t * H_ + tid + 256];
  float g0 = GY[(size_t)t * H_ + tid], g1 = GY[(size_t)t * H_ + tid + 256];
  __shared__ float r1[256], r2[256];
  r1[tid] = x0 * x0 + x1 * x1;
  r2[tid] = x0 * g0 + x1 * g1;
  __syncthreads();
  for (int s = 128; s > 0; s >>= 1) {
    if (tid < s) { r1[tid] += r1[tid + s]; r2[tid] += r2[tid + s]; }
    __syncthreads();
  }
  float r = rsqrtf(r1[0] / H_ + EPS_);
  float coef = r * r * r * r2[0] / (float)H_;
  GX[(size_t)t * H_ + tid] = r * g0 - coef * x0;
  GX[(size_t)t * H_ + tid + 256] = r * g1 - coef * x1;
}

// ---------------- SiLU-gate backward (bf16 GU in place), 8 elems/thread ----------------

__global__ void k_silu_bwd(unsigned short* __restrict__ GU, const float* __restrict__ dact) {
  int idx = blockIdx.x * blockDim.x + threadIdx.x;
  if (idx >= NTOK * INNER_ / 8) return;
  int t = idx / (INNER_ / 8), i8 = (idx % (INNER_ / 8)) * 8;
  size_t gb = (size_t)t * 2 * INNER_;
  bfu g8, u8, og, ou;
  g8.v = *(const bh8*)&GU[gb + i8];
  u8.v = *(const bh8*)&GU[gb + INNER_ + i8];
  const float* da = &dact[(size_t)t * INNER_ + i8];
#pragma unroll
  for (int j = 0; j < 8; ++j) {
    float g = b2f(g8.s[j]), u = b2f(u8.s[j]), d = da[j];
    float sig = 1.f / (1.f + __expf(-g));
    og.s[j] = f2bf(d * u * sig * (1.f + g * (1.f - sig)));
    ou.s[j] = f2bf(d * g * sig);
  }
  *(bh8*)&GU[gb + i8] = og.v;
  *(bh8*)&GU[gb + INNER_ + i8] = ou.v;
}

// ---------------- logits update ----------------

__global__ __launch_bounds__(64) void k_logits_update(const float* __restrict__ G,
                                                      const float* __restrict__ E,
                                                      const float* __restrict__ P,
                                                      const float* __restrict__ alpha,
                                                      float* __restrict__ logits) {
  int t = blockIdx.x, lane = threadIdx.x;
  float dp[V_];
#pragma unroll
  for (int v = 0; v < V_; ++v) dp[v] = 0.f;
  for (int hh = lane; hh < H_; hh += 64) {
    float gh = G[(size_t)t * H_ + hh];
#pragma unroll
    for (int v = 0; v < V_; ++v) dp[v] += gh * E[v * H_ + hh];
  }
#pragma unroll
  for (int v = 0; v < V_; ++v) dp[v] = wave_sum64(dp[v]) * ESCALE_;
  float dot = 0.f;
  float pv[V_];
#pragma unroll
  for (int v = 0; v < V_; ++v) {
    pv[v] = P[t * V_ + v];
    dot += pv[v] * dp[v];
  }
  float a = fmaxf(alpha[0], 1e-4f);
  if (lane < V_) logits[t * V_ + lane] -= a * pv[lane] * (dp[lane] - dot);
}

// ---------------- host-side orchestration ----------------
// bf16: Q16/Q016 (qkv), dQ16 (aliased with fp32 ACT), GU16, DO16.
// L0 attention checkpoint: Q016/AO0/MB0/LB0 written once per step by the initial forward;
// backward L0 skips qkv GEMM + rope + attn fwd.

struct Ctx {
  unsigned short *Q16, *Q016, *dQ16, *GU16, *DO16;
  float *ACT, *X1, *X2, *AO, *AO0, *G, *UDX, *P, *MB, *LB, *DB, *MB0, *LB0, *CS, *SN;
  const unsigned short *WTqkv[2], *WTo[2], *WTgu[2], *WTd[2];
  hipStream_t st;
};

static inline dim3 ggrid(int M, int N) { return dim3(N / 128, (M + 127) / 128); }

static void block_forward(Ctx& c, int l, const float* hin, float* hout,
                          unsigned short* qb, float* ao, float* mb, float* lb, bool skip_attn) {
  if (!skip_attn) {
    k_gemm<1, 0, 0, 0, 1><<<ggrid(NTOK, 3 * H_), 256, 0, c.st>>>(
        hin, nullptr, nullptr, c.WTqkv[l], nullptr, nullptr, qb, NTOK, 3 * H_, H_, H_);
    k_rope<0><<<(NTOK * NH_ * 2 * 32 + 255) / 256, 256, 0, c.st>>>(qb, c.CS, c.SN);
    k_attn_fwd3<<<dim3((S_ + 63) / 64, NH_, B_), 256, 0, c.st>>>(qb, ao, mb, lb);
  }
  k_gemm<1, 0, 0, 1, 0><<<ggrid(NTOK, H_), 256, 0, c.st>>>(
      ao, nullptr, nullptr, c.WTo[l], hin, c.X1, nullptr, NTOK, H_, H_, H_);
  k_rms_fwd<<<NTOK, 256, 0, c.st>>>(c.X1, c.UDX);
  k_gemm<1, 0, 0, 0, 1><<<ggrid(NTOK, 2 * INNER_), 256, 0, c.st>>>(
      c.UDX, nullptr, nullptr, c.WTgu[l], nullptr, nullptr, c.GU16, NTOK, 2 * INNER_, H_, H_);
  k_gemm<1, 1, 1, 1, 0><<<ggrid(NTOK, H_), 256, 0, c.st>>>(
      nullptr, c.GU16, nullptr, c.WTd[l], c.UDX, c.X2, nullptr, NTOK, H_, INNER_, 2 * INNER_);
  if (hout) k_rms_fwd<<<NTOK, 256, 0, c.st>>>(c.X2, hout);
}

static void block_backward(Ctx& c, int l, const float* hin,
                           unsigned short* qb, float* ao, float* mb, float* lb, bool skip_attn,
                           const float* wqkv, const float* wo, const float* wgu, const float* wd) {
  block_forward(c, l, hin, nullptr, qb, ao, mb, lb, skip_attn);
  k_rms_bwd<<<NTOK, 256, 0, c.st>>>(c.X2, c.G, c.UDX);
  k_gemm<0, 0, 0, 0, 0><<<ggrid(NTOK, INNER_), 256, 0, c.st>>>(
      c.UDX, nullptr, wd, nullptr, nullptr, c.ACT, nullptr, NTOK, INNER_, H_, H_);
  k_silu_bwd<<<(NTOK * INNER_ / 8 + 255) / 256, 256, 0, c.st>>>(c.GU16, c.ACT);
  k_gemm<0, 1, 0, 1, 0><<<ggrid(NTOK, H_), 256, 0, c.st>>>(
      nullptr, c.GU16, wgu, nullptr, c.UDX, c.G, nullptr, NTOK, H_, 2 * INNER_, 2 * INNER_);
  k_rms_bwd<<<NTOK, 256, 0, c.st>>>(c.X1, c.G, c.UDX);
  k_gemm<0, 0, 0, 0, 0><<<ggrid(NTOK, H_), 256, 0, c.st>>>(
      c.UDX, nullptr, wo, nullptr, nullptr, c.X2, nullptr, NTOK, H_, H_, H_);
  k_cast8<<<(NTOK * H_ / 8 + 255) / 256, 256, 0, c.st>>>(c.X2, c.DO16, NTOK * H_ / 8);
  dim3 agrid((S_ + 63) / 64, NH_, B_);
  k_delta<<<agrid, 256, 0, c.st>>>(ao, c.X2, c.DB);
  k_attn_bwd_dq3<<<agrid, 256, 0, c.st>>>(qb, c.DO16, mb, lb, c.DB, c.dQ16);
  k_attn_bwd_kv3<<<agrid, 256, 0, c.st>>>(qb, c.DO16, mb, lb, c.DB, c.dQ16);
  k_rope<1><<<(NTOK * NH_ * 2 * 32 + 255) / 256, 256, 0, c.st>>>(c.dQ16, c.CS, c.SN);
  k_gemm<0, 1, 0, 1, 0><<<ggrid(NTOK, H_), 256, 0, c.st>>>(
      nullptr, c.dQ16, wqkv, nullptr, c.UDX, c.G, nullptr, NTOK, H_, 3 * H_, 3 * H_);
}

extern "C" void kernel_launch(void* const* d_in, const int* in_sizes, int n_in,
                              void* d_out, int out_size, void* d_ws, size_t ws_size,
                              hipStream_t stream) {
  const int* inputs = (const int*)d_in[0];
  const float* E = (const float*)d_in[2];
  const float* ew = (const float*)d_in[3];
  const float* qkvw = (const float*)d_in[4];
  const float* ow = (const float*)d_in[5];
  const float* guw = (const float*)d_in[6];
  const float* dw = (const float*)d_in[7];
  const float* alpha = (const float*)d_in[8];
  float* logits = (float*)d_out;

  const size_t WT_FLOATS = 3407872;
  const size_t NEED =
      2 * ((size_t)NTOK * 3 * H_ / 2) +  // Q16, Q016 (bf16)
      ((size_t)NTOK * INNER_) +          // GU16 (bf16, 2*INNER wide)
      ((size_t)NTOK * INNER_) +          // ACT fp32 (aliases dQ16 bf16)
      6 * ((size_t)NTOK * H_) +          // X1, X2, AO, AO0, G, UDX
      ((size_t)NTOK * H_ / 2) +          // DO16 (bf16)
      ((size_t)NTOK * V_) +              // P
      5 * ((size_t)B_ * NH_ * S_) +      // MB, LB, DB, MB0, LB0
      2 * ((size_t)S_ * 32) +            // CS, SN
      WT_FLOATS;                         // bf16 transposed weights
  if (ws_size < NEED * sizeof(float)) {
    k_zero<<<(NTOK * V_ + 255) / 256, 256, 0, stream>>>(logits, NTOK * V_);
    return;
  }

  float* f = (float*)d_ws;
  Ctx c;
  c.st = stream;
  c.Q16 = (unsigned short*)f;  f += (size_t)NTOK * 3 * H_ / 2;
  c.Q016 = (unsigned short*)f; f += (size_t)NTOK * 3 * H_ / 2;
  c.GU16 = (unsigned short*)f; f += (size_t)NTOK * INNER_;
  c.ACT = f; c.dQ16 = (unsigned short*)f; f += (size_t)NTOK * INNER_;
  c.X1 = f;   f += (size_t)NTOK * H_;
  c.X2 = f;   f += (size_t)NTOK * H_;
  c.AO = f;   f += (size_t)NTOK * H_;
  c.AO0 = f;  f += (size_t)NTOK * H_;
  c.G = f;    f += (size_t)NTOK * H_;
  c.UDX = f;  f += (size_t)NTOK * H_;
  c.DO16 = (unsigned short*)f; f += (size_t)NTOK * H_ / 2;
  c.P = f;    f += (size_t)NTOK * V_;
  c.MB = f;   f += (size_t)B_ * NH_ * S_;
  c.LB = f;   f += (size_t)B_ * NH_ * S_;
  c.DB = f;   f += (size_t)B_ * NH_ * S_;
  c.MB0 = f;  f += (size_t)B_ * NH_ * S_;
  c.LB0 = f;  f += (size_t)B_ * NH_ * S_;
  c.CS = f;   f += (size_t)S_ * 32;
  c.SN = f;   f += (size_t)S_ * 32;
  unsigned short* wt = (unsigned short*)f;

  const size_t LQKV = (size_t)H_ * 3 * H_;
  const size_t LO = (size_t)H_ * H_;
  const size_t LGU = (size_t)H_ * 2 * INNER_;
  const size_t LD = (size_t)INNER_ * H_;

  for (int l = 0; l < 2; ++l) {
    c.WTqkv[l] = wt;
    k_wt<<<dim3(3 * H_ / 32, H_ / 32), dim3(32, 8), 0, stream>>>(qkvw + l * LQKV, wt, H_, 3 * H_);
    wt += LQKV;
    c.WTo[l] = wt;
    k_wt<<<dim3(H_ / 32, H_ / 32), dim3(32, 8), 0, stream>>>(ow + l * LO, wt, H_, H_);
    wt += LO;
    c.WTgu[l] = wt;
    k_wt<<<dim3(2 * INNER_ / 32, H_ / 32), dim3(32, 8), 0, stream>>>(guw + l * LGU, wt, H_, 2 * INNER_);
    wt += LGU;
    c.WTd[l] = wt;
    k_wt<<<dim3(H_ / 32, INNER_ / 32), dim3(32, 8), 0, stream>>>(dw + l * LD, wt, INNER_, H_);
    wt += LD;
  }

  k_zero<<<(NTOK * V_ + 255) / 256, 256, 0, stream>>>(logits, NTOK * V_);
  k_rope_tables<<<(S_ * 32 + 255) / 256, 256, 0, stream>>>(c.CS, c.SN);

  for (int step = 0; step < STEPS_; ++step) {
    k_softmax_logits<<<(NTOK + 255) / 256, 256, 0, stream>>>(logits, c.P);
    // h0 -> X1; forward L0 writes its attention state into the L0 checkpoint buffers
    k_h0<<<NTOK, 256, 0, stream>>>(c.P, E, inputs, c.X1);
    block_forward(c, 0, c.X1, c.UDX, c.Q016, c.AO0, c.MB0, c.LB0, false);
    // dE/dh2 = energy_w broadcast
    k_gfill<<<(NTOK * H_ + 255) / 256, 256, 0, stream>>>(ew, c.G);
    // backward L1 (full recompute, scratch attention buffers)
    block_backward(c, 1, c.UDX, c.Q16, c.AO, c.MB, c.LB, false,
                   qkvw + LQKV, ow + LO, guw + LGU, dw + LD);
    // backward L0: h0 again -> X1; attention fwd SKIPPED (checkpointed)
    k_h0<<<NTOK, 256, 0, stream>>>(c.P, E, inputs, c.X1);
    block_backward(c, 0, c.X1, c.Q016, c.AO0, c.MB0, c.LB0, true,
                   qkvw, ow, guw, dw);
    k_logits_update<<<NTOK, 64, 0, stream>>>(c.G, E, c.P, alpha, logits);
  }
}

// Round 8
// 3083.602 us; speedup vs baseline: 28.4347x; 1.1317x over previous
//
#include <hip/hip_runtime.h>
#include <math.h>

#define B_ 8
#define S_ 900
#define V_ 11
#define H_ 512
#define NH_ 8
#define HD_ 64
#define INNER_ 1536
#define STEPS_ 2
#define NTOK (B_*S_)
#define EPS_ 1e-5f
#define THETA_ 10000.0f
#define ESCALE_ 22.627416997969522f
#define SCALE_ 0.125f
#define PT_ 68   // attention LDS pitch (ushorts)
#define GP_ 36   // gemm LDS pitch (ushorts): 72B rows, 18-bank stride, gcd(18,32)=2 -> conflict-free

typedef __attribute__((ext_vector_type(8))) short bh8;
typedef __attribute__((ext_vector_type(4))) float f32x4;
typedef __attribute__((ext_vector_type(4))) unsigned short us4;

union bfu { bh8 v; unsigned short s[8]; us4 q[2]; };

__device__ inline unsigned short f2bf(float x) {
  unsigned u = __builtin_bit_cast(unsigned, x);
  return (unsigned short)((u + 0x7FFFu + ((u >> 16) & 1u)) >> 16);
}
__device__ inline float b2f(unsigned short s) {
  return __builtin_bit_cast(float, (unsigned)s << 16);
}

__device__ inline bh8 lds16(const unsigned short* p) {  // 8B-aligned 16B LDS read
  bfu u;
  u.q[0] = *(const us4*)p;
  u.q[1] = *(const us4*)(p + 4);
  return u.v;
}
__device__ inline void sts16(unsigned short* p, bfu u) {
  *(us4*)p = u.q[0];
  *(us4*)(p + 4) = u.q[1];
}

__device__ inline float wave_sum64(float x) {
#pragma unroll
  for (int off = 32; off > 0; off >>= 1) x += __shfl_xor(x, off, 64);
  return x;
}

__device__ inline float quad_sum(float x) {
  x += __shfl_xor(x, 1, 64);
  x += __shfl_xor(x, 2, 64);
  return x;
}

// ---------------- small kernels ----------------

__global__ void k_zero(float* p, int n) {
  int i = blockIdx.x * blockDim.x + threadIdx.x;
  if (i < n) p[i] = 0.f;
}

__global__ void k_rope_tables(float* cs, float* sn) {
  int idx = blockIdx.x * blockDim.x + threadIdx.x;
  if (idx >= S_ * 32) return;
  int s = idx >> 5, i = idx & 31;
  float freq = powf(THETA_, -(float)i / 32.0f);
  float ang = (float)s * freq;
  cs[idx] = cosf(ang);
  sn[idx] = sinf(ang);
}

__global__ void k_softmax_logits(const float* __restrict__ logits, float* __restrict__ P) {
  int t = blockIdx.x * blockDim.x + threadIdx.x;
  if (t >= NTOK) return;
  float x[V_];
  float m = -1e30f;
#pragma unroll
  for (int v = 0; v < V_; ++v) { x[v] = logits[t * V_ + v]; m = fmaxf(m, x[v]); }
  float ssum = 0.f;
#pragma unroll
  for (int v = 0; v < V_; ++v) { x[v] = expf(x[v] - m); ssum += x[v]; }
  float inv = 1.f / ssum;
#pragma unroll
  for (int v = 0; v < V_; ++v) P[t * V_ + v] = x[v] * inv;
}

__global__ void k_h0(const float* __restrict__ P, const float* __restrict__ E,
                     const int* __restrict__ inp, float* __restrict__ h0) {
  int t = blockIdx.x;
  int tid = threadIdx.x;
  __shared__ float p[V_];
  __shared__ int iw;
  if (tid < V_) p[tid] = P[t * V_ + tid];
  if (tid == 0) iw = inp[t];
  __syncthreads();
  for (int h = tid; h < H_; h += blockDim.x) {
    float acc = E[iw * H_ + h];
#pragma unroll
    for (int v = 0; v < V_; ++v) acc += p[v] * E[v * H_ + h];
    h0[(size_t)t * H_ + h] = ESCALE_ * acc;
  }
}

__global__ void k_gfill(const float* __restrict__ ew, float* __restrict__ G) {
  int idx = blockIdx.x * blockDim.x + threadIdx.x;
  if (idx < NTOK * H_) G[idx] = ew[idx & (H_ - 1)];
}

// ---------------- weight transpose-convert: W[K][N] fp32 -> WT[N][K] bf16 ----------------

__global__ void k_wt(const float* __restrict__ W, unsigned short* __restrict__ WT, int K, int N) {
  __shared__ float t[32][33];
  int k0 = blockIdx.y * 32, n0 = blockIdx.x * 32;
  int tx = threadIdx.x, ty = threadIdx.y;
#pragma unroll
  for (int i = 0; i < 4; ++i)
    t[ty + 8 * i][tx] = W[(size_t)(k0 + ty + 8 * i) * N + n0 + tx];
  __syncthreads();
#pragma unroll
  for (int i = 0; i < 4; ++i)
    WT[(size_t)(n0 + ty + 8 * i) * K + k0 + tx] = f2bf(t[tx][ty + 8 * i]);
}

// ---------------- MFMA GEMM: C[M,N] = A[M,K] @ B^T (B stored [N][K]) ----------------
// Tile 64x128, BK=32, 4 waves (2x2), wave-tile 32x64 = 2x4 frags of 16x16x32.
// BSRC: 1 = B bf16 (pre-transposed weights), 0 = B fp32 (weights as stored).
// ABF: A bf16. SILU_A: A = silu(gate)*up pairs (needs ABF, lda=2*INNER_). ADD: += D. CBF: C bf16.

template <int BSRC, int ABF, int SILU_A, int ADD, int CBF>
__global__ __launch_bounds__(256) void k_gemm(const float* __restrict__ Af,
                                              const unsigned short* __restrict__ A16,
                                              const float* __restrict__ Bf,
                                              const unsigned short* __restrict__ Bt,
                                              const float* __restrict__ Dm,
                                              float* __restrict__ Cf,
                                              unsigned short* __restrict__ C16,
                                              int M, int N, int K, int lda) {
  __shared__ unsigned short As[64][GP_];
  __shared__ unsigned short Bs[128][GP_];
  int tid = threadIdx.x;
  int m0 = blockIdx.y * 64, n0 = blockIdx.x * 128;
  int wid = tid >> 6, lane = tid & 63;
  int wr = (wid >> 1) * 32, wc = (wid & 1) * 64;
  int lr = lane & 15, lg = lane >> 4;
  f32x4 acc[2][4] = {};
  for (int k0 = 0; k0 < K; k0 += 32) {
    __syncthreads();
    {  // A tile: 64 rows x 32 cols, one bh8 per thread
      int row = tid >> 2, ck = (tid & 3) * 8;
      int gr = m0 + row; gr = gr < M ? gr : M - 1;
      if (ABF) {
        const unsigned short* src = &A16[(size_t)gr * lda + k0 + ck];
        if (SILU_A) {
          bfu pa;
#pragma unroll
          for (int j = 0; j < 8; ++j) {
            float g = b2f(src[j]), u = b2f(src[INNER_ + j]);
            pa.s[j] = f2bf((g / (1.f + __expf(-g))) * u);
          }
          *(bh8*)&As[row][ck] = pa.v;
        } else {
          *(bh8*)&As[row][ck] = *(const bh8*)src;
        }
      } else {
        const float* src = &Af[(size_t)gr * lda + k0 + ck];
        bfu pa;
#pragma unroll
        for (int j = 0; j < 8; ++j) pa.s[j] = f2bf(src[j]);
        *(bh8*)&As[row][ck] = pa.v;
      }
    }
#pragma unroll
    for (int i = 0; i < 2; ++i) {  // B tile: 128 rows x 32 cols
      int cidx = tid + 256 * i;
      int row = cidx >> 2, ck = (cidx & 3) * 8;
      if (BSRC == 0) {
        const float* bs = &Bf[(size_t)(n0 + row) * K + k0 + ck];
        bfu pb;
#pragma unroll
        for (int j = 0; j < 8; ++j) pb.s[j] = f2bf(bs[j]);
        *(bh8*)&Bs[row][ck] = pb.v;
      } else {
        *(bh8*)&Bs[row][ck] = *(const bh8*)&Bt[(size_t)(n0 + row) * K + k0 + ck];
      }
    }
    __syncthreads();
    bh8 av[2], bv[4];
#pragma unroll
    for (int fr = 0; fr < 2; ++fr) av[fr] = lds16(&As[wr + fr * 16 + lr][lg * 8]);
#pragma unroll
    for (int fc = 0; fc < 4; ++fc) bv[fc] = lds16(&Bs[wc + fc * 16 + lr][lg * 8]);
#pragma unroll
    for (int fr = 0; fr < 2; ++fr)
#pragma unroll
      for (int fc = 0; fc < 4; ++fc)
        acc[fr][fc] = __builtin_amdgcn_mfma_f32_16x16x32_bf16(av[fr], bv[fc], acc[fr][fc], 0, 0, 0);
  }
#pragma unroll
  for (int fr = 0; fr < 2; ++fr) {
    int r0 = m0 + wr + fr * 16 + lg * 4;
#pragma unroll
    for (int i = 0; i < 4; ++i) {
      int gr = r0 + i;
      if (gr >= M) continue;
#pragma unroll
      for (int fc = 0; fc < 4; ++fc) {
        int gc = n0 + wc + fc * 16 + lr;
        float out = acc[fr][fc][i];
        if (ADD) out += Dm[(size_t)gr * N + gc];
        if (CBF) C16[(size_t)gr * N + gc] = f2bf(out);
        else Cf[(size_t)gr * N + gc] = out;
      }
    }
  }
}

// ---------------- RoPE fwd/bwd on bf16 qkv ----------------

template <int BWD>
__global__ void k_rope(unsigned short* __restrict__ Q, const float* __restrict__ cs,
                       const float* __restrict__ sn) {
  int idx = blockIdx.x * blockDim.x + threadIdx.x;
  if (idx >= NTOK * NH_ * 2 * 32) return;
  int i = idx & 31;
  int h = (idx >> 5) & (NH_ - 1);
  int part = (idx >> 8) & 1;
  int t = idx >> 9;
  int s = t % S_;
  float c = cs[s * 32 + i], sv = sn[s * 32 + i];
  size_t base = ((size_t)t * 3 * NH_ + part * NH_ + h) * HD_;
  float x1 = b2f(Q[base + i]), x2 = b2f(Q[base + 32 + i]);
  if (!BWD) {
    Q[base + i] = f2bf(x1 * c - x2 * sv);
    Q[base + 32 + i] = f2bf(x2 * c + x1 * sv);
  } else {
    Q[base + i] = f2bf(x1 * c + x2 * sv);
    Q[base + 32 + i] = f2bf(x2 * c - x1 * sv);
  }
}

// ---------------- MFMA flash attention (bf16 QKV) ----------------
// QKV16 layout [t][24][64] ushorts: Q at slot h, K at 8+h, V at 16+h.

__global__ __launch_bounds__(256) void k_attn_fwd3(const unsigned short* __restrict__ QKV,
                                                   float* __restrict__ AO,
                                                   float* __restrict__ MB,
                                                   float* __restrict__ LB) {
  __shared__ unsigned short Ks[64][PT_];
  __shared__ unsigned short VT[64][PT_];
  __shared__ unsigned short Ps[4][16][PT_];
  int tid = threadIdx.x;
  int h = blockIdx.y, b = blockIdx.z;
  int w = tid >> 6, lane = tid & 63;
  int lr = lane & 15, lg = lane >> 4;
  int q0 = blockIdx.x * 64 + w * 16;

  bh8 qf[2];
  {
    int qr = q0 + lr; if (qr >= S_) qr = S_ - 1;
    const unsigned short* qp = &QKV[((size_t)(b * S_ + qr) * 24 + h) * 64 + lg * 8];
    qf[0] = *(const bh8*)qp;
    qf[1] = *(const bh8*)(qp + 32);
  }
  f32x4 accO[4] = {};
  float m[4], lsum[4];
#pragma unroll
  for (int i = 0; i < 4; ++i) { m[i] = -1e30f; lsum[i] = 0.f; }

  for (int kt = 0; kt < S_; kt += 64) {
    __syncthreads();
    {
      int r = tid >> 2, c0 = (tid & 3) * 16;
      int src = kt + r;
      size_t ts = (size_t)b * S_ + (src < S_ ? src : S_ - 1);
      const unsigned short* gp = &QKV[(ts * 24 + 8 + h) * 64 + c0];
      bfu p0, p1;
      p0.v = *(const bh8*)gp;
      p1.v = *(const bh8*)(gp + 8);
      sts16(&Ks[r][c0], p0);
      sts16(&Ks[r][c0 + 8], p1);
    }
    {
      int d0 = (tid & 15) * 4, k0r = (tid >> 4) * 4;
      us4 rv[4];
#pragma unroll
      for (int j = 0; j < 4; ++j) {
        int src = kt + k0r + j;
        size_t ts = (size_t)b * S_ + (src < S_ ? src : S_ - 1);
        rv[j] = *(const us4*)&QKV[(ts * 24 + 16 + h) * 64 + d0];
      }
#pragma unroll
      for (int dd = 0; dd < 4; ++dd) {
        us4 pk = {rv[0][dd], rv[1][dd], rv[2][dd], rv[3][dd]};
        *(us4*)&VT[d0 + dd][k0r] = pk;
      }
    }
    __syncthreads();
    f32x4 accS[4] = {};
#pragma unroll
    for (int ks = 0; ks < 2; ++ks)
#pragma unroll
      for (int fk = 0; fk < 4; ++fk)
        accS[fk] = __builtin_amdgcn_mfma_f32_16x16x32_bf16(qf[ks], lds16(&Ks[fk * 16 + lr][ks * 32 + lg * 8]), accS[fk], 0, 0, 0);
    float sc[4][4], pmax[4];
#pragma unroll
    for (int i = 0; i < 4; ++i) pmax[i] = -1e30f;
#pragma unroll
    for (int fk = 0; fk < 4; ++fk)
#pragma unroll
      for (int i = 0; i < 4; ++i) {
        float s = accS[fk][i] * SCALE_;
        if (kt + fk * 16 + lr >= S_) s = -1e30f;
        sc[fk][i] = s;
        pmax[i] = fmaxf(pmax[i], s);
      }
#pragma unroll
    for (int i = 0; i < 4; ++i) {
      float v = pmax[i];
      v = fmaxf(v, __shfl_xor(v, 1, 64));
      v = fmaxf(v, __shfl_xor(v, 2, 64));
      v = fmaxf(v, __shfl_xor(v, 4, 64));
      v = fmaxf(v, __shfl_xor(v, 8, 64));
      pmax[i] = v;
    }
    float psum[4];
#pragma unroll
    for (int i = 0; i < 4; ++i) {
      float mn = fmaxf(m[i], pmax[i]);
      float eo = __expf(m[i] - mn);
      m[i] = mn;
      lsum[i] *= eo;
#pragma unroll
      for (int fd = 0; fd < 4; ++fd) accO[fd][i] *= eo;
      psum[i] = 0.f;
    }
#pragma unroll
    for (int fk = 0; fk < 4; ++fk)
#pragma unroll
      for (int i = 0; i < 4; ++i) {
        float p = __expf(sc[fk][i] - m[i]);
        sc[fk][i] = p;
        psum[i] += p;
      }
#pragma unroll
    for (int i = 0; i < 4; ++i) {
      float v = psum[i];
      v += __shfl_xor(v, 1, 64);
      v += __shfl_xor(v, 2, 64);
      v += __shfl_xor(v, 4, 64);
      v += __shfl_xor(v, 8, 64);
      lsum[i] += v;
    }
#pragma unroll
    for (int fk = 0; fk < 4; ++fk)
#pragma unroll
      for (int i = 0; i < 4; ++i)
        Ps[w][lg * 4 + i][fk * 16 + lr] = f2bf(sc[fk][i]);
#pragma unroll
    for (int ks = 0; ks < 2; ++ks) {
      bh8 ap = lds16(&Ps[w][lr][ks * 32 + lg * 8]);
#pragma unroll
      for (int fd = 0; fd < 4; ++fd)
        accO[fd] = __builtin_amdgcn_mfma_f32_16x16x32_bf16(ap, lds16(&VT[fd * 16 + lr][ks * 32 + lg * 8]), accO[fd], 0, 0, 0);
    }
  }
#pragma unroll
  for (int i = 0; i < 4; ++i) {
    int q = q0 + lg * 4 + i;
    if (q < S_) {
      float linv = 1.f / lsum[i];
      size_t obase = (size_t)(b * S_ + q) * H_ + h * 64;
#pragma unroll
      for (int fd = 0; fd < 4; ++fd) AO[obase + fd * 16 + lr] = accO[fd][i] * linv;
      if (lr == 0) {
        MB[((size_t)b * NH_ + h) * S_ + q] = m[i];
        LB[((size_t)b * NH_ + h) * S_ + q] = linv;
      }
    }
  }
}

// delta[b,h,q] = dot(dO_row(bf16), O_row(fp32))
__global__ __launch_bounds__(256) void k_delta(const float* __restrict__ O,
                                               const unsigned short* __restrict__ dO,
                                               float* __restrict__ DB) {
  int tid = threadIdx.x;
  int h = blockIdx.y, b = blockIdx.z;
  int r = blockIdx.x * 64 + (tid >> 2), part = tid & 3;
  if (r >= S_) return;
  size_t base = (size_t)(b * S_ + r) * H_ + h * 64 + part * 16;
  const float4* op = (const float4*)&O[base];
  bfu d0, d1;
  d0.v = *(const bh8*)&dO[base];
  d1.v = *(const bh8*)&dO[base + 8];
  float s = 0.f;
#pragma unroll
  for (int i = 0; i < 4; ++i) {
    float4 a = op[i];
    const bfu& dd = (i < 2) ? d0 : d1;
    int j0 = (i & 1) * 4;
    s += a.x * b2f(dd.s[j0]) + a.y * b2f(dd.s[j0 + 1]) + a.z * b2f(dd.s[j0 + 2]) + a.w * b2f(dd.s[j0 + 3]);
  }
  s = quad_sum(s);
  if (part == 0) DB[((size_t)b * NH_ + h) * S_ + r] = s;
}

// dQ pass
__global__ __launch_bounds__(256) void k_attn_bwd_dq3(const unsigned short* __restrict__ QKV,
                                                      const unsigned short* __restrict__ dO,
                                                      const float* __restrict__ MB,
                                                      const float* __restrict__ LB,
                                                      const float* __restrict__ DB,
                                                      unsigned short* __restrict__ dQKV) {
  __shared__ unsigned short Ks[64][PT_];
  __shared__ unsigned short Vs[64][PT_];
  __shared__ unsigned short KT[64][PT_];
  __shared__ unsigned short Ps[4][16][PT_];
  int tid = threadIdx.x;
  int h = blockIdx.y, b = blockIdx.z;
  int w = tid >> 6, lane = tid & 63;
  int lr = lane & 15, lg = lane >> 4;
  int q0 = blockIdx.x * 64 + w * 16;
  size_t sbase = ((size_t)b * NH_ + h) * S_;

  bh8 qf[2], dof[2];
  {
    int qr = q0 + lr; if (qr >= S_) qr = S_ - 1;
    const unsigned short* qp = &QKV[((size_t)(b * S_ + qr) * 24 + h) * 64 + lg * 8];
    const unsigned short* dp = &dO[(size_t)(b * S_ + qr) * H_ + h * 64 + lg * 8];
    qf[0] = *(const bh8*)qp;  qf[1] = *(const bh8*)(qp + 32);
    dof[0] = *(const bh8*)dp; dof[1] = *(const bh8*)(dp + 32);
  }
  float mrow[4], lrow[4], drow[4];
#pragma unroll
  for (int i = 0; i < 4; ++i) {
    int q = q0 + lg * 4 + i; if (q >= S_) q = S_ - 1;
    mrow[i] = MB[sbase + q];
    lrow[i] = LB[sbase + q];
    drow[i] = DB[sbase + q];
  }
  f32x4 accQ[4] = {};

  for (int kt = 0; kt < S_; kt += 64) {
    __syncthreads();
    {
      int r = tid >> 2, c0 = (tid & 3) * 16;
      int src = kt + r;
      bool vld = src < S_;
      size_t ts = (size_t)b * S_ + (vld ? src : S_ - 1);
      const unsigned short* kp = &QKV[(ts * 24 + 8 + h) * 64 + c0];
      bfu p0{}, p1{}, p2{}, p3{};
      if (vld) {
        p0.v = *(const bh8*)kp;
        p1.v = *(const bh8*)(kp + 8);
        p2.v = *(const bh8*)(kp + 512);
        p3.v = *(const bh8*)(kp + 520);
      }
      sts16(&Ks[r][c0], p0); sts16(&Ks[r][c0 + 8], p1);
      sts16(&Vs[r][c0], p2); sts16(&Vs[r][c0 + 8], p3);
    }
    {
      int d0 = (tid & 15) * 4, k0r = (tid >> 4) * 4;
      us4 rv[4];
#pragma unroll
      for (int j = 0; j < 4; ++j) {
        int src = kt + k0r + j;
        bool vld = src < S_;
        size_t ts = (size_t)b * S_ + (vld ? src : S_ - 1);
        us4 t = *(const us4*)&QKV[(ts * 24 + 8 + h) * 64 + d0];
        if (!vld) t = us4{0, 0, 0, 0};
        rv[j] = t;
      }
#pragma unroll
      for (int dd = 0; dd < 4; ++dd) {
        us4 pk = {rv[0][dd], rv[1][dd], rv[2][dd], rv[3][dd]};
        *(us4*)&KT[d0 + dd][k0r] = pk;
      }
    }
    __syncthreads();
    f32x4 aS[4] = {}, aD[4] = {};
#pragma unroll
    for (int ks = 0; ks < 2; ++ks)
#pragma unroll
      for (int fk = 0; fk < 4; ++fk) {
        aS[fk] = __builtin_amdgcn_mfma_f32_16x16x32_bf16(qf[ks], lds16(&Ks[fk * 16 + lr][ks * 32 + lg * 8]), aS[fk], 0, 0, 0);
        aD[fk] = __builtin_amdgcn_mfma_f32_16x16x32_bf16(dof[ks], lds16(&Vs[fk * 16 + lr][ks * 32 + lg * 8]), aD[fk], 0, 0, 0);
      }
#pragma unroll
    for (int fk = 0; fk < 4; ++fk)
#pragma unroll
      for (int i = 0; i < 4; ++i) {
        float p = __expf(aS[fk][i] * SCALE_ - mrow[i]) * lrow[i];
        float ds = p * (aD[fk][i] - drow[i]);
        Ps[w][lg * 4 + i][fk * 16 + lr] = f2bf(ds);
      }
#pragma unroll
    for (int ks = 0; ks < 2; ++ks) {
      bh8 ap = lds16(&Ps[w][lr][ks * 32 + lg * 8]);
#pragma unroll
      for (int fd = 0; fd < 4; ++fd)
        accQ[fd] = __builtin_amdgcn_mfma_f32_16x16x32_bf16(ap, lds16(&KT[fd * 16 + lr][ks * 32 + lg * 8]), accQ[fd], 0, 0, 0);
    }
  }
#pragma unroll
  for (int i = 0; i < 4; ++i) {
    int q = q0 + lg * 4 + i;
    if (q < S_) {
      size_t obase = ((size_t)(b * S_ + q) * 24 + h) * 64;
#pragma unroll
      for (int fd = 0; fd < 4; ++fd) dQKV[obase + fd * 16 + lr] = f2bf(SCALE_ * accQ[fd][i]);
    }
  }
}

// dK + dV pass
__global__ __launch_bounds__(256) void k_attn_bwd_kv3(const unsigned short* __restrict__ QKV,
                                                      const unsigned short* __restrict__ dO,
                                                      const float* __restrict__ MB,
                                                      const float* __restrict__ LB,
                                                      const float* __restrict__ DB,
                                                      unsigned short* __restrict__ dQKV) {
  __shared__ unsigned short Qs[64][PT_];
  __shared__ unsigned short dOs[64][PT_];
  __shared__ unsigned short QT[64][PT_];
  __shared__ unsigned short dOT[64][PT_];
  __shared__ unsigned short Ps[4][16][PT_];
  __shared__ float sM[64], sL[64], sD[64];
  int tid = threadIdx.x;
  int h = blockIdx.y, b = blockIdx.z;
  int w = tid >> 6, lane = tid & 63;
  int lr = lane & 15, lg = lane >> 4;
  int k0w = blockIdx.x * 64 + w * 16;
  size_t sbase = ((size_t)b * NH_ + h) * S_;

  bh8 kf[2], vf[2];
  {
    int kr = k0w + lr; if (kr >= S_) kr = S_ - 1;
    const unsigned short* kp = &QKV[((size_t)(b * S_ + kr) * 24 + 8 + h) * 64 + lg * 8];
    kf[0] = *(const bh8*)kp;        kf[1] = *(const bh8*)(kp + 32);
    vf[0] = *(const bh8*)(kp + 512); vf[1] = *(const bh8*)(kp + 544);
  }
  f32x4 accK[4] = {}, accV[4] = {};

  for (int qt = 0; qt < S_; qt += 64) {
    __syncthreads();
    {
      int r = tid >> 2, c0 = (tid & 3) * 16;
      int src = qt + r;
      bool vld = src < S_;
      size_t ts = (size_t)b * S_ + (vld ? src : S_ - 1);
      const unsigned short* qp = &QKV[(ts * 24 + h) * 64 + c0];
      const unsigned short* dp = &dO[ts * H_ + h * 64 + c0];
      bfu p0, p1, p2{}, p3{};
      p0.v = *(const bh8*)qp;
      p1.v = *(const bh8*)(qp + 8);
      if (vld) {
        p2.v = *(const bh8*)dp;
        p3.v = *(const bh8*)(dp + 8);
      }
      sts16(&Qs[r][c0], p0);  sts16(&Qs[r][c0 + 8], p1);
      sts16(&dOs[r][c0], p2); sts16(&dOs[r][c0 + 8], p3);
    }
    {
      int d0 = (tid & 15) * 4, q0r = (tid >> 4) * 4;
      us4 rq[4], rd[4];
#pragma unroll
      for (int j = 0; j < 4; ++j) {
        int src = qt + q0r + j;
        bool vld = src < S_;
        size_t ts = (size_t)b * S_ + (vld ? src : S_ - 1);
        rq[j] = *(const us4*)&QKV[(ts * 24 + h) * 64 + d0];
        us4 td = *(const us4*)&dO[ts * H_ + h * 64 + d0];
        if (!vld) td = us4{0, 0, 0, 0};
        rd[j] = td;
      }
#pragma unroll
      for (int dd = 0; dd < 4; ++dd) {
        us4 pq = {rq[0][dd], rq[1][dd], rq[2][dd], rq[3][dd]};
        us4 pd = {rd[0][dd], rd[1][dd], rd[2][dd], rd[3][dd]};
        *(us4*)&QT[d0 + dd][q0r] = pq;
        *(us4*)&dOT[d0 + dd][q0r] = pd;
      }
    }
    if (tid < 64) {
      int src = qt + tid;
      bool vld = src < S_;
      int sc = vld ? src : S_ - 1;
      sM[tid] = MB[sbase + sc];
      sL[tid] = LB[sbase + sc];
      sD[tid] = vld ? DB[sbase + sc] : 0.f;
    }
    __syncthreads();
    f32x4 aS[4] = {}, aD[4] = {};
#pragma unroll
    for (int ks = 0; ks < 2; ++ks)
#pragma unroll
      for (int fq = 0; fq < 4; ++fq) {
        aS[fq] = __builtin_amdgcn_mfma_f32_16x16x32_bf16(kf[ks], lds16(&Qs[fq * 16 + lr][ks * 32 + lg * 8]), aS[fq], 0, 0, 0);
        aD[fq] = __builtin_amdgcn_mfma_f32_16x16x32_bf16(vf[ks], lds16(&dOs[fq * 16 + lr][ks * 32 + lg * 8]), aD[fq], 0, 0, 0);
      }
    float pv[4][4];
#pragma unroll
    for (int fq = 0; fq < 4; ++fq) {
      float mq = sM[fq * 16 + lr], lq = sL[fq * 16 + lr];
#pragma unroll
      for (int i = 0; i < 4; ++i) {
        float p = __expf(aS[fq][i] * SCALE_ - mq) * lq;
        pv[fq][i] = p;
        Ps[w][lg * 4 + i][fq * 16 + lr] = f2bf(p);
      }
    }
#pragma unroll
    for (int qs = 0; qs < 2; ++qs) {
      bh8 ap = lds16(&Ps[w][lr][qs * 32 + lg * 8]);
#pragma unroll
      for (int fd = 0; fd < 4; ++fd)
        accV[fd] = __builtin_amdgcn_mfma_f32_16x16x32_bf16(ap, lds16(&dOT[fd * 16 + lr][qs * 32 + lg * 8]), accV[fd], 0, 0, 0);
    }
#pragma unroll
    for (int fq = 0; fq < 4; ++fq) {
      float dq = sD[fq * 16 + lr];
#pragma unroll
      for (int i = 0; i < 4; ++i)
        Ps[w][lg * 4 + i][fq * 16 + lr] = f2bf(pv[fq][i] * (aD[fq][i] - dq));
    }
#pragma unroll
    for (int qs = 0; qs < 2; ++qs) {
      bh8 ap = lds16(&Ps[w][lr][qs * 32 + lg * 8]);
#pragma unroll
      for (int fd = 0; fd < 4; ++fd)
        accK[fd] = __builtin_amdgcn_mfma_f32_16x16x32_bf16(ap, lds16(&QT[fd * 16 + lr][qs * 32 + lg * 8]), accK[fd], 0, 0, 0);
    }
  }
#pragma unroll
  for (int i = 0; i < 4; ++i) {
    int k = k0w + lg * 4 + i;
    if (k < S_) {
      size_t obase = ((size_t)(b * S_ + k) * 24 + 8 + h) * 64;
#pragma unroll
      for (int fd = 0; fd < 4; ++fd) {
        dQKV[obase + fd * 16 + lr] = f2bf(SCALE_ * accK[fd][i]);
        dQKV[obase + 512 + fd * 16 + lr] = f2bf(accV[fd][i]);
      }
    }
  }
}

// ---------------- RMS norm fwd/bwd ----------------

__global__ __launch_bounds__(256) void k_rms_fwd(const float* __restrict__ X, float* __restrict__ Y) {
  int t = blockIdx.x, tid = threadIdx.x;
  float x0 = X[(size_t)t * H_ + tid], x1 = X[(size_t)t * H_ + tid + 256];
  __shared__ float red[256];
  red[tid] = x0 * x0 + x1 * x1;
  __syncthreads();
  for (int s = 128; s > 0; s >>= 1) {
    if (tid < s) red[tid] += red[tid + s];
    __syncthreads();
  }
  float r = rsqrtf(red[0] / H_ + EPS_);
  Y[(size_t)t * H_ + tid] = x0 * r;
  Y[(size_t)t * H_ + tid + 256] = x1 * r;
}

__global__ __launch_bounds__(256) void k_rms_bwd(const float* __restrict__ X,
                                                 const float* __restrict__ GY,
                                                 float* __restrict__ GX) {
  int t = blockIdx.x, tid = threadIdx.x;
  float x0 = X[(size_t)t * H_ + tid], x1 = X[(size_t)t * H_ + tid + 256];
  float g0 = GY[(size_t)t * H_ + tid], g1 = GY[(size_t)t * H_ + tid + 256];
  __shared__ float r1[256], r2[256];
  r1[tid] = x0 * x0 + x1 * x1;
  r2[tid] = x0 * g0 + x1 * g1;
  __syncthreads();
  for (int s = 128; s > 0; s >>= 1) {
    if (tid < s) { r1[tid] += r1[tid + s]; r2[tid] += r2[tid + s]; }
    __syncthreads();
  }
  float r = rsqrtf(r1[0] / H_ + EPS_);
  float coef = r * r * r * r2[0] / (float)H_;
  GX[(size_t)t * H_ + tid] = r * g0 - coef * x0;
  GX[(size_t)t * H_ + tid + 256] = r * g1 - coef * x1;
}

// ---------------- SiLU-gate backward (bf16 GU in place) ----------------

__global__ void k_silu_bwd(unsigned short* __restrict__ GU, const float* __restrict__ dact) {
  int idx = blockIdx.x * blockDim.x + threadIdx.x;
  if (idx >= NTOK * INNER_ / 8) return;
  int t = idx / (INNER_ / 8), i8 = (idx % (INNER_ / 8)) * 8;
  size_t gb = (size_t)t * 2 * INNER_;
  bfu g8, u8, og, ou;
  g8.v = *(const bh8*)&GU[gb + i8];
  u8.v = *(const bh8*)&GU[gb + INNER_ + i8];
  const float* da = &dact[(size_t)t * INNER_ + i8];
#pragma unroll
  for (int j = 0; j < 8; ++j) {
    float g = b2f(g8.s[j]), u = b2f(u8.s[j]), d = da[j];
    float sig = 1.f / (1.f + __expf(-g));
    og.s[j] = f2bf(d * u * sig * (1.f + g * (1.f - sig)));
    ou.s[j] = f2bf(d * g * sig);
  }
  *(bh8*)&GU[gb + i8] = og.v;
  *(bh8*)&GU[gb + INNER_ + i8] = ou.v;
}

// ---------------- logits update ----------------

__global__ __launch_bounds__(64) void k_logits_update(const float* __restrict__ G,
                                                      const float* __restrict__ E,
                                                      const float* __restrict__ P,
                                                      const float* __restrict__ alpha,
                                                      float* __restrict__ logits) {
  int t = blockIdx.x, lane = threadIdx.x;
  float dp[V_];
#pragma unroll
  for (int v = 0; v < V_; ++v) dp[v] = 0.f;
  for (int hh = lane; hh < H_; hh += 64) {
    float gh = G[(size_t)t * H_ + hh];
#pragma unroll
    for (int v = 0; v < V_; ++v) dp[v] += gh * E[v * H_ + hh];
  }
#pragma unroll
  for (int v = 0; v < V_; ++v) dp[v] = wave_sum64(dp[v]) * ESCALE_;
  float dot = 0.f;
  float pv[V_];
#pragma unroll
  for (int v = 0; v < V_; ++v) {
    pv[v] = P[t * V_ + v];
    dot += pv[v] * dp[v];
  }
  float a = fmaxf(alpha[0], 1e-4f);
  if (lane < V_) logits[t * V_ + lane] -= a * pv[lane] * (dp[lane] - dot);
}

// ---------------- host-side orchestration ----------------

struct Ctx {
  unsigned short *Q16, *Q016, *dQ16, *GU16, *DO16;
  float *ACT, *X1, *X2, *AO, *AO0, *G, *UDX, *P, *MB, *LB, *DB, *MB0, *LB0, *CS, *SN;
  const unsigned short *WTqkv[2], *WTo[2], *WTgu[2], *WTd[2];
  hipStream_t st;
};

static inline dim3 ggrid(int M, int N) { return dim3(N / 128, (M + 63) / 64); }

static void block_forward(Ctx& c, int l, const float* hin, float* hout,
                          unsigned short* qb, float* ao, float* mb, float* lb, bool skip_attn) {
  if (!skip_attn) {
    k_gemm<1, 0, 0, 0, 1><<<ggrid(NTOK, 3 * H_), 256, 0, c.st>>>(
        hin, nullptr, nullptr, c.WTqkv[l], nullptr, nullptr, qb, NTOK, 3 * H_, H_, H_);
    k_rope<0><<<(NTOK * NH_ * 2 * 32 + 255) / 256, 256, 0, c.st>>>(qb, c.CS, c.SN);
    k_attn_fwd3<<<dim3((S_ + 63) / 64, NH_, B_), 256, 0, c.st>>>(qb, ao, mb, lb);
  }
  k_gemm<1, 0, 0, 1, 0><<<ggrid(NTOK, H_), 256, 0, c.st>>>(
      ao, nullptr, nullptr, c.WTo[l], hin, c.X1, nullptr, NTOK, H_, H_, H_);
  k_rms_fwd<<<NTOK, 256, 0, c.st>>>(c.X1, c.UDX);
  k_gemm<1, 0, 0, 0, 1><<<ggrid(NTOK, 2 * INNER_), 256, 0, c.st>>>(
      c.UDX, nullptr, nullptr, c.WTgu[l], nullptr, nullptr, c.GU16, NTOK, 2 * INNER_, H_, H_);
  k_gemm<1, 1, 1, 1, 0><<<ggrid(NTOK, H_), 256, 0, c.st>>>(
      nullptr, c.GU16, nullptr, c.WTd[l], c.UDX, c.X2, nullptr, NTOK, H_, INNER_, 2 * INNER_);
  if (hout) k_rms_fwd<<<NTOK, 256, 0, c.st>>>(c.X2, hout);
}

static void block_backward(Ctx& c, int l, const float* hin,
                           unsigned short* qb, float* ao, float* mb, float* lb, bool skip_attn,
                           const float* wqkv, const float* wo, const float* wgu, const float* wd) {
  block_forward(c, l, hin, nullptr, qb, ao, mb, lb, skip_attn);
  k_rms_bwd<<<NTOK, 256, 0, c.st>>>(c.X2, c.G, c.UDX);
  k_gemm<0, 0, 0, 0, 0><<<ggrid(NTOK, INNER_), 256, 0, c.st>>>(
      c.UDX, nullptr, wd, nullptr, nullptr, c.ACT, nullptr, NTOK, INNER_, H_, H_);
  k_silu_bwd<<<(NTOK * INNER_ / 8 + 255) / 256, 256, 0, c.st>>>(c.GU16, c.ACT);
  k_gemm<0, 1, 0, 1, 0><<<ggrid(NTOK, H_), 256, 0, c.st>>>(
      nullptr, c.GU16, wgu, nullptr, c.UDX, c.G, nullptr, NTOK, H_, 2 * INNER_, 2 * INNER_);
  k_rms_bwd<<<NTOK, 256, 0, c.st>>>(c.X1, c.G, c.UDX);
  // d_attn_out -> DO16 (bf16 direct; delta reads bf16)
  k_gemm<0, 0, 0, 0, 1><<<ggrid(NTOK, H_), 256, 0, c.st>>>(
      c.UDX, nullptr, wo, nullptr, nullptr, nullptr, c.DO16, NTOK, H_, H_, H_);
  dim3 agrid((S_ + 63) / 64, NH_, B_);
  k_delta<<<agrid, 256, 0, c.st>>>(ao, c.DO16, c.DB);
  k_attn_bwd_dq3<<<agrid, 256, 0, c.st>>>(qb, c.DO16, mb, lb, c.DB, c.dQ16);
  k_attn_bwd_kv3<<<agrid, 256, 0, c.st>>>(qb, c.DO16, mb, lb, c.DB, c.dQ16);
  k_rope<1><<<(NTOK * NH_ * 2 * 32 + 255) / 256, 256, 0, c.st>>>(c.dQ16, c.CS, c.SN);
  k_gemm<0, 1, 0, 1, 0><<<ggrid(NTOK, H_), 256, 0, c.st>>>(
      nullptr, c.dQ16, wqkv, nullptr, c.UDX, c.G, nullptr, NTOK, H_, 3 * H_, 3 * H_);
}

extern "C" void kernel_launch(void* const* d_in, const int* in_sizes, int n_in,
                              void* d_out, int out_size, void* d_ws, size_t ws_size,
                              hipStream_t stream) {
  const int* inputs = (const int*)d_in[0];
  const float* E = (const float*)d_in[2];
  const float* ew = (const float*)d_in[3];
  const float* qkvw = (const float*)d_in[4];
  const float* ow = (const float*)d_in[5];
  const float* guw = (const float*)d_in[6];
  const float* dw = (const float*)d_in[7];
  const float* alpha = (const float*)d_in[8];
  float* logits = (float*)d_out;

  const size_t WT_FLOATS = 3407872;
  const size_t NEED =
      2 * ((size_t)NTOK * 3 * H_ / 2) +
      ((size_t)NTOK * INNER_) +
      ((size_t)NTOK * INNER_) +
      6 * ((size_t)NTOK * H_) +
      ((size_t)NTOK * H_ / 2) +
      ((size_t)NTOK * V_) +
      5 * ((size_t)B_ * NH_ * S_) +
      2 * ((size_t)S_ * 32) +
      WT_FLOATS;
  if (ws_size < NEED * sizeof(float)) {
    k_zero<<<(NTOK * V_ + 255) / 256, 256, 0, stream>>>(logits, NTOK * V_);
    return;
  }

  float* f = (float*)d_ws;
  Ctx c;
  c.st = stream;
  c.Q16 = (unsigned short*)f;  f += (size_t)NTOK * 3 * H_ / 2;
  c.Q016 = (unsigned short*)f; f += (size_t)NTOK * 3 * H_ / 2;
  c.GU16 = (unsigned short*)f; f += (size_t)NTOK * INNER_;
  c.ACT = f; c.dQ16 = (unsigned short*)f; f += (size_t)NTOK * INNER_;
  c.X1 = f;   f += (size_t)NTOK * H_;
  c.X2 = f;   f += (size_t)NTOK * H_;
  c.AO = f;   f += (size_t)NTOK * H_;
  c.AO0 = f;  f += (size_t)NTOK * H_;
  c.G = f;    f += (size_t)NTOK * H_;
  c.UDX = f;  f += (size_t)NTOK * H_;
  c.DO16 = (unsigned short*)f; f += (size_t)NTOK * H_ / 2;
  c.P = f;    f += (size_t)NTOK * V_;
  c.MB = f;   f += (size_t)B_ * NH_ * S_;
  c.LB = f;   f += (size_t)B_ * NH_ * S_;
  c.DB = f;   f += (size_t)B_ * NH_ * S_;
  c.MB0 = f;  f += (size_t)B_ * NH_ * S_;
  c.LB0 = f;  f += (size_t)B_ * NH_ * S_;
  c.CS = f;   f += (size_t)S_ * 32;
  c.SN = f;   f += (size_t)S_ * 32;
  unsigned short* wt = (unsigned short*)f;

  const size_t LQKV = (size_t)H_ * 3 * H_;
  const size_t LO = (size_t)H_ * H_;
  const size_t LGU = (size_t)H_ * 2 * INNER_;
  const size_t LD = (size_t)INNER_ * H_;

  for (int l = 0; l < 2; ++l) {
    c.WTqkv[l] = wt;
    k_wt<<<dim3(3 * H_ / 32, H_ / 32), dim3(32, 8), 0, stream>>>(qkvw + l * LQKV, wt, H_, 3 * H_);
    wt += LQKV;
    c.WTo[l] = wt;
    k_wt<<<dim3(H_ / 32, H_ / 32), dim3(32, 8), 0, stream>>>(ow + l * LO, wt, H_, H_);
    wt += LO;
    c.WTgu[l] = wt;
    k_wt<<<dim3(2 * INNER_ / 32, H_ / 32), dim3(32, 8), 0, stream>>>(guw + l * LGU, wt, H_, 2 * INNER_);
    wt += LGU;
    c.WTd[l] = wt;
    k_wt<<<dim3(H_ / 32, INNER_ / 32), dim3(32, 8), 0, stream>>>(dw + l * LD, wt, INNER_, H_);
    wt += LD;
  }

  k_zero<<<(NTOK * V_ + 255) / 256, 256, 0, stream>>>(logits, NTOK * V_);
  k_rope_tables<<<(S_ * 32 + 255) / 256, 256, 0, stream>>>(c.CS, c.SN);

  for (int step = 0; step < STEPS_; ++step) {
    k_softmax_logits<<<(NTOK + 255) / 256, 256, 0, stream>>>(logits, c.P);
    k_h0<<<NTOK, 256, 0, stream>>>(c.P, E, inputs, c.X1);
    block_forward(c, 0, c.X1, c.UDX, c.Q016, c.AO0, c.MB0, c.LB0, false);
    k_gfill<<<(NTOK * H_ + 255) / 256, 256, 0, stream>>>(ew, c.G);
    block_backward(c, 1, c.UDX, c.Q16, c.AO, c.MB, c.LB, false,
                   qkvw + LQKV, ow + LO, guw + LGU, dw + LD);
    k_h0<<<NTOK, 256, 0, stream>>>(c.P, E, inputs, c.X1);
    block_backward(c, 0, c.X1, c.Q016, c.AO0, c.MB0, c.LB0, true,
                   qkvw, ow, guw, dw);
    k_logits_update<<<NTOK, 64, 0, stream>>>(c.G, E, c.P, alpha, logits);
  }
}

// Round 9
// 2701.439 us; speedup vs baseline: 32.4573x; 1.1415x over previous
//
#include <hip/hip_runtime.h>
#include <math.h>

#define B_ 8
#define S_ 900
#define V_ 11
#define H_ 512
#define NH_ 8
#define HD_ 64
#define INNER_ 1536
#define STEPS_ 2
#define NTOK (B_*S_)
#define EPS_ 1e-5f
#define THETA_ 10000.0f
#define ESCALE_ 22.627416997969522f
#define SCALE_ 0.125f
#define PT_ 68   // attention LDS pitch (ushorts)

typedef __attribute__((ext_vector_type(8))) short bh8;
typedef __attribute__((ext_vector_type(4))) float f32x4;
typedef __attribute__((ext_vector_type(4))) unsigned short us4;

union bfu { bh8 v; unsigned short s[8]; us4 q[2]; };

__device__ inline unsigned short f2bf(float x) {
  unsigned u = __builtin_bit_cast(unsigned, x);
  return (unsigned short)((u + 0x7FFFu + ((u >> 16) & 1u)) >> 16);
}
__device__ inline float b2f(unsigned short s) {
  return __builtin_bit_cast(float, (unsigned)s << 16);
}

// async global->LDS, 16B per lane; LDS dest = wave-uniform base + lane*16
__device__ inline void gld16(const unsigned short* g, unsigned short* l) {
  __builtin_amdgcn_global_load_lds(
      (const __attribute__((address_space(1))) void*)(g),
      (__attribute__((address_space(3))) void*)(l), 16, 0, 0);
}

__device__ inline bh8 lds16(const unsigned short* p) {
  bfu u;
  u.q[0] = *(const us4*)p;
  u.q[1] = *(const us4*)(p + 4);
  return u.v;
}
__device__ inline void sts16(unsigned short* p, bfu u) {
  *(us4*)p = u.q[0];
  *(us4*)(p + 4) = u.q[1];
}

__device__ inline float wave_sum64(float x) {
#pragma unroll
  for (int off = 32; off > 0; off >>= 1) x += __shfl_xor(x, off, 64);
  return x;
}

__device__ inline float quad_sum(float x) {
  x += __shfl_xor(x, 1, 64);
  x += __shfl_xor(x, 2, 64);
  return x;
}

// ---------------- small kernels ----------------

__global__ void k_zero(float* p, int n) {
  int i = blockIdx.x * blockDim.x + threadIdx.x;
  if (i < n) p[i] = 0.f;
}

__global__ void k_rope_tables(float* cs, float* sn) {
  int idx = blockIdx.x * blockDim.x + threadIdx.x;
  if (idx >= S_ * 32) return;
  int s = idx >> 5, i = idx & 31;
  float freq = powf(THETA_, -(float)i / 32.0f);
  float ang = (float)s * freq;
  cs[idx] = cosf(ang);
  sn[idx] = sinf(ang);
}

__global__ void k_softmax_logits(const float* __restrict__ logits, float* __restrict__ P) {
  int t = blockIdx.x * blockDim.x + threadIdx.x;
  if (t >= NTOK) return;
  float x[V_];
  float m = -1e30f;
#pragma unroll
  for (int v = 0; v < V_; ++v) { x[v] = logits[t * V_ + v]; m = fmaxf(m, x[v]); }
  float ssum = 0.f;
#pragma unroll
  for (int v = 0; v < V_; ++v) { x[v] = expf(x[v] - m); ssum += x[v]; }
  float inv = 1.f / ssum;
#pragma unroll
  for (int v = 0; v < V_; ++v) P[t * V_ + v] = x[v] * inv;
}

// h0 -> fp32 + bf16
__global__ void k_h0(const float* __restrict__ P, const float* __restrict__ E,
                     const int* __restrict__ inp, float* __restrict__ h0,
                     unsigned short* __restrict__ h016) {
  int t = blockIdx.x;
  int tid = threadIdx.x;
  __shared__ float p[V_];
  __shared__ int iw;
  if (tid < V_) p[tid] = P[t * V_ + tid];
  if (tid == 0) iw = inp[t];
  __syncthreads();
  for (int h = tid; h < H_; h += blockDim.x) {
    float acc = E[iw * H_ + h];
#pragma unroll
    for (int v = 0; v < V_; ++v) acc += p[v] * E[v * H_ + h];
    float val = ESCALE_ * acc;
    h0[(size_t)t * H_ + h] = val;
    h016[(size_t)t * H_ + h] = f2bf(val);
  }
}

__global__ void k_gfill(const float* __restrict__ ew, float* __restrict__ G) {
  int idx = blockIdx.x * blockDim.x + threadIdx.x;
  if (idx < NTOK * H_) G[idx] = ew[idx & (H_ - 1)];
}

// fp32 -> bf16 cast, 8 elems/thread (for stored-orientation weights)
__global__ void k_cast8(const float* __restrict__ X, unsigned short* __restrict__ Y, int n8) {
  int i = blockIdx.x * blockDim.x + threadIdx.x;
  if (i >= n8) return;
  const float4* p = (const float4*)(X + (size_t)i * 8);
  float4 a = p[0], b = p[1];
  bfu o;
  o.s[0] = f2bf(a.x); o.s[1] = f2bf(a.y); o.s[2] = f2bf(a.z); o.s[3] = f2bf(a.w);
  o.s[4] = f2bf(b.x); o.s[5] = f2bf(b.y); o.s[6] = f2bf(b.z); o.s[7] = f2bf(b.w);
  *(bh8*)(Y + (size_t)i * 8) = o.v;
}

// ---------------- weight transpose-convert: W[K][N] fp32 -> WT[N][K] bf16 ----------------

__global__ void k_wt(const float* __restrict__ W, unsigned short* __restrict__ WT, int K, int N) {
  __shared__ float t[32][33];
  int k0 = blockIdx.y * 32, n0 = blockIdx.x * 32;
  int tx = threadIdx.x, ty = threadIdx.y;
#pragma unroll
  for (int i = 0; i < 4; ++i)
    t[ty + 8 * i][tx] = W[(size_t)(k0 + ty + 8 * i) * N + n0 + tx];
  __syncthreads();
#pragma unroll
  for (int i = 0; i < 4; ++i)
    WT[(size_t)(n0 + ty + 8 * i) * K + k0 + tx] = f2bf(t[tx][ty + 8 * i]);
}

// ---------------- MFMA GEMM: C[M,N] = A[M,K] @ B^T (A,B bf16; B stored [N][K]) ----------------
// Tile 64x128, BK=32, 4 waves (2x2), wave-tile 32x64.
// Staging via global_load_lds (16B/lane) into linear [rows][32] LDS (64B rows: b128 frag
// reads are at the 8-pass floor). SILU_A path stages manually (fused activation).

template <int SILU_A, int ADD, int CBF>
__global__ __launch_bounds__(256) void k_gemm(const unsigned short* __restrict__ A16,
                                              const unsigned short* __restrict__ Bt,
                                              const float* __restrict__ Dm,
                                              float* __restrict__ Cf,
                                              unsigned short* __restrict__ C16,
                                              int M, int N, int K, int lda) {
  __shared__ unsigned short As[64][32];
  __shared__ unsigned short Bs[128][32];
  int tid = threadIdx.x;
  int m0 = blockIdx.y * 64, n0 = blockIdx.x * 128;
  int wid = tid >> 6, lane = tid & 63;
  int wr = (wid >> 1) * 32, wc = (wid & 1) * 64;
  int lr = lane & 15, lg = lane >> 4;
  int srow = lane >> 2, sck = (lane & 3) * 8;
  f32x4 acc[2][4] = {};
  for (int k0 = 0; k0 < K; k0 += 32) {
    __syncthreads();
    if (SILU_A) {
      int row = tid >> 2, ck = (tid & 3) * 8;
      int gr = m0 + row; gr = gr < M ? gr : M - 1;
      const unsigned short* src = &A16[(size_t)gr * lda + k0 + ck];
      bfu pa;
#pragma unroll
      for (int j = 0; j < 8; ++j) {
        float g = b2f(src[j]), u = b2f(src[INNER_ + j]);
        pa.s[j] = f2bf((g / (1.f + __expf(-g))) * u);
      }
      *(bh8*)&As[row][ck] = pa.v;
    } else {
      int row = wid * 16 + srow;
      int gr = m0 + row; gr = gr < M ? gr : M - 1;
      gld16(&A16[(size_t)gr * lda + k0 + sck], &As[wid * 16][0]);
    }
#pragma unroll
    for (int i = 0; i < 2; ++i) {
      int bb = wid * 2 + i;
      gld16(&Bt[(size_t)(n0 + bb * 16 + srow) * K + k0 + sck], &Bs[bb * 16][0]);
    }
    __syncthreads();
    bh8 av[2], bv[4];
#pragma unroll
    for (int fr = 0; fr < 2; ++fr) av[fr] = *(const bh8*)&As[wr + fr * 16 + lr][lg * 8];
#pragma unroll
    for (int fc = 0; fc < 4; ++fc) bv[fc] = *(const bh8*)&Bs[wc + fc * 16 + lr][lg * 8];
#pragma unroll
    for (int fr = 0; fr < 2; ++fr)
#pragma unroll
      for (int fc = 0; fc < 4; ++fc)
        acc[fr][fc] = __builtin_amdgcn_mfma_f32_16x16x32_bf16(av[fr], bv[fc], acc[fr][fc], 0, 0, 0);
  }
#pragma unroll
  for (int fr = 0; fr < 2; ++fr) {
    int r0 = m0 + wr + fr * 16 + lg * 4;
#pragma unroll
    for (int i = 0; i < 4; ++i) {
      int gr = r0 + i;
      if (gr >= M) continue;
#pragma unroll
      for (int fc = 0; fc < 4; ++fc) {
        int gc = n0 + wc + fc * 16 + lr;
        float out = acc[fr][fc][i];
        if (ADD) out += Dm[(size_t)gr * N + gc];
        if (CBF) C16[(size_t)gr * N + gc] = f2bf(out);
        else Cf[(size_t)gr * N + gc] = out;
      }
    }
  }
}

// ---------------- RoPE fwd/bwd on bf16 qkv ----------------

template <int BWD>
__global__ void k_rope(unsigned short* __restrict__ Q, const float* __restrict__ cs,
                       const float* __restrict__ sn) {
  int idx = blockIdx.x * blockDim.x + threadIdx.x;
  if (idx >= NTOK * NH_ * 2 * 32) return;
  int i = idx & 31;
  int h = (idx >> 5) & (NH_ - 1);
  int part = (idx >> 8) & 1;
  int t = idx >> 9;
  int s = t % S_;
  float c = cs[s * 32 + i], sv = sn[s * 32 + i];
  size_t base = ((size_t)t * 3 * NH_ + part * NH_ + h) * HD_;
  float x1 = b2f(Q[base + i]), x2 = b2f(Q[base + 32 + i]);
  if (!BWD) {
    Q[base + i] = f2bf(x1 * c - x2 * sv);
    Q[base + 32 + i] = f2bf(x2 * c + x1 * sv);
  } else {
    Q[base + i] = f2bf(x1 * c + x2 * sv);
    Q[base + 32 + i] = f2bf(x2 * c - x1 * sv);
  }
}

// ---------------- MFMA flash attention (bf16 QKV, bf16 O) ----------------

__global__ __launch_bounds__(256) void k_attn_fwd3(const unsigned short* __restrict__ QKV,
                                                   unsigned short* __restrict__ AO,
                                                   float* __restrict__ MB,
                                                   float* __restrict__ LB) {
  __shared__ unsigned short Ks[64][PT_];
  __shared__ unsigned short VT[64][PT_];
  __shared__ unsigned short Ps[4][16][PT_];
  int tid = threadIdx.x;
  int h = blockIdx.y, b = blockIdx.z;
  int w = tid >> 6, lane = tid & 63;
  int lr = lane & 15, lg = lane >> 4;
  int q0 = blockIdx.x * 64 + w * 16;

  bh8 qf[2];
  {
    int qr = q0 + lr; if (qr >= S_) qr = S_ - 1;
    const unsigned short* qp = &QKV[((size_t)(b * S_ + qr) * 24 + h) * 64 + lg * 8];
    qf[0] = *(const bh8*)qp;
    qf[1] = *(const bh8*)(qp + 32);
  }
  f32x4 accO[4] = {};
  float m[4], lsum[4];
#pragma unroll
  for (int i = 0; i < 4; ++i) { m[i] = -1e30f; lsum[i] = 0.f; }

  for (int kt = 0; kt < S_; kt += 64) {
    __syncthreads();
    {
      int r = tid >> 2, c0 = (tid & 3) * 16;
      int src = kt + r;
      size_t ts = (size_t)b * S_ + (src < S_ ? src : S_ - 1);
      const unsigned short* gp = &QKV[(ts * 24 + 8 + h) * 64 + c0];
      bfu p0, p1;
      p0.v = *(const bh8*)gp;
      p1.v = *(const bh8*)(gp + 8);
      sts16(&Ks[r][c0], p0);
      sts16(&Ks[r][c0 + 8], p1);
    }
    {
      int d0 = (tid & 15) * 4, k0r = (tid >> 4) * 4;
      us4 rv[4];
#pragma unroll
      for (int j = 0; j < 4; ++j) {
        int src = kt + k0r + j;
        size_t ts = (size_t)b * S_ + (src < S_ ? src : S_ - 1);
        rv[j] = *(const us4*)&QKV[(ts * 24 + 16 + h) * 64 + d0];
      }
#pragma unroll
      for (int dd = 0; dd < 4; ++dd) {
        us4 pk = {rv[0][dd], rv[1][dd], rv[2][dd], rv[3][dd]};
        *(us4*)&VT[d0 + dd][k0r] = pk;
      }
    }
    __syncthreads();
    f32x4 accS[4] = {};
#pragma unroll
    for (int ks = 0; ks < 2; ++ks)
#pragma unroll
      for (int fk = 0; fk < 4; ++fk)
        accS[fk] = __builtin_amdgcn_mfma_f32_16x16x32_bf16(qf[ks], lds16(&Ks[fk * 16 + lr][ks * 32 + lg * 8]), accS[fk], 0, 0, 0);
    float sc[4][4], pmax[4];
#pragma unroll
    for (int i = 0; i < 4; ++i) pmax[i] = -1e30f;
#pragma unroll
    for (int fk = 0; fk < 4; ++fk)
#pragma unroll
      for (int i = 0; i < 4; ++i) {
        float s = accS[fk][i] * SCALE_;
        if (kt + fk * 16 + lr >= S_) s = -1e30f;
        sc[fk][i] = s;
        pmax[i] = fmaxf(pmax[i], s);
      }
#pragma unroll
    for (int i = 0; i < 4; ++i) {
      float v = pmax[i];
      v = fmaxf(v, __shfl_xor(v, 1, 64));
      v = fmaxf(v, __shfl_xor(v, 2, 64));
      v = fmaxf(v, __shfl_xor(v, 4, 64));
      v = fmaxf(v, __shfl_xor(v, 8, 64));
      pmax[i] = v;
    }
    float psum[4];
#pragma unroll
    for (int i = 0; i < 4; ++i) {
      float mn = fmaxf(m[i], pmax[i]);
      float eo = __expf(m[i] - mn);
      m[i] = mn;
      lsum[i] *= eo;
#pragma unroll
      for (int fd = 0; fd < 4; ++fd) accO[fd][i] *= eo;
      psum[i] = 0.f;
    }
#pragma unroll
    for (int fk = 0; fk < 4; ++fk)
#pragma unroll
      for (int i = 0; i < 4; ++i) {
        float p = __expf(sc[fk][i] - m[i]);
        sc[fk][i] = p;
        psum[i] += p;
      }
#pragma unroll
    for (int i = 0; i < 4; ++i) {
      float v = psum[i];
      v += __shfl_xor(v, 1, 64);
      v += __shfl_xor(v, 2, 64);
      v += __shfl_xor(v, 4, 64);
      v += __shfl_xor(v, 8, 64);
      lsum[i] += v;
    }
#pragma unroll
    for (int fk = 0; fk < 4; ++fk)
#pragma unroll
      for (int i = 0; i < 4; ++i)
        Ps[w][lg * 4 + i][fk * 16 + lr] = f2bf(sc[fk][i]);
#pragma unroll
    for (int ks = 0; ks < 2; ++ks) {
      bh8 ap = lds16(&Ps[w][lr][ks * 32 + lg * 8]);
#pragma unroll
      for (int fd = 0; fd < 4; ++fd)
        accO[fd] = __builtin_amdgcn_mfma_f32_16x16x32_bf16(ap, lds16(&VT[fd * 16 + lr][ks * 32 + lg * 8]), accO[fd], 0, 0, 0);
    }
  }
#pragma unroll
  for (int i = 0; i < 4; ++i) {
    int q = q0 + lg * 4 + i;
    if (q < S_) {
      float linv = 1.f / lsum[i];
      size_t obase = (size_t)(b * S_ + q) * H_ + h * 64;
#pragma unroll
      for (int fd = 0; fd < 4; ++fd) AO[obase + fd * 16 + lr] = f2bf(accO[fd][i] * linv);
      if (lr == 0) {
        MB[((size_t)b * NH_ + h) * S_ + q] = m[i];
        LB[((size_t)b * NH_ + h) * S_ + q] = linv;
      }
    }
  }
}

// delta[b,h,q] = dot(dO_row, O_row), both bf16
__global__ __launch_bounds__(256) void k_delta(const unsigned short* __restrict__ O,
                                               const unsigned short* __restrict__ dO,
                                               float* __restrict__ DB) {
  int tid = threadIdx.x;
  int h = blockIdx.y, b = blockIdx.z;
  int r = blockIdx.x * 64 + (tid >> 2), part = tid & 3;
  if (r >= S_) return;
  size_t base = (size_t)(b * S_ + r) * H_ + h * 64 + part * 16;
  bfu o0, o1, d0, d1;
  o0.v = *(const bh8*)&O[base];  o1.v = *(const bh8*)&O[base + 8];
  d0.v = *(const bh8*)&dO[base]; d1.v = *(const bh8*)&dO[base + 8];
  float s = 0.f;
#pragma unroll
  for (int j = 0; j < 8; ++j)
    s += b2f(o0.s[j]) * b2f(d0.s[j]) + b2f(o1.s[j]) * b2f(d1.s[j]);
  s = quad_sum(s);
  if (part == 0) DB[((size_t)b * NH_ + h) * S_ + r] = s;
}

// dQ pass
__global__ __launch_bounds__(256) void k_attn_bwd_dq3(const unsigned short* __restrict__ QKV,
                                                      const unsigned short* __restrict__ dO,
                                                      const float* __restrict__ MB,
                                                      const float* __restrict__ LB,
                                                      const float* __restrict__ DB,
                                                      unsigned short* __restrict__ dQKV) {
  __shared__ unsigned short Ks[64][PT_];
  __shared__ unsigned short Vs[64][PT_];
  __shared__ unsigned short KT[64][PT_];
  __shared__ unsigned short Ps[4][16][PT_];
  int tid = threadIdx.x;
  int h = blockIdx.y, b = blockIdx.z;
  int w = tid >> 6, lane = tid & 63;
  int lr = lane & 15, lg = lane >> 4;
  int q0 = blockIdx.x * 64 + w * 16;
  size_t sbase = ((size_t)b * NH_ + h) * S_;

  bh8 qf[2], dof[2];
  {
    int qr = q0 + lr; if (qr >= S_) qr = S_ - 1;
    const unsigned short* qp = &QKV[((size_t)(b * S_ + qr) * 24 + h) * 64 + lg * 8];
    const unsigned short* dp = &dO[(size_t)(b * S_ + qr) * H_ + h * 64 + lg * 8];
    qf[0] = *(const bh8*)qp;  qf[1] = *(const bh8*)(qp + 32);
    dof[0] = *(const bh8*)dp; dof[1] = *(const bh8*)(dp + 32);
  }
  float mrow[4], lrow[4], drow[4];
#pragma unroll
  for (int i = 0; i < 4; ++i) {
    int q = q0 + lg * 4 + i; if (q >= S_) q = S_ - 1;
    mrow[i] = MB[sbase + q];
    lrow[i] = LB[sbase + q];
    drow[i] = DB[sbase + q];
  }
  f32x4 accQ[4] = {};

  for (int kt = 0; kt < S_; kt += 64) {
    __syncthreads();
    {
      int r = tid >> 2, c0 = (tid & 3) * 16;
      int src = kt + r;
      bool vld = src < S_;
      size_t ts = (size_t)b * S_ + (vld ? src : S_ - 1);
      const unsigned short* kp = &QKV[(ts * 24 + 8 + h) * 64 + c0];
      bfu p0{}, p1{}, p2{}, p3{};
      if (vld) {
        p0.v = *(const bh8*)kp;
        p1.v = *(const bh8*)(kp + 8);
        p2.v = *(const bh8*)(kp + 512);
        p3.v = *(const bh8*)(kp + 520);
      }
      sts16(&Ks[r][c0], p0); sts16(&Ks[r][c0 + 8], p1);
      sts16(&Vs[r][c0], p2); sts16(&Vs[r][c0 + 8], p3);
    }
    {
      int d0 = (tid & 15) * 4, k0r = (tid >> 4) * 4;
      us4 rv[4];
#pragma unroll
      for (int j = 0; j < 4; ++j) {
        int src = kt + k0r + j;
        bool vld = src < S_;
        size_t ts = (size_t)b * S_ + (vld ? src : S_ - 1);
        us4 t = *(const us4*)&QKV[(ts * 24 + 8 + h) * 64 + d0];
        if (!vld) t = us4{0, 0, 0, 0};
        rv[j] = t;
      }
#pragma unroll
      for (int dd = 0; dd < 4; ++dd) {
        us4 pk = {rv[0][dd], rv[1][dd], rv[2][dd], rv[3][dd]};
        *(us4*)&KT[d0 + dd][k0r] = pk;
      }
    }
    __syncthreads();
    f32x4 aS[4] = {}, aD[4] = {};
#pragma unroll
    for (int ks = 0; ks < 2; ++ks)
#pragma unroll
      for (int fk = 0; fk < 4; ++fk) {
        aS[fk] = __builtin_amdgcn_mfma_f32_16x16x32_bf16(qf[ks], lds16(&Ks[fk * 16 + lr][ks * 32 + lg * 8]), aS[fk], 0, 0, 0);
        aD[fk] = __builtin_amdgcn_mfma_f32_16x16x32_bf16(dof[ks], lds16(&Vs[fk * 16 + lr][ks * 32 + lg * 8]), aD[fk], 0, 0, 0);
      }
#pragma unroll
    for (int fk = 0; fk < 4; ++fk)
#pragma unroll
      for (int i = 0; i < 4; ++i) {
        float p = __expf(aS[fk][i] * SCALE_ - mrow[i]) * lrow[i];
        float ds = p * (aD[fk][i] - drow[i]);
        Ps[w][lg * 4 + i][fk * 16 + lr] = f2bf(ds);
      }
#pragma unroll
    for (int ks = 0; ks < 2; ++ks) {
      bh8 ap = lds16(&Ps[w][lr][ks * 32 + lg * 8]);
#pragma unroll
      for (int fd = 0; fd < 4; ++fd)
        accQ[fd] = __builtin_amdgcn_mfma_f32_16x16x32_bf16(ap, lds16(&KT[fd * 16 + lr][ks * 32 + lg * 8]), accQ[fd], 0, 0, 0);
    }
  }
#pragma unroll
  for (int i = 0; i < 4; ++i) {
    int q = q0 + lg * 4 + i;
    if (q < S_) {
      size_t obase = ((size_t)(b * S_ + q) * 24 + h) * 64;
#pragma unroll
      for (int fd = 0; fd < 4; ++fd) dQKV[obase + fd * 16 + lr] = f2bf(SCALE_ * accQ[fd][i]);
    }
  }
}

// dK + dV pass
__global__ __launch_bounds__(256) void k_attn_bwd_kv3(const unsigned short* __restrict__ QKV,
                                                      const unsigned short* __restrict__ dO,
                                                      const float* __restrict__ MB,
                                                      const float* __restrict__ LB,
                                                      const float* __restrict__ DB,
                                                      unsigned short* __restrict__ dQKV) {
  __shared__ unsigned short Qs[64][PT_];
  __shared__ unsigned short dOs[64][PT_];
  __shared__ unsigned short QT[64][PT_];
  __shared__ unsigned short dOT[64][PT_];
  __shared__ unsigned short Ps[4][16][PT_];
  __shared__ float sM[64], sL[64], sD[64];
  int tid = threadIdx.x;
  int h = blockIdx.y, b = blockIdx.z;
  int w = tid >> 6, lane = tid & 63;
  int lr = lane & 15, lg = lane >> 4;
  int k0w = blockIdx.x * 64 + w * 16;
  size_t sbase = ((size_t)b * NH_ + h) * S_;

  bh8 kf[2], vf[2];
  {
    int kr = k0w + lr; if (kr >= S_) kr = S_ - 1;
    const unsigned short* kp = &QKV[((size_t)(b * S_ + kr) * 24 + 8 + h) * 64 + lg * 8];
    kf[0] = *(const bh8*)kp;        kf[1] = *(const bh8*)(kp + 32);
    vf[0] = *(const bh8*)(kp + 512); vf[1] = *(const bh8*)(kp + 544);
  }
  f32x4 accK[4] = {}, accV[4] = {};

  for (int qt = 0; qt < S_; qt += 64) {
    __syncthreads();
    {
      int r = tid >> 2, c0 = (tid & 3) * 16;
      int src = qt + r;
      bool vld = src < S_;
      size_t ts = (size_t)b * S_ + (vld ? src : S_ - 1);
      const unsigned short* qp = &QKV[(ts * 24 + h) * 64 + c0];
      const unsigned short* dp = &dO[ts * H_ + h * 64 + c0];
      bfu p0, p1, p2{}, p3{};
      p0.v = *(const bh8*)qp;
      p1.v = *(const bh8*)(qp + 8);
      if (vld) {
        p2.v = *(const bh8*)dp;
        p3.v = *(const bh8*)(dp + 8);
      }
      sts16(&Qs[r][c0], p0);  sts16(&Qs[r][c0 + 8], p1);
      sts16(&dOs[r][c0], p2); sts16(&dOs[r][c0 + 8], p3);
    }
    {
      int d0 = (tid & 15) * 4, q0r = (tid >> 4) * 4;
      us4 rq[4], rd[4];
#pragma unroll
      for (int j = 0; j < 4; ++j) {
        int src = qt + q0r + j;
        bool vld = src < S_;
        size_t ts = (size_t)b * S_ + (vld ? src : S_ - 1);
        rq[j] = *(const us4*)&QKV[(ts * 24 + h) * 64 + d0];
        us4 td = *(const us4*)&dO[ts * H_ + h * 64 + d0];
        if (!vld) td = us4{0, 0, 0, 0};
        rd[j] = td;
      }
#pragma unroll
      for (int dd = 0; dd < 4; ++dd) {
        us4 pq = {rq[0][dd], rq[1][dd], rq[2][dd], rq[3][dd]};
        us4 pd = {rd[0][dd], rd[1][dd], rd[2][dd], rd[3][dd]};
        *(us4*)&QT[d0 + dd][q0r] = pq;
        *(us4*)&dOT[d0 + dd][q0r] = pd;
      }
    }
    if (tid < 64) {
      int src = qt + tid;
      bool vld = src < S_;
      int sc = vld ? src : S_ - 1;
      sM[tid] = MB[sbase + sc];
      sL[tid] = LB[sbase + sc];
      sD[tid] = vld ? DB[sbase + sc] : 0.f;
    }
    __syncthreads();
    f32x4 aS[4] = {}, aD[4] = {};
#pragma unroll
    for (int ks = 0; ks < 2; ++ks)
#pragma unroll
      for (int fq = 0; fq < 4; ++fq) {
        aS[fq] = __builtin_amdgcn_mfma_f32_16x16x32_bf16(kf[ks], lds16(&Qs[fq * 16 + lr][ks * 32 + lg * 8]), aS[fq], 0, 0, 0);
        aD[fq] = __builtin_amdgcn_mfma_f32_16x16x32_bf16(vf[ks], lds16(&dOs[fq * 16 + lr][ks * 32 + lg * 8]), aD[fq], 0, 0, 0);
      }
    float pv[4][4];
#pragma unroll
    for (int fq = 0; fq < 4; ++fq) {
      float mq = sM[fq * 16 + lr], lq = sL[fq * 16 + lr];
#pragma unroll
      for (int i = 0; i < 4; ++i) {
        float p = __expf(aS[fq][i] * SCALE_ - mq) * lq;
        pv[fq][i] = p;
        Ps[w][lg * 4 + i][fq * 16 + lr] = f2bf(p);
      }
    }
#pragma unroll
    for (int qs = 0; qs < 2; ++qs) {
      bh8 ap = lds16(&Ps[w][lr][qs * 32 + lg * 8]);
#pragma unroll
      for (int fd = 0; fd < 4; ++fd)
        accV[fd] = __builtin_amdgcn_mfma_f32_16x16x32_bf16(ap, lds16(&dOT[fd * 16 + lr][qs * 32 + lg * 8]), accV[fd], 0, 0, 0);
    }
#pragma unroll
    for (int fq = 0; fq < 4; ++fq) {
      float dq = sD[fq * 16 + lr];
#pragma unroll
      for (int i = 0; i < 4; ++i)
        Ps[w][lg * 4 + i][fq * 16 + lr] = f2bf(pv[fq][i] * (aD[fq][i] - dq));
    }
#pragma unroll
    for (int qs = 0; qs < 2; ++qs) {
      bh8 ap = lds16(&Ps[w][lr][qs * 32 + lg * 8]);
#pragma unroll
      for (int fd = 0; fd < 4; ++fd)
        accK[fd] = __builtin_amdgcn_mfma_f32_16x16x32_bf16(ap, lds16(&QT[fd * 16 + lr][qs * 32 + lg * 8]), accK[fd], 0, 0, 0);
    }
  }
#pragma unroll
  for (int i = 0; i < 4; ++i) {
    int k = k0w + lg * 4 + i;
    if (k < S_) {
      size_t obase = ((size_t)(b * S_ + k) * 24 + 8 + h) * 64;
#pragma unroll
      for (int fd = 0; fd < 4; ++fd) {
        dQKV[obase + fd * 16 + lr] = f2bf(SCALE_ * accK[fd][i]);
        dQKV[obase + 512 + fd * 16 + lr] = f2bf(accV[fd][i]);
      }
    }
  }
}

// ---------------- RMS norm fwd/bwd (dual fp32+bf16 outputs) ----------------

__global__ __launch_bounds__(256) void k_rms_fwd(const float* __restrict__ X, float* __restrict__ Y,
                                                 unsigned short* __restrict__ Y16) {
  int t = blockIdx.x, tid = threadIdx.x;
  float x0 = X[(size_t)t * H_ + tid], x1 = X[(size_t)t * H_ + tid + 256];
  __shared__ float red[256];
  red[tid] = x0 * x0 + x1 * x1;
  __syncthreads();
  for (int s = 128; s > 0; s >>= 1) {
    if (tid < s) red[tid] += red[tid + s];
    __syncthreads();
  }
  float r = rsqrtf(red[0] / H_ + EPS_);
  float y0 = x0 * r, y1 = x1 * r;
  Y[(size_t)t * H_ + tid] = y0;
  Y[(size_t)t * H_ + tid + 256] = y1;
  Y16[(size_t)t * H_ + tid] = f2bf(y0);
  Y16[(size_t)t * H_ + tid + 256] = f2bf(y1);
}

__global__ __launch_bounds__(256) void k_rms_bwd(const float* __restrict__ X,
                                                 const float* __restrict__ GY,
                                                 float* __restrict__ GX,
                                                 unsigned short* __restrict__ GX16) {
  int t = blockIdx.x, tid = threadIdx.x;
  float x0 = X[(size_t)t * H_ + tid], x1 = X[(size_t)t * H_ + tid + 256];
  float g0 = GY[(size_t)t * H_ + tid], g1 = GY[(size_t)t * H_ + tid + 256];
  __shared__ float r1[256], r2[256];
  r1[tid] = x0 * x0 + x1 * x1;
  r2[tid] = x0 * g0 + x1 * g1;
  __syncthreads();
  for (int s = 128; s > 0; s >>= 1) {
    if (tid < s) { r1[tid] += r1[tid + s]; r2[tid] += r2[tid + s]; }
    __syncthreads();
  }
  float r = rsqrtf(r1[0] / H_ + EPS_);
  float coef = r * r * r * r2[0] / (float)H_;
  float o0 = r * g0 - coef * x0, o1 = r * g1 - coef * x1;
  GX[(size_t)t * H_ + tid] = o0;
  GX[(size_t)t * H_ + tid + 256] = o1;
  GX16[(size_t)t * H_ + tid] = f2bf(o0);
  GX16[(size_t)t * H_ + tid + 256] = f2bf(o1);
}

// ---------------- SiLU-gate backward (bf16 GU in place) ----------------

__global__ void k_silu_bwd(unsigned short* __restrict__ GU, const float* __restrict__ dact) {
  int idx = blockIdx.x * blockDim.x + threadIdx.x;
  if (idx >= NTOK * INNER_ / 8) return;
  int t = idx / (INNER_ / 8), i8 = (idx % (INNER_ / 8)) * 8;
  size_t gb = (size_t)t * 2 * INNER_;
  bfu g8, u8, og, ou;
  g8.v = *(const bh8*)&GU[gb + i8];
  u8.v = *(const bh8*)&GU[gb + INNER_ + i8];
  const float* da = &dact[(size_t)t * INNER_ + i8];
#pragma unroll
  for (int j = 0; j < 8; ++j) {
    float g = b2f(g8.s[j]), u = b2f(u8.s[j]), d = da[j];
    float sig = 1.f / (1.f + __expf(-g));
    og.s[j] = f2bf(d * u * sig * (1.f + g * (1.f - sig)));
    ou.s[j] = f2bf(d * g * sig);
  }
  *(bh8*)&GU[gb + i8] = og.v;
  *(bh8*)&GU[gb + INNER_ + i8] = ou.v;
}

// ---------------- logits update ----------------

__global__ __launch_bounds__(64) void k_logits_update(const float* __restrict__ G,
                                                      const float* __restrict__ E,
                                                      const float* __restrict__ P,
                                                      const float* __restrict__ alpha,
                                                      float* __restrict__ logits) {
  int t = blockIdx.x, lane = threadIdx.x;
  float dp[V_];
#pragma unroll
  for (int v = 0; v < V_; ++v) dp[v] = 0.f;
  for (int hh = lane; hh < H_; hh += 64) {
    float gh = G[(size_t)t * H_ + hh];
#pragma unroll
    for (int v = 0; v < V_; ++v) dp[v] += gh * E[v * H_ + hh];
  }
#pragma unroll
  for (int v = 0; v < V_; ++v) dp[v] = wave_sum64(dp[v]) * ESCALE_;
  float dot = 0.f;
  float pv[V_];
#pragma unroll
  for (int v = 0; v < V_; ++v) {
    pv[v] = P[t * V_ + v];
    dot += pv[v] * dp[v];
  }
  float a = fmaxf(alpha[0], 1e-4f);
  if (lane < V_) logits[t * V_ + lane] -= a * pv[lane] * (dp[lane] - dot);
}

// ---------------- host-side orchestration ----------------
// All GEMM operands bf16: weights pre-converted both orientations (WT transposed for fwd,
// WS stored for bwd); activations get bf16 twins (X116, UDX16) written by k_h0/rms kernels.
// AO/AO0 bf16. ACT(fp32) aliases dQ16. L0 attention checkpoint as before.

struct Ctx {
  unsigned short *Q16, *Q016, *dQ16, *GU16, *DO16, *AO16, *AO016, *X116, *UDX16;
  float *ACT, *X1, *X2, *G, *UDX, *P, *MB, *LB, *DB, *MB0, *LB0, *CS, *SN;
  const unsigned short *WTqkv[2], *WTo[2], *WTgu[2], *WTd[2];
  const unsigned short *WSqkv[2], *WSo[2], *WSgu[2], *WSd[2];
  hipStream_t st;
};

static inline dim3 ggrid(int M, int N) { return dim3(N / 128, (M + 63) / 64); }

static void block_forward(Ctx& c, int l, const float* hin, const unsigned short* hin16,
                          float* hout, unsigned short* qb, unsigned short* ao,
                          float* mb, float* lb, bool skip_attn) {
  if (!skip_attn) {
    k_gemm<0, 0, 1><<<ggrid(NTOK, 3 * H_), 256, 0, c.st>>>(
        hin16, c.WTqkv[l], nullptr, nullptr, qb, NTOK, 3 * H_, H_, H_);
    k_rope<0><<<(NTOK * NH_ * 2 * 32 + 255) / 256, 256, 0, c.st>>>(qb, c.CS, c.SN);
    k_attn_fwd3<<<dim3((S_ + 63) / 64, NH_, B_), 256, 0, c.st>>>(qb, ao, mb, lb);
  }
  k_gemm<0, 1, 0><<<ggrid(NTOK, H_), 256, 0, c.st>>>(
      ao, c.WTo[l], hin, c.X1, nullptr, NTOK, H_, H_, H_);
  k_rms_fwd<<<NTOK, 256, 0, c.st>>>(c.X1, c.UDX, c.UDX16);
  k_gemm<0, 0, 1><<<ggrid(NTOK, 2 * INNER_), 256, 0, c.st>>>(
      c.UDX16, c.WTgu[l], nullptr, nullptr, c.GU16, NTOK, 2 * INNER_, H_, H_);
  k_gemm<1, 1, 0><<<ggrid(NTOK, H_), 256, 0, c.st>>>(
      c.GU16, c.WTd[l], c.UDX, c.X2, nullptr, NTOK, H_, INNER_, 2 * INNER_);
  if (hout) k_rms_fwd<<<NTOK, 256, 0, c.st>>>(c.X2, hout, c.UDX16);  // h1 fp32 + h1_16
}

static void block_backward(Ctx& c, int l, const float* hin, const unsigned short* hin16,
                           unsigned short* qb, unsigned short* ao, float* mb, float* lb,
                           bool skip_attn) {
  block_forward(c, l, hin, hin16, nullptr, qb, ao, mb, lb, skip_attn);
  k_rms_bwd<<<NTOK, 256, 0, c.st>>>(c.X2, c.G, c.UDX, c.UDX16);
  k_gemm<0, 0, 0><<<ggrid(NTOK, INNER_), 256, 0, c.st>>>(
      c.UDX16, c.WSd[l], nullptr, c.ACT, nullptr, NTOK, INNER_, H_, H_);
  k_silu_bwd<<<(NTOK * INNER_ / 8 + 255) / 256, 256, 0, c.st>>>(c.GU16, c.ACT);
  k_gemm<0, 1, 0><<<ggrid(NTOK, H_), 256, 0, c.st>>>(
      c.GU16, c.WSgu[l], c.UDX, c.G, nullptr, NTOK, H_, 2 * INNER_, 2 * INNER_);
  k_rms_bwd<<<NTOK, 256, 0, c.st>>>(c.X1, c.G, c.UDX, c.UDX16);
  k_gemm<0, 0, 1><<<ggrid(NTOK, H_), 256, 0, c.st>>>(
      c.UDX16, c.WSo[l], nullptr, nullptr, c.DO16, NTOK, H_, H_, H_);
  dim3 agrid((S_ + 63) / 64, NH_, B_);
  k_delta<<<agrid, 256, 0, c.st>>>(ao, c.DO16, c.DB);
  k_attn_bwd_dq3<<<agrid, 256, 0, c.st>>>(qb, c.DO16, mb, lb, c.DB, c.dQ16);
  k_attn_bwd_kv3<<<agrid, 256, 0, c.st>>>(qb, c.DO16, mb, lb, c.DB, c.dQ16);
  k_rope<1><<<(NTOK * NH_ * 2 * 32 + 255) / 256, 256, 0, c.st>>>(c.dQ16, c.CS, c.SN);
  k_gemm<0, 1, 0><<<ggrid(NTOK, H_), 256, 0, c.st>>>(
      c.dQ16, c.WSqkv[l], c.UDX, c.G, nullptr, NTOK, H_, 3 * H_, 3 * H_);
}

extern "C" void kernel_launch(void* const* d_in, const int* in_sizes, int n_in,
                              void* d_out, int out_size, void* d_ws, size_t ws_size,
                              hipStream_t stream) {
  const int* inputs = (const int*)d_in[0];
  const float* E = (const float*)d_in[2];
  const float* ew = (const float*)d_in[3];
  const float* qkvw = (const float*)d_in[4];
  const float* ow = (const float*)d_in[5];
  const float* guw = (const float*)d_in[6];
  const float* dw = (const float*)d_in[7];
  const float* alpha = (const float*)d_in[8];
  float* logits = (float*)d_out;

  const size_t WT_FLOATS = 3407872;  // bf16 elems/2 per orientation, both layers
  const size_t NEED =
      2 * ((size_t)NTOK * 3 * H_ / 2) +  // Q16, Q016
      ((size_t)NTOK * INNER_) +          // GU16
      ((size_t)NTOK * INNER_) +          // ACT fp32 (aliases dQ16)
      4 * ((size_t)NTOK * H_) +          // X1, X2, G, UDX (fp32)
      2 * ((size_t)NTOK * H_ / 2) +      // AO16, AO016
      3 * ((size_t)NTOK * H_ / 2) +      // DO16, X116, UDX16
      ((size_t)NTOK * V_) +              // P
      5 * ((size_t)B_ * NH_ * S_) +      // stats
      2 * ((size_t)S_ * 32) +            // CS, SN
      2 * WT_FLOATS;                     // WT + WS
  if (ws_size < NEED * sizeof(float)) {
    k_zero<<<(NTOK * V_ + 255) / 256, 256, 0, stream>>>(logits, NTOK * V_);
    return;
  }

  float* f = (float*)d_ws;
  Ctx c;
  c.st = stream;
  c.Q16 = (unsigned short*)f;  f += (size_t)NTOK * 3 * H_ / 2;
  c.Q016 = (unsigned short*)f; f += (size_t)NTOK * 3 * H_ / 2;
  c.GU16 = (unsigned short*)f; f += (size_t)NTOK * INNER_;
  c.ACT = f; c.dQ16 = (unsigned short*)f; f += (size_t)NTOK * INNER_;
  c.X1 = f;   f += (size_t)NTOK * H_;
  c.X2 = f;   f += (size_t)NTOK * H_;
  c.G = f;    f += (size_t)NTOK * H_;
  c.UDX = f;  f += (size_t)NTOK * H_;
  c.AO16 = (unsigned short*)f;  f += (size_t)NTOK * H_ / 2;
  c.AO016 = (unsigned short*)f; f += (size_t)NTOK * H_ / 2;
  c.DO16 = (unsigned short*)f;  f += (size_t)NTOK * H_ / 2;
  c.X116 = (unsigned short*)f;  f += (size_t)NTOK * H_ / 2;
  c.UDX16 = (unsigned short*)f; f += (size_t)NTOK * H_ / 2;
  c.P = f;    f += (size_t)NTOK * V_;
  c.MB = f;   f += (size_t)B_ * NH_ * S_;
  c.LB = f;   f += (size_t)B_ * NH_ * S_;
  c.DB = f;   f += (size_t)B_ * NH_ * S_;
  c.MB0 = f;  f += (size_t)B_ * NH_ * S_;
  c.LB0 = f;  f += (size_t)B_ * NH_ * S_;
  c.CS = f;   f += (size_t)S_ * 32;
  c.SN = f;   f += (size_t)S_ * 32;
  unsigned short* wt = (unsigned short*)f;

  const size_t LQKV = (size_t)H_ * 3 * H_;
  const size_t LO = (size_t)H_ * H_;
  const size_t LGU = (size_t)H_ * 2 * INNER_;
  const size_t LD = (size_t)INNER_ * H_;

  // transposed bf16 weights (forward)
  for (int l = 0; l < 2; ++l) {
    c.WTqkv[l] = wt;
    k_wt<<<dim3(3 * H_ / 32, H_ / 32), dim3(32, 8), 0, stream>>>(qkvw + l * LQKV, wt, H_, 3 * H_);
    wt += LQKV;
    c.WTo[l] = wt;
    k_wt<<<dim3(H_ / 32, H_ / 32), dim3(32, 8), 0, stream>>>(ow + l * LO, wt, H_, H_);
    wt += LO;
    c.WTgu[l] = wt;
    k_wt<<<dim3(2 * INNER_ / 32, H_ / 32), dim3(32, 8), 0, stream>>>(guw + l * LGU, wt, H_, 2 * INNER_);
    wt += LGU;
    c.WTd[l] = wt;
    k_wt<<<dim3(H_ / 32, INNER_ / 32), dim3(32, 8), 0, stream>>>(dw + l * LD, wt, INNER_, H_);
    wt += LD;
  }
  // stored-orientation bf16 weights (backward) — straight casts, both layers per array
  {
    unsigned short* ws = wt;
    k_cast8<<<(int)((2 * LQKV / 8 + 255) / 256), 256, 0, stream>>>(qkvw, ws, (int)(2 * LQKV / 8));
    c.WSqkv[0] = ws; c.WSqkv[1] = ws + LQKV; ws += 2 * LQKV;
    k_cast8<<<(int)((2 * LO / 8 + 255) / 256), 256, 0, stream>>>(ow, ws, (int)(2 * LO / 8));
    c.WSo[0] = ws; c.WSo[1] = ws + LO; ws += 2 * LO;
    k_cast8<<<(int)((2 * LGU / 8 + 255) / 256), 256, 0, stream>>>(guw, ws, (int)(2 * LGU / 8));
    c.WSgu[0] = ws; c.WSgu[1] = ws + LGU; ws += 2 * LGU;
    k_cast8<<<(int)((2 * LD / 8 + 255) / 256), 256, 0, stream>>>(dw, ws, (int)(2 * LD / 8));
    c.WSd[0] = ws; c.WSd[1] = ws + LD;
  }

  k_zero<<<(NTOK * V_ + 255) / 256, 256, 0, stream>>>(logits, NTOK * V_);
  k_rope_tables<<<(S_ * 32 + 255) / 256, 256, 0, stream>>>(c.CS, c.SN);

  for (int step = 0; step < STEPS_; ++step) {
    k_softmax_logits<<<(NTOK + 255) / 256, 256, 0, stream>>>(logits, c.P);
    k_h0<<<NTOK, 256, 0, stream>>>(c.P, E, inputs, c.X1, c.X116);
    // forward L0; h1 -> UDX (fp32) + UDX16 (bf16); attention state checkpointed
    block_forward(c, 0, c.X1, c.X116, c.UDX, c.Q016, c.AO016, c.MB0, c.LB0, false);
    k_gfill<<<(NTOK * H_ + 255) / 256, 256, 0, stream>>>(ew, c.G);
    // backward L1 (hin16 = UDX16 read by its qkv GEMM before rms_fwd overwrites it)
    block_backward(c, 1, c.UDX, c.UDX16, c.Q16, c.AO16, c.MB, c.LB, false);
    k_h0<<<NTOK, 256, 0, stream>>>(c.P, E, inputs, c.X1, c.X116);
    // backward L0: attention fwd skipped (checkpointed)
    block_backward(c, 0, c.X1, c.X116, c.Q016, c.AO016, c.MB0, c.LB0, true);
    k_logits_update<<<NTOK, 64, 0, stream>>>(c.G, E, c.P, alpha, logits);
  }
}

// Round 10
// 2635.452 us; speedup vs baseline: 33.2699x; 1.0250x over previous
//
#include <hip/hip_runtime.h>
#include <math.h>

#define B_ 8
#define S_ 900
#define V_ 11
#define H_ 512
#define NH_ 8
#define HD_ 64
#define INNER_ 1536
#define STEPS_ 2
#define NTOK (B_*S_)
#define EPS_ 1e-5f
#define THETA_ 10000.0f
#define ESCALE_ 22.627416997969522f
#define SCALE_ 0.125f
#define PT_ 68   // attention LDS pitch (ushorts)

typedef __attribute__((ext_vector_type(8))) short bh8;
typedef __attribute__((ext_vector_type(4))) float f32x4;
typedef __attribute__((ext_vector_type(4))) unsigned short us4;

union bfu { bh8 v; unsigned short s[8]; us4 q[2]; };

__device__ inline unsigned short f2bf(float x) {
  unsigned u = __builtin_bit_cast(unsigned, x);
  return (unsigned short)((u + 0x7FFFu + ((u >> 16) & 1u)) >> 16);
}
__device__ inline float b2f(unsigned short s) {
  return __builtin_bit_cast(float, (unsigned)s << 16);
}

// async global->LDS, 16B per lane; LDS dest = wave-uniform base + lane*16
__device__ inline void gld16(const unsigned short* g, unsigned short* l) {
  __builtin_amdgcn_global_load_lds(
      (const __attribute__((address_space(1))) void*)(g),
      (__attribute__((address_space(3))) void*)(l), 16, 0, 0);
}

__device__ inline bh8 lds16(const unsigned short* p) {
  bfu u;
  u.q[0] = *(const us4*)p;
  u.q[1] = *(const us4*)(p + 4);
  return u.v;
}
__device__ inline void sts16(unsigned short* p, bfu u) {
  *(us4*)p = u.q[0];
  *(us4*)(p + 4) = u.q[1];
}

__device__ inline float wave_sum64(float x) {
#pragma unroll
  for (int off = 32; off > 0; off >>= 1) x += __shfl_xor(x, off, 64);
  return x;
}

__device__ inline float quad_sum(float x) {
  x += __shfl_xor(x, 1, 64);
  x += __shfl_xor(x, 2, 64);
  return x;
}

// ---------------- small kernels ----------------

__global__ void k_zero(float* p, int n) {
  int i = blockIdx.x * blockDim.x + threadIdx.x;
  if (i < n) p[i] = 0.f;
}

__global__ void k_rope_tables(float* cs, float* sn) {
  int idx = blockIdx.x * blockDim.x + threadIdx.x;
  if (idx >= S_ * 32) return;
  int s = idx >> 5, i = idx & 31;
  float freq = powf(THETA_, -(float)i / 32.0f);
  float ang = (float)s * freq;
  cs[idx] = cosf(ang);
  sn[idx] = sinf(ang);
}

__global__ void k_softmax_logits(const float* __restrict__ logits, float* __restrict__ P) {
  int t = blockIdx.x * blockDim.x + threadIdx.x;
  if (t >= NTOK) return;
  float x[V_];
  float m = -1e30f;
#pragma unroll
  for (int v = 0; v < V_; ++v) { x[v] = logits[t * V_ + v]; m = fmaxf(m, x[v]); }
  float ssum = 0.f;
#pragma unroll
  for (int v = 0; v < V_; ++v) { x[v] = expf(x[v] - m); ssum += x[v]; }
  float inv = 1.f / ssum;
#pragma unroll
  for (int v = 0; v < V_; ++v) P[t * V_ + v] = x[v] * inv;
}

// h0 -> fp32 + bf16
__global__ void k_h0(const float* __restrict__ P, const float* __restrict__ E,
                     const int* __restrict__ inp, float* __restrict__ h0,
                     unsigned short* __restrict__ h016) {
  int t = blockIdx.x;
  int tid = threadIdx.x;
  __shared__ float p[V_];
  __shared__ int iw;
  if (tid < V_) p[tid] = P[t * V_ + tid];
  if (tid == 0) iw = inp[t];
  __syncthreads();
  for (int h = tid; h < H_; h += blockDim.x) {
    float acc = E[iw * H_ + h];
#pragma unroll
    for (int v = 0; v < V_; ++v) acc += p[v] * E[v * H_ + h];
    float val = ESCALE_ * acc;
    h0[(size_t)t * H_ + h] = val;
    h016[(size_t)t * H_ + h] = f2bf(val);
  }
}

__global__ void k_gfill(const float* __restrict__ ew, float* __restrict__ G) {
  int idx = blockIdx.x * blockDim.x + threadIdx.x;
  if (idx < NTOK * H_) G[idx] = ew[idx & (H_ - 1)];
}

// fp32 -> bf16 cast, 8 elems/thread (for stored-orientation weights)
__global__ void k_cast8(const float* __restrict__ X, unsigned short* __restrict__ Y, int n8) {
  int i = blockIdx.x * blockDim.x + threadIdx.x;
  if (i >= n8) return;
  const float4* p = (const float4*)(X + (size_t)i * 8);
  float4 a = p[0], b = p[1];
  bfu o;
  o.s[0] = f2bf(a.x); o.s[1] = f2bf(a.y); o.s[2] = f2bf(a.z); o.s[3] = f2bf(a.w);
  o.s[4] = f2bf(b.x); o.s[5] = f2bf(b.y); o.s[6] = f2bf(b.z); o.s[7] = f2bf(b.w);
  *(bh8*)(Y + (size_t)i * 8) = o.v;
}

// ---------------- weight transpose-convert: W[K][N] fp32 -> WT[N][K] bf16 ----------------

__global__ void k_wt(const float* __restrict__ W, unsigned short* __restrict__ WT, int K, int N) {
  __shared__ float t[32][33];
  int k0 = blockIdx.y * 32, n0 = blockIdx.x * 32;
  int tx = threadIdx.x, ty = threadIdx.y;
#pragma unroll
  for (int i = 0; i < 4; ++i)
    t[ty + 8 * i][tx] = W[(size_t)(k0 + ty + 8 * i) * N + n0 + tx];
  __syncthreads();
#pragma unroll
  for (int i = 0; i < 4; ++i)
    WT[(size_t)(n0 + ty + 8 * i) * K + k0 + tx] = f2bf(t[tx][ty + 8 * i]);
}

// ---------------- MFMA GEMM: C[M,N] = A[M,K] @ B^T (A,B bf16; B stored [N][K]) ----------------
// Tile 64x128, BK=32, 4 waves (2x2), wave-tile 32x64.
// Staging via global_load_lds into linear [rows][32] LDS. SILU_A stages manually.
// ROPE: fused forward rotary on output (wave's 64-col span = one head slot; partner col
//       +-32 = acc[fr][fc^2] in-register). Applies to slots 0..15 (Q,K), identity on V.
// SILUBWD: epilogue reads (gate,up) bf16 pair from GU at output coords, writes dGU in place.

template <int SILU_A, int ADD, int CBF, int ROPE, int SILUBWD>
__global__ __launch_bounds__(256) void k_gemm(const unsigned short* __restrict__ A16,
                                              const unsigned short* __restrict__ Bt,
                                              const float* __restrict__ Dm,
                                              float* __restrict__ Cf,
                                              unsigned short* __restrict__ C16,
                                              unsigned short* __restrict__ GU,
                                              const float* __restrict__ Cs,
                                              const float* __restrict__ Sn,
                                              int M, int N, int K, int lda) {
  __shared__ unsigned short As[64][32];
  __shared__ unsigned short Bs[128][32];
  int tid = threadIdx.x;
  int m0 = blockIdx.y * 64, n0 = blockIdx.x * 128;
  int wid = tid >> 6, lane = tid & 63;
  int wr = (wid >> 1) * 32, wc = (wid & 1) * 64;
  int lr = lane & 15, lg = lane >> 4;
  int srow = lane >> 2, sck = (lane & 3) * 8;
  f32x4 acc[2][4] = {};
  for (int k0 = 0; k0 < K; k0 += 32) {
    __syncthreads();
    if (SILU_A) {
      int row = tid >> 2, ck = (tid & 3) * 8;
      int gr = m0 + row; gr = gr < M ? gr : M - 1;
      const unsigned short* src = &A16[(size_t)gr * lda + k0 + ck];
      bfu pa;
#pragma unroll
      for (int j = 0; j < 8; ++j) {
        float g = b2f(src[j]), u = b2f(src[INNER_ + j]);
        pa.s[j] = f2bf((g / (1.f + __expf(-g))) * u);
      }
      *(bh8*)&As[row][ck] = pa.v;
    } else {
      int row = wid * 16 + srow;
      int gr = m0 + row; gr = gr < M ? gr : M - 1;
      gld16(&A16[(size_t)gr * lda + k0 + sck], &As[wid * 16][0]);
    }
#pragma unroll
    for (int i = 0; i < 2; ++i) {
      int bb = wid * 2 + i;
      gld16(&Bt[(size_t)(n0 + bb * 16 + srow) * K + k0 + sck], &Bs[bb * 16][0]);
    }
    __syncthreads();
    bh8 av[2], bv[4];
#pragma unroll
    for (int fr = 0; fr < 2; ++fr) av[fr] = *(const bh8*)&As[wr + fr * 16 + lr][lg * 8];
#pragma unroll
    for (int fc = 0; fc < 4; ++fc) bv[fc] = *(const bh8*)&Bs[wc + fc * 16 + lr][lg * 8];
#pragma unroll
    for (int fr = 0; fr < 2; ++fr)
#pragma unroll
      for (int fc = 0; fc < 4; ++fc)
        acc[fr][fc] = __builtin_amdgcn_mfma_f32_16x16x32_bf16(av[fr], bv[fc], acc[fr][fc], 0, 0, 0);
  }
  bool rope_on = ROPE && (((n0 + wc) >> 6) < 16);   // wave-uniform: slots 0..15 are Q,K
#pragma unroll
  for (int fr = 0; fr < 2; ++fr) {
    int r0 = m0 + wr + fr * 16 + lg * 4;
#pragma unroll
    for (int i = 0; i < 4; ++i) {
      int gr = r0 + i;
      if (gr >= M) continue;
      float c0 = 1.f, s0 = 0.f, c1 = 1.f, s1 = 0.f;
      if (ROPE) {
        if (rope_on) {
          int s = gr % S_;
          c0 = Cs[s * 32 + lr];      s0 = Sn[s * 32 + lr];       // cols with (fc&1)==0: ii=lr
          c1 = Cs[s * 32 + 16 + lr]; s1 = Sn[s * 32 + 16 + lr];  // (fc&1)==1: ii=16+lr
        }
      }
#pragma unroll
      for (int fc = 0; fc < 4; ++fc) {
        int gc = n0 + wc + fc * 16 + lr;
        float out = acc[fr][fc][i];
        if (ROPE) {
          float part = acc[fr][fc ^ 2][i];
          float cc = (fc & 1) ? c1 : c0;
          float ss = (fc & 1) ? s1 : s0;
          out = (fc < 2) ? (out * cc - part * ss) : (out * cc + part * ss);
        }
        if (ADD) out += Dm[(size_t)gr * N + gc];
        if (SILUBWD) {
          size_t gb = (size_t)gr * (size_t)(2 * INNER_) + gc;
          float g = b2f(GU[gb]), u = b2f(GU[gb + INNER_]);
          float sig = 1.f / (1.f + __expf(-g));
          GU[gb] = f2bf(out * u * sig * (1.f + g * (1.f - sig)));
          GU[gb + INNER_] = f2bf(out * g * sig);
        } else if (CBF) {
          C16[(size_t)gr * N + gc] = f2bf(out);
        } else {
          Cf[(size_t)gr * N + gc] = out;
        }
      }
    }
  }
}

// ---------------- MFMA flash attention (bf16 QKV, bf16 O) ----------------
// QKV16 layout [t][24][64] ushorts: Q at slot h (roped), K at 8+h (roped), V at 16+h.

__global__ __launch_bounds__(256) void k_attn_fwd3(const unsigned short* __restrict__ QKV,
                                                   unsigned short* __restrict__ AO,
                                                   float* __restrict__ MB,
                                                   float* __restrict__ LB) {
  __shared__ unsigned short Ks[64][PT_];
  __shared__ unsigned short VT[64][PT_];
  __shared__ unsigned short Ps[4][16][PT_];
  int tid = threadIdx.x;
  int h = blockIdx.y, b = blockIdx.z;
  int w = tid >> 6, lane = tid & 63;
  int lr = lane & 15, lg = lane >> 4;
  int q0 = blockIdx.x * 64 + w * 16;

  bh8 qf[2];
  {
    int qr = q0 + lr; if (qr >= S_) qr = S_ - 1;
    const unsigned short* qp = &QKV[((size_t)(b * S_ + qr) * 24 + h) * 64 + lg * 8];
    qf[0] = *(const bh8*)qp;
    qf[1] = *(const bh8*)(qp + 32);
  }
  f32x4 accO[4] = {};
  float m[4], lsum[4];
#pragma unroll
  for (int i = 0; i < 4; ++i) { m[i] = -1e30f; lsum[i] = 0.f; }

  for (int kt = 0; kt < S_; kt += 64) {
    __syncthreads();
    {
      int r = tid >> 2, c0 = (tid & 3) * 16;
      int src = kt + r;
      size_t ts = (size_t)b * S_ + (src < S_ ? src : S_ - 1);
      const unsigned short* gp = &QKV[(ts * 24 + 8 + h) * 64 + c0];
      bfu p0, p1;
      p0.v = *(const bh8*)gp;
      p1.v = *(const bh8*)(gp + 8);
      sts16(&Ks[r][c0], p0);
      sts16(&Ks[r][c0 + 8], p1);
    }
    {
      int d0 = (tid & 15) * 4, k0r = (tid >> 4) * 4;
      us4 rv[4];
#pragma unroll
      for (int j = 0; j < 4; ++j) {
        int src = kt + k0r + j;
        size_t ts = (size_t)b * S_ + (src < S_ ? src : S_ - 1);
        rv[j] = *(const us4*)&QKV[(ts * 24 + 16 + h) * 64 + d0];
      }
#pragma unroll
      for (int dd = 0; dd < 4; ++dd) {
        us4 pk = {rv[0][dd], rv[1][dd], rv[2][dd], rv[3][dd]};
        *(us4*)&VT[d0 + dd][k0r] = pk;
      }
    }
    __syncthreads();
    f32x4 accS[4] = {};
#pragma unroll
    for (int ks = 0; ks < 2; ++ks)
#pragma unroll
      for (int fk = 0; fk < 4; ++fk)
        accS[fk] = __builtin_amdgcn_mfma_f32_16x16x32_bf16(qf[ks], lds16(&Ks[fk * 16 + lr][ks * 32 + lg * 8]), accS[fk], 0, 0, 0);
    float sc[4][4], pmax[4];
#pragma unroll
    for (int i = 0; i < 4; ++i) pmax[i] = -1e30f;
#pragma unroll
    for (int fk = 0; fk < 4; ++fk)
#pragma unroll
      for (int i = 0; i < 4; ++i) {
        float s = accS[fk][i] * SCALE_;
        if (kt + fk * 16 + lr >= S_) s = -1e30f;
        sc[fk][i] = s;
        pmax[i] = fmaxf(pmax[i], s);
      }
#pragma unroll
    for (int i = 0; i < 4; ++i) {
      float v = pmax[i];
      v = fmaxf(v, __shfl_xor(v, 1, 64));
      v = fmaxf(v, __shfl_xor(v, 2, 64));
      v = fmaxf(v, __shfl_xor(v, 4, 64));
      v = fmaxf(v, __shfl_xor(v, 8, 64));
      pmax[i] = v;
    }
    float psum[4];
#pragma unroll
    for (int i = 0; i < 4; ++i) {
      float mn = fmaxf(m[i], pmax[i]);
      float eo = __expf(m[i] - mn);
      m[i] = mn;
      lsum[i] *= eo;
#pragma unroll
      for (int fd = 0; fd < 4; ++fd) accO[fd][i] *= eo;
      psum[i] = 0.f;
    }
#pragma unroll
    for (int fk = 0; fk < 4; ++fk)
#pragma unroll
      for (int i = 0; i < 4; ++i) {
        float p = __expf(sc[fk][i] - m[i]);
        sc[fk][i] = p;
        psum[i] += p;
      }
#pragma unroll
    for (int i = 0; i < 4; ++i) {
      float v = psum[i];
      v += __shfl_xor(v, 1, 64);
      v += __shfl_xor(v, 2, 64);
      v += __shfl_xor(v, 4, 64);
      v += __shfl_xor(v, 8, 64);
      lsum[i] += v;
    }
#pragma unroll
    for (int fk = 0; fk < 4; ++fk)
#pragma unroll
      for (int i = 0; i < 4; ++i)
        Ps[w][lg * 4 + i][fk * 16 + lr] = f2bf(sc[fk][i]);
#pragma unroll
    for (int ks = 0; ks < 2; ++ks) {
      bh8 ap = lds16(&Ps[w][lr][ks * 32 + lg * 8]);
#pragma unroll
      for (int fd = 0; fd < 4; ++fd)
        accO[fd] = __builtin_amdgcn_mfma_f32_16x16x32_bf16(ap, lds16(&VT[fd * 16 + lr][ks * 32 + lg * 8]), accO[fd], 0, 0, 0);
    }
  }
#pragma unroll
  for (int i = 0; i < 4; ++i) {
    int q = q0 + lg * 4 + i;
    if (q < S_) {
      float linv = 1.f / lsum[i];
      size_t obase = (size_t)(b * S_ + q) * H_ + h * 64;
#pragma unroll
      for (int fd = 0; fd < 4; ++fd) AO[obase + fd * 16 + lr] = f2bf(accO[fd][i] * linv);
      if (lr == 0) {
        MB[((size_t)b * NH_ + h) * S_ + q] = m[i];
        LB[((size_t)b * NH_ + h) * S_ + q] = linv;
      }
    }
  }
}

// delta[b,h,q] = dot(dO_row, O_row), both bf16
__global__ __launch_bounds__(256) void k_delta(const unsigned short* __restrict__ O,
                                               const unsigned short* __restrict__ dO,
                                               float* __restrict__ DB) {
  int tid = threadIdx.x;
  int h = blockIdx.y, b = blockIdx.z;
  int r = blockIdx.x * 64 + (tid >> 2), part = tid & 3;
  if (r >= S_) return;
  size_t base = (size_t)(b * S_ + r) * H_ + h * 64 + part * 16;
  bfu o0, o1, d0, d1;
  o0.v = *(const bh8*)&O[base];  o1.v = *(const bh8*)&O[base + 8];
  d0.v = *(const bh8*)&dO[base]; d1.v = *(const bh8*)&dO[base + 8];
  float s = 0.f;
#pragma unroll
  for (int j = 0; j < 8; ++j)
    s += b2f(o0.s[j]) * b2f(d0.s[j]) + b2f(o1.s[j]) * b2f(d1.s[j]);
  s = quad_sum(s);
  if (part == 0) DB[((size_t)b * NH_ + h) * S_ + r] = s;
}

// dQ pass; fused inverse-RoPE on output (q row index == sequence position)
__global__ __launch_bounds__(256) void k_attn_bwd_dq3(const unsigned short* __restrict__ QKV,
                                                      const unsigned short* __restrict__ dO,
                                                      const float* __restrict__ MB,
                                                      const float* __restrict__ LB,
                                                      const float* __restrict__ DB,
                                                      const float* __restrict__ Cs,
                                                      const float* __restrict__ Sn,
                                                      unsigned short* __restrict__ dQKV) {
  __shared__ unsigned short Ks[64][PT_];
  __shared__ unsigned short Vs[64][PT_];
  __shared__ unsigned short KT[64][PT_];
  __shared__ unsigned short Ps[4][16][PT_];
  int tid = threadIdx.x;
  int h = blockIdx.y, b = blockIdx.z;
  int w = tid >> 6, lane = tid & 63;
  int lr = lane & 15, lg = lane >> 4;
  int q0 = blockIdx.x * 64 + w * 16;
  size_t sbase = ((size_t)b * NH_ + h) * S_;

  bh8 qf[2], dof[2];
  {
    int qr = q0 + lr; if (qr >= S_) qr = S_ - 1;
    const unsigned short* qp = &QKV[((size_t)(b * S_ + qr) * 24 + h) * 64 + lg * 8];
    const unsigned short* dp = &dO[(size_t)(b * S_ + qr) * H_ + h * 64 + lg * 8];
    qf[0] = *(const bh8*)qp;  qf[1] = *(const bh8*)(qp + 32);
    dof[0] = *(const bh8*)dp; dof[1] = *(const bh8*)(dp + 32);
  }
  float mrow[4], lrow[4], drow[4];
#pragma unroll
  for (int i = 0; i < 4; ++i) {
    int q = q0 + lg * 4 + i; if (q >= S_) q = S_ - 1;
    mrow[i] = MB[sbase + q];
    lrow[i] = LB[sbase + q];
    drow[i] = DB[sbase + q];
  }
  f32x4 accQ[4] = {};

  for (int kt = 0; kt < S_; kt += 64) {
    __syncthreads();
    {
      int r = tid >> 2, c0 = (tid & 3) * 16;
      int src = kt + r;
      bool vld = src < S_;
      size_t ts = (size_t)b * S_ + (vld ? src : S_ - 1);
      const unsigned short* kp = &QKV[(ts * 24 + 8 + h) * 64 + c0];
      bfu p0{}, p1{}, p2{}, p3{};
      if (vld) {
        p0.v = *(const bh8*)kp;
        p1.v = *(const bh8*)(kp + 8);
        p2.v = *(const bh8*)(kp + 512);
        p3.v = *(const bh8*)(kp + 520);
      }
      sts16(&Ks[r][c0], p0); sts16(&Ks[r][c0 + 8], p1);
      sts16(&Vs[r][c0], p2); sts16(&Vs[r][c0 + 8], p3);
    }
    {
      int d0 = (tid & 15) * 4, k0r = (tid >> 4) * 4;
      us4 rv[4];
#pragma unroll
      for (int j = 0; j < 4; ++j) {
        int src = kt + k0r + j;
        bool vld = src < S_;
        size_t ts = (size_t)b * S_ + (vld ? src : S_ - 1);
        us4 t = *(const us4*)&QKV[(ts * 24 + 8 + h) * 64 + d0];
        if (!vld) t = us4{0, 0, 0, 0};
        rv[j] = t;
      }
#pragma unroll
      for (int dd = 0; dd < 4; ++dd) {
        us4 pk = {rv[0][dd], rv[1][dd], rv[2][dd], rv[3][dd]};
        *(us4*)&KT[d0 + dd][k0r] = pk;
      }
    }
    __syncthreads();
    f32x4 aS[4] = {}, aD[4] = {};
#pragma unroll
    for (int ks = 0; ks < 2; ++ks)
#pragma unroll
      for (int fk = 0; fk < 4; ++fk) {
        aS[fk] = __builtin_amdgcn_mfma_f32_16x16x32_bf16(qf[ks], lds16(&Ks[fk * 16 + lr][ks * 32 + lg * 8]), aS[fk], 0, 0, 0);
        aD[fk] = __builtin_amdgcn_mfma_f32_16x16x32_bf16(dof[ks], lds16(&Vs[fk * 16 + lr][ks * 32 + lg * 8]), aD[fk], 0, 0, 0);
      }
#pragma unroll
    for (int fk = 0; fk < 4; ++fk)
#pragma unroll
      for (int i = 0; i < 4; ++i) {
        float p = __expf(aS[fk][i] * SCALE_ - mrow[i]) * lrow[i];
        float ds = p * (aD[fk][i] - drow[i]);
        Ps[w][lg * 4 + i][fk * 16 + lr] = f2bf(ds);
      }
#pragma unroll
    for (int ks = 0; ks < 2; ++ks) {
      bh8 ap = lds16(&Ps[w][lr][ks * 32 + lg * 8]);
#pragma unroll
      for (int fd = 0; fd < 4; ++fd)
        accQ[fd] = __builtin_amdgcn_mfma_f32_16x16x32_bf16(ap, lds16(&KT[fd * 16 + lr][ks * 32 + lg * 8]), accQ[fd], 0, 0, 0);
    }
  }
#pragma unroll
  for (int i = 0; i < 4; ++i) {
    int q = q0 + lg * 4 + i;
    if (q < S_) {
      size_t obase = ((size_t)(b * S_ + q) * 24 + h) * 64;
      float c0 = Cs[q * 32 + lr], s0 = Sn[q * 32 + lr];
      float c1 = Cs[q * 32 + 16 + lr], s1 = Sn[q * 32 + 16 + lr];
#pragma unroll
      for (int fd = 0; fd < 4; ++fd) {
        float x = SCALE_ * accQ[fd][i];
        float p = SCALE_ * accQ[fd ^ 2][i];
        float cc = (fd & 1) ? c1 : c0;
        float ss = (fd & 1) ? s1 : s0;
        float out = (fd < 2) ? (x * cc + p * ss) : (x * cc - p * ss);  // inverse rotation
        dQKV[obase + fd * 16 + lr] = f2bf(out);
      }
    }
  }
}

// dK + dV pass; fused inverse-RoPE on dK (k row index == sequence position), dV plain
__global__ __launch_bounds__(256) void k_attn_bwd_kv3(const unsigned short* __restrict__ QKV,
                                                      const unsigned short* __restrict__ dO,
                                                      const float* __restrict__ MB,
                                                      const float* __restrict__ LB,
                                                      const float* __restrict__ DB,
                                                      const float* __restrict__ Cs,
                                                      const float* __restrict__ Sn,
                                                      unsigned short* __restrict__ dQKV) {
  __shared__ unsigned short Qs[64][PT_];
  __shared__ unsigned short dOs[64][PT_];
  __shared__ unsigned short QT[64][PT_];
  __shared__ unsigned short dOT[64][PT_];
  __shared__ unsigned short Ps[4][16][PT_];
  __shared__ float sM[64], sL[64], sD[64];
  int tid = threadIdx.x;
  int h = blockIdx.y, b = blockIdx.z;
  int w = tid >> 6, lane = tid & 63;
  int lr = lane & 15, lg = lane >> 4;
  int k0w = blockIdx.x * 64 + w * 16;
  size_t sbase = ((size_t)b * NH_ + h) * S_;

  bh8 kf[2], vf[2];
  {
    int kr = k0w + lr; if (kr >= S_) kr = S_ - 1;
    const unsigned short* kp = &QKV[((size_t)(b * S_ + kr) * 24 + 8 + h) * 64 + lg * 8];
    kf[0] = *(const bh8*)kp;        kf[1] = *(const bh8*)(kp + 32);
    vf[0] = *(const bh8*)(kp + 512); vf[1] = *(const bh8*)(kp + 544);
  }
  f32x4 accK[4] = {}, accV[4] = {};

  for (int qt = 0; qt < S_; qt += 64) {
    __syncthreads();
    {
      int r = tid >> 2, c0 = (tid & 3) * 16;
      int src = qt + r;
      bool vld = src < S_;
      size_t ts = (size_t)b * S_ + (vld ? src : S_ - 1);
      const unsigned short* qp = &QKV[(ts * 24 + h) * 64 + c0];
      const unsigned short* dp = &dO[ts * H_ + h * 64 + c0];
      bfu p0, p1, p2{}, p3{};
      p0.v = *(const bh8*)qp;
      p1.v = *(const bh8*)(qp + 8);
      if (vld) {
        p2.v = *(const bh8*)dp;
        p3.v = *(const bh8*)(dp + 8);
      }
      sts16(&Qs[r][c0], p0);  sts16(&Qs[r][c0 + 8], p1);
      sts16(&dOs[r][c0], p2); sts16(&dOs[r][c0 + 8], p3);
    }
    {
      int d0 = (tid & 15) * 4, q0r = (tid >> 4) * 4;
      us4 rq[4], rd[4];
#pragma unroll
      for (int j = 0; j < 4; ++j) {
        int src = qt + q0r + j;
        bool vld = src < S_;
        size_t ts = (size_t)b * S_ + (vld ? src : S_ - 1);
        rq[j] = *(const us4*)&QKV[(ts * 24 + h) * 64 + d0];
        us4 td = *(const us4*)&dO[ts * H_ + h * 64 + d0];
        if (!vld) td = us4{0, 0, 0, 0};
        rd[j] = td;
      }
#pragma unroll
      for (int dd = 0; dd < 4; ++dd) {
        us4 pq = {rq[0][dd], rq[1][dd], rq[2][dd], rq[3][dd]};
        us4 pd = {rd[0][dd], rd[1][dd], rd[2][dd], rd[3][dd]};
        *(us4*)&QT[d0 + dd][q0r] = pq;
        *(us4*)&dOT[d0 + dd][q0r] = pd;
      }
    }
    if (tid < 64) {
      int src = qt + tid;
      bool vld = src < S_;
      int sc = vld ? src : S_ - 1;
      sM[tid] = MB[sbase + sc];
      sL[tid] = LB[sbase + sc];
      sD[tid] = vld ? DB[sbase + sc] : 0.f;
    }
    __syncthreads();
    f32x4 aS[4] = {}, aD[4] = {};
#pragma unroll
    for (int ks = 0; ks < 2; ++ks)
#pragma unroll
      for (int fq = 0; fq < 4; ++fq) {
        aS[fq] = __builtin_amdgcn_mfma_f32_16x16x32_bf16(kf[ks], lds16(&Qs[fq * 16 + lr][ks * 32 + lg * 8]), aS[fq], 0, 0, 0);
        aD[fq] = __builtin_amdgcn_mfma_f32_16x16x32_bf16(vf[ks], lds16(&dOs[fq * 16 + lr][ks * 32 + lg * 8]), aD[fq], 0, 0, 0);
      }
    float pv[4][4];
#pragma unroll
    for (int fq = 0; fq < 4; ++fq) {
      float mq = sM[fq * 16 + lr], lq = sL[fq * 16 + lr];
#pragma unroll
      for (int i = 0; i < 4; ++i) {
        float p = __expf(aS[fq][i] * SCALE_ - mq) * lq;
        pv[fq][i] = p;
        Ps[w][lg * 4 + i][fq * 16 + lr] = f2bf(p);
      }
    }
#pragma unroll
    for (int qs = 0; qs < 2; ++qs) {
      bh8 ap = lds16(&Ps[w][lr][qs * 32 + lg * 8]);
#pragma unroll
      for (int fd = 0; fd < 4; ++fd)
        accV[fd] = __builtin_amdgcn_mfma_f32_16x16x32_bf16(ap, lds16(&dOT[fd * 16 + lr][qs * 32 + lg * 8]), accV[fd], 0, 0, 0);
    }
#pragma unroll
    for (int fq = 0; fq < 4; ++fq) {
      float dq = sD[fq * 16 + lr];
#pragma unroll
      for (int i = 0; i < 4; ++i)
        Ps[w][lg * 4 + i][fq * 16 + lr] = f2bf(pv[fq][i] * (aD[fq][i] - dq));
    }
#pragma unroll
    for (int qs = 0; qs < 2; ++qs) {
      bh8 ap = lds16(&Ps[w][lr][qs * 32 + lg * 8]);
#pragma unroll
      for (int fd = 0; fd < 4; ++fd)
        accK[fd] = __builtin_amdgcn_mfma_f32_16x16x32_bf16(ap, lds16(&QT[fd * 16 + lr][qs * 32 + lg * 8]), accK[fd], 0, 0, 0);
    }
  }
#pragma unroll
  for (int i = 0; i < 4; ++i) {
    int k = k0w + lg * 4 + i;
    if (k < S_) {
      size_t obase = ((size_t)(b * S_ + k) * 24 + 8 + h) * 64;
      float c0 = Cs[k * 32 + lr], s0 = Sn[k * 32 + lr];
      float c1 = Cs[k * 32 + 16 + lr], s1 = Sn[k * 32 + 16 + lr];
#pragma unroll
      for (int fd = 0; fd < 4; ++fd) {
        float x = SCALE_ * accK[fd][i];
        float p = SCALE_ * accK[fd ^ 2][i];
        float cc = (fd & 1) ? c1 : c0;
        float ss = (fd & 1) ? s1 : s0;
        float out = (fd < 2) ? (x * cc + p * ss) : (x * cc - p * ss);  // inverse rotation
        dQKV[obase + fd * 16 + lr] = f2bf(out);
        dQKV[obase + 512 + fd * 16 + lr] = f2bf(accV[fd][i]);
      }
    }
  }
}

// ---------------- RMS norm fwd/bwd (dual fp32+bf16 outputs) ----------------

__global__ __launch_bounds__(256) void k_rms_fwd(const float* __restrict__ X, float* __restrict__ Y,
                                                 unsigned short* __restrict__ Y16) {
  int t = blockIdx.x, tid = threadIdx.x;
  float x0 = X[(size_t)t * H_ + tid], x1 = X[(size_t)t * H_ + tid + 256];
  __shared__ float red[256];
  red[tid] = x0 * x0 + x1 * x1;
  __syncthreads();
  for (int s = 128; s > 0; s >>= 1) {
    if (tid < s) red[tid] += red[tid + s];
    __syncthreads();
  }
  float r = rsqrtf(red[0] / H_ + EPS_);
  float y0 = x0 * r, y1 = x1 * r;
  Y[(size_t)t * H_ + tid] = y0;
  Y[(size_t)t * H_ + tid + 256] = y1;
  Y16[(size_t)t * H_ + tid] = f2bf(y0);
  Y16[(size_t)t * H_ + tid + 256] = f2bf(y1);
}

__global__ __launch_bounds__(256) void k_rms_bwd(const float* __restrict__ X,
                                                 const float* __restrict__ GY,
                                                 float* __restrict__ GX,
                                                 unsigned short* __restrict__ GX16) {
  int t = blockIdx.x, tid = threadIdx.x;
  float x0 = X[(size_t)t * H_ + tid], x1 = X[(size_t)t * H_ + tid + 256];
  float g0 = GY[(size_t)t * H_ + tid], g1 = GY[(size_t)t * H_ + tid + 256];
  __shared__ float r1[256], r2[256];
  r1[tid] = x0 * x0 + x1 * x1;
  r2[tid] = x0 * g0 + x1 * g1;
  __syncthreads();
  for (int s = 128; s > 0; s >>= 1) {
    if (tid < s) { r1[tid] += r1[tid + s]; r2[tid] += r2[tid + s]; }
    __syncthreads();
  }
  float r = rsqrtf(r1[0] / H_ + EPS_);
  float coef = r * r * r * r2[0] / (float)H_;
  float o0 = r * g0 - coef * x0, o1 = r * g1 - coef * x1;
  GX[(size_t)t * H_ + tid] = o0;
  GX[(size_t)t * H_ + tid + 256] = o1;
  GX16[(size_t)t * H_ + tid] = f2bf(o0);
  GX16[(size_t)t * H_ + tid + 256] = f2bf(o1);
}

// ---------------- logits update ----------------

__global__ __launch_bounds__(64) void k_logits_update(const float* __restrict__ G,
                                                      const float* __restrict__ E,
                                                      const float* __restrict__ P,
                                                      const float* __restrict__ alpha,
                                                      float* __restrict__ logits) {
  int t = blockIdx.x, lane = threadIdx.x;
  float dp[V_];
#pragma unroll
  for (int v = 0; v < V_; ++v) dp[v] = 0.f;
  for (int hh = lane; hh < H_; hh += 64) {
    float gh = G[(size_t)t * H_ + hh];
#pragma unroll
    for (int v = 0; v < V_; ++v) dp[v] += gh * E[v * H_ + hh];
  }
#pragma unroll
  for (int v = 0; v < V_; ++v) dp[v] = wave_sum64(dp[v]) * ESCALE_;
  float dot = 0.f;
  float pv[V_];
#pragma unroll
  for (int v = 0; v < V_; ++v) {
    pv[v] = P[t * V_ + v];
    dot += pv[v] * dp[v];
  }
  float a = fmaxf(alpha[0], 1e-4f);
  if (lane < V_) logits[t * V_ + lane] -= a * pv[lane] * (dp[lane] - dot);
}

// ---------------- host-side orchestration ----------------
// RoPE fused into qkv-GEMM epilogue (fwd) and dq3/kv3 epilogues (bwd).
// SiLU-bwd fused into dact-GEMM epilogue (writes dGU into GU16 in place).

struct Ctx {
  unsigned short *Q16, *Q016, *dQ16, *GU16, *DO16, *AO16, *AO016, *X116, *UDX16;
  float *X1, *X2, *G, *UDX, *P, *MB, *LB, *DB, *MB0, *LB0, *CS, *SN;
  const unsigned short *WTqkv[2], *WTo[2], *WTgu[2], *WTd[2];
  const unsigned short *WSqkv[2], *WSo[2], *WSgu[2], *WSd[2];
  hipStream_t st;
};

static inline dim3 ggrid(int M, int N) { return dim3(N / 128, (M + 63) / 64); }

static void block_forward(Ctx& c, int l, const float* hin, const unsigned short* hin16,
                          float* hout, unsigned short* qb, unsigned short* ao,
                          float* mb, float* lb, bool skip_attn) {
  if (!skip_attn) {
    // qkv GEMM with fused RoPE (slots 0..15), bf16 out
    k_gemm<0, 0, 1, 1, 0><<<ggrid(NTOK, 3 * H_), 256, 0, c.st>>>(
        hin16, c.WTqkv[l], nullptr, nullptr, qb, nullptr, c.CS, c.SN, NTOK, 3 * H_, H_, H_);
    k_attn_fwd3<<<dim3((S_ + 63) / 64, NH_, B_), 256, 0, c.st>>>(qb, ao, mb, lb);
  }
  k_gemm<0, 1, 0, 0, 0><<<ggrid(NTOK, H_), 256, 0, c.st>>>(
      ao, c.WTo[l], hin, c.X1, nullptr, nullptr, nullptr, nullptr, NTOK, H_, H_, H_);
  k_rms_fwd<<<NTOK, 256, 0, c.st>>>(c.X1, c.UDX, c.UDX16);
  k_gemm<0, 0, 1, 0, 0><<<ggrid(NTOK, 2 * INNER_), 256, 0, c.st>>>(
      c.UDX16, c.WTgu[l], nullptr, nullptr, c.GU16, nullptr, nullptr, nullptr, NTOK, 2 * INNER_, H_, H_);
  k_gemm<1, 1, 0, 0, 0><<<ggrid(NTOK, H_), 256, 0, c.st>>>(
      c.GU16, c.WTd[l], c.UDX, c.X2, nullptr, nullptr, nullptr, nullptr, NTOK, H_, INNER_, 2 * INNER_);
  if (hout) k_rms_fwd<<<NTOK, 256, 0, c.st>>>(c.X2, hout, c.UDX16);
}

static void block_backward(Ctx& c, int l, const float* hin, const unsigned short* hin16,
                           unsigned short* qb, unsigned short* ao, float* mb, float* lb,
                           bool skip_attn) {
  block_forward(c, l, hin, hin16, nullptr, qb, ao, mb, lb, skip_attn);
  k_rms_bwd<<<NTOK, 256, 0, c.st>>>(c.X2, c.G, c.UDX, c.UDX16);
  // dact GEMM with fused SiLU-bwd: writes dGU into GU16 in place
  k_gemm<0, 0, 0, 0, 1><<<ggrid(NTOK, INNER_), 256, 0, c.st>>>(
      c.UDX16, c.WSd[l], nullptr, nullptr, nullptr, c.GU16, nullptr, nullptr, NTOK, INNER_, H_, H_);
  k_gemm<0, 1, 0, 0, 0><<<ggrid(NTOK, H_), 256, 0, c.st>>>(
      c.GU16, c.WSgu[l], c.UDX, c.G, nullptr, nullptr, nullptr, nullptr, NTOK, H_, 2 * INNER_, 2 * INNER_);
  k_rms_bwd<<<NTOK, 256, 0, c.st>>>(c.X1, c.G, c.UDX, c.UDX16);
  k_gemm<0, 0, 1, 0, 0><<<ggrid(NTOK, H_), 256, 0, c.st>>>(
      c.UDX16, c.WSo[l], nullptr, nullptr, c.DO16, nullptr, nullptr, nullptr, NTOK, H_, H_, H_);
  dim3 agrid((S_ + 63) / 64, NH_, B_);
  k_delta<<<agrid, 256, 0, c.st>>>(ao, c.DO16, c.DB);
  k_attn_bwd_dq3<<<agrid, 256, 0, c.st>>>(qb, c.DO16, mb, lb, c.DB, c.CS, c.SN, c.dQ16);
  k_attn_bwd_kv3<<<agrid, 256, 0, c.st>>>(qb, c.DO16, mb, lb, c.DB, c.CS, c.SN, c.dQ16);
  k_gemm<0, 1, 0, 0, 0><<<ggrid(NTOK, H_), 256, 0, c.st>>>(
      c.dQ16, c.WSqkv[l], c.UDX, c.G, nullptr, nullptr, nullptr, nullptr, NTOK, H_, 3 * H_, 3 * H_);
}

extern "C" void kernel_launch(void* const* d_in, const int* in_sizes, int n_in,
                              void* d_out, int out_size, void* d_ws, size_t ws_size,
                              hipStream_t stream) {
  const int* inputs = (const int*)d_in[0];
  const float* E = (const float*)d_in[2];
  const float* ew = (const float*)d_in[3];
  const float* qkvw = (const float*)d_in[4];
  const float* ow = (const float*)d_in[5];
  const float* guw = (const float*)d_in[6];
  const float* dw = (const float*)d_in[7];
  const float* alpha = (const float*)d_in[8];
  float* logits = (float*)d_out;

  const size_t WT_FLOATS = 3407872;  // bf16 elems/2 per orientation, both layers
  const size_t NEED =
      3 * ((size_t)NTOK * 3 * H_ / 2) +  // Q16, Q016, dQ16 (bf16)
      ((size_t)NTOK * INNER_) +          // GU16 (bf16, 2*INNER wide)
      4 * ((size_t)NTOK * H_) +          // X1, X2, G, UDX (fp32)
      5 * ((size_t)NTOK * H_ / 2) +      // AO16, AO016, DO16, X116, UDX16
      ((size_t)NTOK * V_) +              // P
      5 * ((size_t)B_ * NH_ * S_) +      // stats
      2 * ((size_t)S_ * 32) +            // CS, SN
      2 * WT_FLOATS;                     // WT + WS
  if (ws_size < NEED * sizeof(float)) {
    k_zero<<<(NTOK * V_ + 255) / 256, 256, 0, stream>>>(logits, NTOK * V_);
    return;
  }

  float* f = (float*)d_ws;
  Ctx c;
  c.st = stream;
  c.Q16 = (unsigned short*)f;  f += (size_t)NTOK * 3 * H_ / 2;
  c.Q016 = (unsigned short*)f; f += (size_t)NTOK * 3 * H_ / 2;
  c.dQ16 = (unsigned short*)f; f += (size_t)NTOK * 3 * H_ / 2;
  c.GU16 = (unsigned short*)f; f += (size_t)NTOK * INNER_;
  c.X1 = f;   f += (size_t)NTOK * H_;
  c.X2 = f;   f += (size_t)NTOK * H_;
  c.G = f;    f += (size_t)NTOK * H_;
  c.UDX = f;  f += (size_t)NTOK * H_;
  c.AO16 = (unsigned short*)f;  f += (size_t)NTOK * H_ / 2;
  c.AO016 = (unsigned short*)f; f += (size_t)NTOK * H_ / 2;
  c.DO16 = (unsigned short*)f;  f += (size_t)NTOK * H_ / 2;
  c.X116 = (unsigned short*)f;  f += (size_t)NTOK * H_ / 2;
  c.UDX16 = (unsigned short*)f; f += (size_t)NTOK * H_ / 2;
  c.P = f;    f += (size_t)NTOK * V_;
  c.MB = f;   f += (size_t)B_ * NH_ * S_;
  c.LB = f;   f += (size_t)B_ * NH_ * S_;
  c.DB = f;   f += (size_t)B_ * NH_ * S_;
  c.MB0 = f;  f += (size_t)B_ * NH_ * S_;
  c.LB0 = f;  f += (size_t)B_ * NH_ * S_;
  c.CS = f;   f += (size_t)S_ * 32;
  c.SN = f;   f += (size_t)S_ * 32;
  unsigned short* wt = (unsigned short*)f;

  const size_t LQKV = (size_t)H_ * 3 * H_;
  const size_t LO = (size_t)H_ * H_;
  const size_t LGU = (size_t)H_ * 2 * INNER_;
  const size_t LD = (size_t)INNER_ * H_;

  // transposed bf16 weights (forward)
  for (int l = 0; l < 2; ++l) {
    c.WTqkv[l] = wt;
    k_wt<<<dim3(3 * H_ / 32, H_ / 32), dim3(32, 8), 0, stream>>>(qkvw + l * LQKV, wt, H_, 3 * H_);
    wt += LQKV;
    c.WTo[l] = wt;
    k_wt<<<dim3(H_ / 32, H_ / 32), dim3(32, 8), 0, stream>>>(ow + l * LO, wt, H_, H_);
    wt += LO;
    c.WTgu[l] = wt;
    k_wt<<<dim3(2 * INNER_ / 32, H_ / 32), dim3(32, 8), 0, stream>>>(guw + l * LGU, wt, H_, 2 * INNER_);
    wt += LGU;
    c.WTd[l] = wt;
    k_wt<<<dim3(H_ / 32, INNER_ / 32), dim3(32, 8), 0, stream>>>(dw + l * LD, wt, INNER_, H_);
    wt += LD;
  }
  // stored-orientation bf16 weights (backward)
  {
    unsigned short* ws = wt;
    k_cast8<<<(int)((2 * LQKV / 8 + 255) / 256), 256, 0, stream>>>(qkvw, ws, (int)(2 * LQKV / 8));
    c.WSqkv[0] = ws; c.WSqkv[1] = ws + LQKV; ws += 2 * LQKV;
    k_cast8<<<(int)((2 * LO / 8 + 255) / 256), 256, 0, stream>>>(ow, ws, (int)(2 * LO / 8));
    c.WSo[0] = ws; c.WSo[1] = ws + LO; ws += 2 * LO;
    k_cast8<<<(int)((2 * LGU / 8 + 255) / 256), 256, 0, stream>>>(guw, ws, (int)(2 * LGU / 8));
    c.WSgu[0] = ws; c.WSgu[1] = ws + LGU; ws += 2 * LGU;
    k_cast8<<<(int)((2 * LD / 8 + 255) / 256), 256, 0, stream>>>(dw, ws, (int)(2 * LD / 8));
    c.WSd[0] = ws; c.WSd[1] = ws + LD;
  }

  k_zero<<<(NTOK * V_ + 255) / 256, 256, 0, stream>>>(logits, NTOK * V_);
  k_rope_tables<<<(S_ * 32 + 255) / 256, 256, 0, stream>>>(c.CS, c.SN);

  for (int step = 0; step < STEPS_; ++step) {
    k_softmax_logits<<<(NTOK + 255) / 256, 256, 0, stream>>>(logits, c.P);
    k_h0<<<NTOK, 256, 0, stream>>>(c.P, E, inputs, c.X1, c.X116);
    block_forward(c, 0, c.X1, c.X116, c.UDX, c.Q016, c.AO016, c.MB0, c.LB0, false);
    k_gfill<<<(NTOK * H_ + 255) / 256, 256, 0, stream>>>(ew, c.G);
    block_backward(c, 1, c.UDX, c.UDX16, c.Q16, c.AO16, c.MB, c.LB, false);
    k_h0<<<NTOK, 256, 0, stream>>>(c.P, E, inputs, c.X1, c.X116);
    block_backward(c, 0, c.X1, c.X116, c.Q016, c.AO016, c.MB0, c.LB0, true);
    k_logits_update<<<NTOK, 64, 0, stream>>>(c.G, E, c.P, alpha, logits);
  }
}

// Round 11
// 2429.704 us; speedup vs baseline: 36.0872x; 1.0847x over previous
//
#include <hip/hip_runtime.h>
#include <math.h>

#define B_ 8
#define S_ 900
#define V_ 11
#define H_ 512
#define NH_ 8
#define HD_ 64
#define INNER_ 1536
#define STEPS_ 2
#define NTOK (B_*S_)
#define EPS_ 1e-5f
#define THETA_ 10000.0f
#define ESCALE_ 22.627416997969522f
#define SCALE_ 0.125f
#define PT_ 68   // attention LDS pitch (ushorts)

typedef __attribute__((ext_vector_type(8))) short bh8;
typedef __attribute__((ext_vector_type(4))) float f32x4;
typedef __attribute__((ext_vector_type(4))) unsigned short us4;

union bfu { bh8 v; unsigned short s[8]; us4 q[2]; };

__device__ inline unsigned short f2bf(float x) {
  unsigned u = __builtin_bit_cast(unsigned, x);
  return (unsigned short)((u + 0x7FFFu + ((u >> 16) & 1u)) >> 16);
}
__device__ inline float b2f(unsigned short s) {
  return __builtin_bit_cast(float, (unsigned)s << 16);
}

// async global->LDS, 16B per lane; LDS dest = wave-uniform base + lane*16
__device__ inline void gld16(const unsigned short* g, unsigned short* l) {
  __builtin_amdgcn_global_load_lds(
      (const __attribute__((address_space(1))) void*)(g),
      (__attribute__((address_space(3))) void*)(l), 16, 0, 0);
}

__device__ inline bh8 lds16(const unsigned short* p) {
  bfu u;
  u.q[0] = *(const us4*)p;
  u.q[1] = *(const us4*)(p + 4);
  return u.v;
}
__device__ inline void sts16(unsigned short* p, bfu u) {
  *(us4*)p = u.q[0];
  *(us4*)(p + 4) = u.q[1];
}

__device__ inline float wave_sum64(float x) {
#pragma unroll
  for (int off = 32; off > 0; off >>= 1) x += __shfl_xor(x, off, 64);
  return x;
}

__device__ inline float quad_sum(float x) {
  x += __shfl_xor(x, 1, 64);
  x += __shfl_xor(x, 2, 64);
  return x;
}

// ---------------- small kernels ----------------

__global__ void k_zero(float* p, int n) {
  int i = blockIdx.x * blockDim.x + threadIdx.x;
  if (i < n) p[i] = 0.f;
}

__global__ void k_rope_tables(float* cs, float* sn) {
  int idx = blockIdx.x * blockDim.x + threadIdx.x;
  if (idx >= S_ * 32) return;
  int s = idx >> 5, i = idx & 31;
  float freq = powf(THETA_, -(float)i / 32.0f);
  float ang = (float)s * freq;
  cs[idx] = cosf(ang);
  sn[idx] = sinf(ang);
}

__global__ void k_softmax_logits(const float* __restrict__ logits, float* __restrict__ P) {
  int t = blockIdx.x * blockDim.x + threadIdx.x;
  if (t >= NTOK) return;
  float x[V_];
  float m = -1e30f;
#pragma unroll
  for (int v = 0; v < V_; ++v) { x[v] = logits[t * V_ + v]; m = fmaxf(m, x[v]); }
  float ssum = 0.f;
#pragma unroll
  for (int v = 0; v < V_; ++v) { x[v] = expf(x[v] - m); ssum += x[v]; }
  float inv = 1.f / ssum;
#pragma unroll
  for (int v = 0; v < V_; ++v) P[t * V_ + v] = x[v] * inv;
}

// h0 -> fp32 + bf16
__global__ void k_h0(const float* __restrict__ P, const float* __restrict__ E,
                     const int* __restrict__ inp, float* __restrict__ h0,
                     unsigned short* __restrict__ h016) {
  int t = blockIdx.x;
  int tid = threadIdx.x;
  __shared__ float p[V_];
  __shared__ int iw;
  if (tid < V_) p[tid] = P[t * V_ + tid];
  if (tid == 0) iw = inp[t];
  __syncthreads();
  for (int h = tid; h < H_; h += blockDim.x) {
    float acc = E[iw * H_ + h];
#pragma unroll
    for (int v = 0; v < V_; ++v) acc += p[v] * E[v * H_ + h];
    float val = ESCALE_ * acc;
    h0[(size_t)t * H_ + h] = val;
    h016[(size_t)t * H_ + h] = f2bf(val);
  }
}

__global__ void k_gfill(const float* __restrict__ ew, float* __restrict__ G) {
  int idx = blockIdx.x * blockDim.x + threadIdx.x;
  if (idx < NTOK * H_) G[idx] = ew[idx & (H_ - 1)];
}

// fp32 -> bf16 cast, 8 elems/thread
__global__ void k_cast8(const float* __restrict__ X, unsigned short* __restrict__ Y, int n8) {
  int i = blockIdx.x * blockDim.x + threadIdx.x;
  if (i >= n8) return;
  const float4* p = (const float4*)(X + (size_t)i * 8);
  float4 a = p[0], b = p[1];
  bfu o;
  o.s[0] = f2bf(a.x); o.s[1] = f2bf(a.y); o.s[2] = f2bf(a.z); o.s[3] = f2bf(a.w);
  o.s[4] = f2bf(b.x); o.s[5] = f2bf(b.y); o.s[6] = f2bf(b.z); o.s[7] = f2bf(b.w);
  *(bh8*)(Y + (size_t)i * 8) = o.v;
}

// ---------------- weight transpose-convert: W[K][N] fp32 -> WT[N][K] bf16 ----------------

__global__ void k_wt(const float* __restrict__ W, unsigned short* __restrict__ WT, int K, int N) {
  __shared__ float t[32][33];
  int k0 = blockIdx.y * 32, n0 = blockIdx.x * 32;
  int tx = threadIdx.x, ty = threadIdx.y;
#pragma unroll
  for (int i = 0; i < 4; ++i)
    t[ty + 8 * i][tx] = W[(size_t)(k0 + ty + 8 * i) * N + n0 + tx];
  __syncthreads();
#pragma unroll
  for (int i = 0; i < 4; ++i)
    WT[(size_t)(n0 + ty + 8 * i) * K + k0 + tx] = f2bf(t[tx][ty + 8 * i]);
}

// ---------------- MFMA GEMM: C[M,N] = A[M,K] @ B^T (A,B bf16; B stored [N][K]) ----------------
// Tile TM x 128 (TM = 64 or 128), BK=32, 4 waves (2x2), wave-tile (TM/2) x 64.
// Staging via global_load_lds into linear [rows][32] LDS. SILU_A stages manually.
// ROPE: fused forward rotary on output (slots 0..15 = Q,K; identity on V).
// SILUBWD: epilogue reads (gate,up) bf16 pair from GU, writes dGU in place.

template <int TM, int SILU_A, int ADD, int CBF, int ROPE, int SILUBWD>
__global__ __launch_bounds__(256) void k_gemm(const unsigned short* __restrict__ A16,
                                              const unsigned short* __restrict__ Bt,
                                              const float* __restrict__ Dm,
                                              float* __restrict__ Cf,
                                              unsigned short* __restrict__ C16,
                                              unsigned short* __restrict__ GU,
                                              const float* __restrict__ Cs,
                                              const float* __restrict__ Sn,
                                              int M, int N, int K, int lda) {
  __shared__ unsigned short As[TM][32];
  __shared__ unsigned short Bs[128][32];
  constexpr int FR = TM / 32;  // row-fragments per wave: 2 (TM=64) or 4 (TM=128)
  int tid = threadIdx.x;
  int m0 = blockIdx.y * TM, n0 = blockIdx.x * 128;
  int wid = tid >> 6, lane = tid & 63;
  int wr = (wid >> 1) * (FR * 16), wc = (wid & 1) * 64;
  int lr = lane & 15, lg = lane >> 4;
  int srow = lane >> 2, sck = (lane & 3) * 8;
  f32x4 acc[FR][4] = {};
  for (int k0 = 0; k0 < K; k0 += 32) {
    __syncthreads();
#pragma unroll
    for (int half = 0; half < TM / 64; ++half) {
      if (SILU_A) {
        int row = (tid >> 2) + 64 * half;
        int ck = (tid & 3) * 8;
        int gr = m0 + row; gr = gr < M ? gr : M - 1;
        const unsigned short* src = &A16[(size_t)gr * lda + k0 + ck];
        bfu pa;
#pragma unroll
        for (int j = 0; j < 8; ++j) {
          float g = b2f(src[j]), u = b2f(src[INNER_ + j]);
          pa.s[j] = f2bf((g / (1.f + __expf(-g))) * u);
        }
        *(bh8*)&As[row][ck] = pa.v;
      } else {
        int gr = m0 + 64 * half + wid * 16 + srow; gr = gr < M ? gr : M - 1;
        gld16(&A16[(size_t)gr * lda + k0 + sck], &As[64 * half + wid * 16][0]);
      }
    }
#pragma unroll
    for (int i = 0; i < 2; ++i) {
      int bb = wid * 2 + i;
      gld16(&Bt[(size_t)(n0 + bb * 16 + srow) * K + k0 + sck], &Bs[bb * 16][0]);
    }
    __syncthreads();
    bh8 av[FR], bv[4];
#pragma unroll
    for (int fr = 0; fr < FR; ++fr) av[fr] = *(const bh8*)&As[wr + fr * 16 + lr][lg * 8];
#pragma unroll
    for (int fc = 0; fc < 4; ++fc) bv[fc] = *(const bh8*)&Bs[wc + fc * 16 + lr][lg * 8];
#pragma unroll
    for (int fr = 0; fr < FR; ++fr)
#pragma unroll
      for (int fc = 0; fc < 4; ++fc)
        acc[fr][fc] = __builtin_amdgcn_mfma_f32_16x16x32_bf16(av[fr], bv[fc], acc[fr][fc], 0, 0, 0);
  }
  bool rope_on = ROPE && (((n0 + wc) >> 6) < 16);   // wave-uniform: slots 0..15 are Q,K
#pragma unroll
  for (int fr = 0; fr < FR; ++fr) {
    int r0 = m0 + wr + fr * 16 + lg * 4;
#pragma unroll
    for (int i = 0; i < 4; ++i) {
      int gr = r0 + i;
      if (gr >= M) continue;
      float c0 = 1.f, s0 = 0.f, c1 = 1.f, s1 = 0.f;
      if (ROPE) {
        if (rope_on) {
          int s = gr % S_;
          c0 = Cs[s * 32 + lr];      s0 = Sn[s * 32 + lr];
          c1 = Cs[s * 32 + 16 + lr]; s1 = Sn[s * 32 + 16 + lr];
        }
      }
#pragma unroll
      for (int fc = 0; fc < 4; ++fc) {
        int gc = n0 + wc + fc * 16 + lr;
        float out = acc[fr][fc][i];
        if (ROPE) {
          float part = acc[fr][fc ^ 2][i];
          float cc = (fc & 1) ? c1 : c0;
          float ss = (fc & 1) ? s1 : s0;
          out = (fc < 2) ? (out * cc - part * ss) : (out * cc + part * ss);
        }
        if (ADD) out += Dm[(size_t)gr * N + gc];
        if (SILUBWD) {
          size_t gb = (size_t)gr * (size_t)(2 * INNER_) + gc;
          float g = b2f(GU[gb]), u = b2f(GU[gb + INNER_]);
          float sig = 1.f / (1.f + __expf(-g));
          GU[gb] = f2bf(out * u * sig * (1.f + g * (1.f - sig)));
          GU[gb + INNER_] = f2bf(out * g * sig);
        } else if (CBF) {
          C16[(size_t)gr * N + gc] = f2bf(out);
        } else {
          Cf[(size_t)gr * N + gc] = out;
        }
      }
    }
  }
}

// ---------------- MFMA flash attention (bf16 QKV, bf16 O) ----------------
// QKV16 layout [t][24][64] ushorts: Q at slot h (roped), K at 8+h (roped), V at 16+h.

__global__ __launch_bounds__(256) void k_attn_fwd3(const unsigned short* __restrict__ QKV,
                                                   unsigned short* __restrict__ AO,
                                                   float* __restrict__ MB,
                                                   float* __restrict__ LB) {
  __shared__ unsigned short Ks[64][PT_];
  __shared__ unsigned short VT[64][PT_];
  __shared__ unsigned short Ps[4][16][PT_];
  int tid = threadIdx.x;
  int h = blockIdx.y, b = blockIdx.z;
  int w = tid >> 6, lane = tid & 63;
  int lr = lane & 15, lg = lane >> 4;
  int q0 = blockIdx.x * 64 + w * 16;

  bh8 qf[2];
  {
    int qr = q0 + lr; if (qr >= S_) qr = S_ - 1;
    const unsigned short* qp = &QKV[((size_t)(b * S_ + qr) * 24 + h) * 64 + lg * 8];
    qf[0] = *(const bh8*)qp;
    qf[1] = *(const bh8*)(qp + 32);
  }
  f32x4 accO[4] = {};
  float m[4], lsum[4];
#pragma unroll
  for (int i = 0; i < 4; ++i) { m[i] = -1e30f; lsum[i] = 0.f; }

  for (int kt = 0; kt < S_; kt += 64) {
    __syncthreads();
    {
      int r = tid >> 2, c0 = (tid & 3) * 16;
      int src = kt + r;
      size_t ts = (size_t)b * S_ + (src < S_ ? src : S_ - 1);
      const unsigned short* gp = &QKV[(ts * 24 + 8 + h) * 64 + c0];
      bfu p0, p1;
      p0.v = *(const bh8*)gp;
      p1.v = *(const bh8*)(gp + 8);
      sts16(&Ks[r][c0], p0);
      sts16(&Ks[r][c0 + 8], p1);
    }
    {
      int d0 = (tid & 15) * 4, k0r = (tid >> 4) * 4;
      us4 rv[4];
#pragma unroll
      for (int j = 0; j < 4; ++j) {
        int src = kt + k0r + j;
        size_t ts = (size_t)b * S_ + (src < S_ ? src : S_ - 1);
        rv[j] = *(const us4*)&QKV[(ts * 24 + 16 + h) * 64 + d0];
      }
#pragma unroll
      for (int dd = 0; dd < 4; ++dd) {
        us4 pk = {rv[0][dd], rv[1][dd], rv[2][dd], rv[3][dd]};
        *(us4*)&VT[d0 + dd][k0r] = pk;
      }
    }
    __syncthreads();
    f32x4 accS[4] = {};
#pragma unroll
    for (int ks = 0; ks < 2; ++ks)
#pragma unroll
      for (int fk = 0; fk < 4; ++fk)
        accS[fk] = __builtin_amdgcn_mfma_f32_16x16x32_bf16(qf[ks], lds16(&Ks[fk * 16 + lr][ks * 32 + lg * 8]), accS[fk], 0, 0, 0);
    float sc[4][4], pmax[4];
#pragma unroll
    for (int i = 0; i < 4; ++i) pmax[i] = -1e30f;
#pragma unroll
    for (int fk = 0; fk < 4; ++fk)
#pragma unroll
      for (int i = 0; i < 4; ++i) {
        float s = accS[fk][i] * SCALE_;
        if (kt + fk * 16 + lr >= S_) s = -1e30f;
        sc[fk][i] = s;
        pmax[i] = fmaxf(pmax[i], s);
      }
#pragma unroll
    for (int i = 0; i < 4; ++i) {
      float v = pmax[i];
      v = fmaxf(v, __shfl_xor(v, 1, 64));
      v = fmaxf(v, __shfl_xor(v, 2, 64));
      v = fmaxf(v, __shfl_xor(v, 4, 64));
      v = fmaxf(v, __shfl_xor(v, 8, 64));
      pmax[i] = v;
    }
    float psum[4];
#pragma unroll
    for (int i = 0; i < 4; ++i) {
      float mn = fmaxf(m[i], pmax[i]);
      float eo = __expf(m[i] - mn);
      m[i] = mn;
      lsum[i] *= eo;
#pragma unroll
      for (int fd = 0; fd < 4; ++fd) accO[fd][i] *= eo;
      psum[i] = 0.f;
    }
#pragma unroll
    for (int fk = 0; fk < 4; ++fk)
#pragma unroll
      for (int i = 0; i < 4; ++i) {
        float p = __expf(sc[fk][i] - m[i]);
        sc[fk][i] = p;
        psum[i] += p;
      }
#pragma unroll
    for (int i = 0; i < 4; ++i) {
      float v = psum[i];
      v += __shfl_xor(v, 1, 64);
      v += __shfl_xor(v, 2, 64);
      v += __shfl_xor(v, 4, 64);
      v += __shfl_xor(v, 8, 64);
      lsum[i] += v;
    }
#pragma unroll
    for (int fk = 0; fk < 4; ++fk)
#pragma unroll
      for (int i = 0; i < 4; ++i)
        Ps[w][lg * 4 + i][fk * 16 + lr] = f2bf(sc[fk][i]);
#pragma unroll
    for (int ks = 0; ks < 2; ++ks) {
      bh8 ap = lds16(&Ps[w][lr][ks * 32 + lg * 8]);
#pragma unroll
      for (int fd = 0; fd < 4; ++fd)
        accO[fd] = __builtin_amdgcn_mfma_f32_16x16x32_bf16(ap, lds16(&VT[fd * 16 + lr][ks * 32 + lg * 8]), accO[fd], 0, 0, 0);
    }
  }
#pragma unroll
  for (int i = 0; i < 4; ++i) {
    int q = q0 + lg * 4 + i;
    if (q < S_) {
      float linv = 1.f / lsum[i];
      size_t obase = (size_t)(b * S_ + q) * H_ + h * 64;
#pragma unroll
      for (int fd = 0; fd < 4; ++fd) AO[obase + fd * 16 + lr] = f2bf(accO[fd][i] * linv);
      if (lr == 0) {
        MB[((size_t)b * NH_ + h) * S_ + q] = m[i];
        LB[((size_t)b * NH_ + h) * S_ + q] = linv;
      }
    }
  }
}

// delta[b,h,q] = dot(dO_row, O_row), both bf16
__global__ __launch_bounds__(256) void k_delta(const unsigned short* __restrict__ O,
                                               const unsigned short* __restrict__ dO,
                                               float* __restrict__ DB) {
  int tid = threadIdx.x;
  int h = blockIdx.y, b = blockIdx.z;
  int r = blockIdx.x * 64 + (tid >> 2), part = tid & 3;
  if (r >= S_) return;
  size_t base = (size_t)(b * S_ + r) * H_ + h * 64 + part * 16;
  bfu o0, o1, d0, d1;
  o0.v = *(const bh8*)&O[base];  o1.v = *(const bh8*)&O[base + 8];
  d0.v = *(const bh8*)&dO[base]; d1.v = *(const bh8*)&dO[base + 8];
  float s = 0.f;
#pragma unroll
  for (int j = 0; j < 8; ++j)
    s += b2f(o0.s[j]) * b2f(d0.s[j]) + b2f(o1.s[j]) * b2f(d1.s[j]);
  s = quad_sum(s);
  if (part == 0) DB[((size_t)b * NH_ + h) * S_ + r] = s;
}

// dQ pass; fused inverse-RoPE on output
__global__ __launch_bounds__(256) void k_attn_bwd_dq3(const unsigned short* __restrict__ QKV,
                                                      const unsigned short* __restrict__ dO,
                                                      const float* __restrict__ MB,
                                                      const float* __restrict__ LB,
                                                      const float* __restrict__ DB,
                                                      const float* __restrict__ Cs,
                                                      const float* __restrict__ Sn,
                                                      unsigned short* __restrict__ dQKV) {
  __shared__ unsigned short Ks[64][PT_];
  __shared__ unsigned short Vs[64][PT_];
  __shared__ unsigned short KT[64][PT_];
  __shared__ unsigned short Ps[4][16][PT_];
  int tid = threadIdx.x;
  int h = blockIdx.y, b = blockIdx.z;
  int w = tid >> 6, lane = tid & 63;
  int lr = lane & 15, lg = lane >> 4;
  int q0 = blockIdx.x * 64 + w * 16;
  size_t sbase = ((size_t)b * NH_ + h) * S_;

  bh8 qf[2], dof[2];
  {
    int qr = q0 + lr; if (qr >= S_) qr = S_ - 1;
    const unsigned short* qp = &QKV[((size_t)(b * S_ + qr) * 24 + h) * 64 + lg * 8];
    const unsigned short* dp = &dO[(size_t)(b * S_ + qr) * H_ + h * 64 + lg * 8];
    qf[0] = *(const bh8*)qp;  qf[1] = *(const bh8*)(qp + 32);
    dof[0] = *(const bh8*)dp; dof[1] = *(const bh8*)(dp + 32);
  }
  float mrow[4], lrow[4], drow[4];
#pragma unroll
  for (int i = 0; i < 4; ++i) {
    int q = q0 + lg * 4 + i; if (q >= S_) q = S_ - 1;
    mrow[i] = MB[sbase + q];
    lrow[i] = LB[sbase + q];
    drow[i] = DB[sbase + q];
  }
  f32x4 accQ[4] = {};

  for (int kt = 0; kt < S_; kt += 64) {
    __syncthreads();
    {
      int r = tid >> 2, c0 = (tid & 3) * 16;
      int src = kt + r;
      bool vld = src < S_;
      size_t ts = (size_t)b * S_ + (vld ? src : S_ - 1);
      const unsigned short* kp = &QKV[(ts * 24 + 8 + h) * 64 + c0];
      bfu p0{}, p1{}, p2{}, p3{};
      if (vld) {
        p0.v = *(const bh8*)kp;
        p1.v = *(const bh8*)(kp + 8);
        p2.v = *(const bh8*)(kp + 512);
        p3.v = *(const bh8*)(kp + 520);
      }
      sts16(&Ks[r][c0], p0); sts16(&Ks[r][c0 + 8], p1);
      sts16(&Vs[r][c0], p2); sts16(&Vs[r][c0 + 8], p3);
    }
    {
      int d0 = (tid & 15) * 4, k0r = (tid >> 4) * 4;
      us4 rv[4];
#pragma unroll
      for (int j = 0; j < 4; ++j) {
        int src = kt + k0r + j;
        bool vld = src < S_;
        size_t ts = (size_t)b * S_ + (vld ? src : S_ - 1);
        us4 t = *(const us4*)&QKV[(ts * 24 + 8 + h) * 64 + d0];
        if (!vld) t = us4{0, 0, 0, 0};
        rv[j] = t;
      }
#pragma unroll
      for (int dd = 0; dd < 4; ++dd) {
        us4 pk = {rv[0][dd], rv[1][dd], rv[2][dd], rv[3][dd]};
        *(us4*)&KT[d0 + dd][k0r] = pk;
      }
    }
    __syncthreads();
    f32x4 aS[4] = {}, aD[4] = {};
#pragma unroll
    for (int ks = 0; ks < 2; ++ks)
#pragma unroll
      for (int fk = 0; fk < 4; ++fk) {
        aS[fk] = __builtin_amdgcn_mfma_f32_16x16x32_bf16(qf[ks], lds16(&Ks[fk * 16 + lr][ks * 32 + lg * 8]), aS[fk], 0, 0, 0);
        aD[fk] = __builtin_amdgcn_mfma_f32_16x16x32_bf16(dof[ks], lds16(&Vs[fk * 16 + lr][ks * 32 + lg * 8]), aD[fk], 0, 0, 0);
      }
#pragma unroll
    for (int fk = 0; fk < 4; ++fk)
#pragma unroll
      for (int i = 0; i < 4; ++i) {
        float p = __expf(aS[fk][i] * SCALE_ - mrow[i]) * lrow[i];
        float ds = p * (aD[fk][i] - drow[i]);
        Ps[w][lg * 4 + i][fk * 16 + lr] = f2bf(ds);
      }
#pragma unroll
    for (int ks = 0; ks < 2; ++ks) {
      bh8 ap = lds16(&Ps[w][lr][ks * 32 + lg * 8]);
#pragma unroll
      for (int fd = 0; fd < 4; ++fd)
        accQ[fd] = __builtin_amdgcn_mfma_f32_16x16x32_bf16(ap, lds16(&KT[fd * 16 + lr][ks * 32 + lg * 8]), accQ[fd], 0, 0, 0);
    }
  }
#pragma unroll
  for (int i = 0; i < 4; ++i) {
    int q = q0 + lg * 4 + i;
    if (q < S_) {
      size_t obase = ((size_t)(b * S_ + q) * 24 + h) * 64;
      float c0 = Cs[q * 32 + lr], s0 = Sn[q * 32 + lr];
      float c1 = Cs[q * 32 + 16 + lr], s1 = Sn[q * 32 + 16 + lr];
#pragma unroll
      for (int fd = 0; fd < 4; ++fd) {
        float x = SCALE_ * accQ[fd][i];
        float p = SCALE_ * accQ[fd ^ 2][i];
        float cc = (fd & 1) ? c1 : c0;
        float ss = (fd & 1) ? s1 : s0;
        float out = (fd < 2) ? (x * cc + p * ss) : (x * cc - p * ss);  // inverse rotation
        dQKV[obase + fd * 16 + lr] = f2bf(out);
      }
    }
  }
}

// dK + dV pass; fused inverse-RoPE on dK, dV plain
__global__ __launch_bounds__(256) void k_attn_bwd_kv3(const unsigned short* __restrict__ QKV,
                                                      const unsigned short* __restrict__ dO,
                                                      const float* __restrict__ MB,
                                                      const float* __restrict__ LB,
                                                      const float* __restrict__ DB,
                                                      const float* __restrict__ Cs,
                                                      const float* __restrict__ Sn,
                                                      unsigned short* __restrict__ dQKV) {
  __shared__ unsigned short Qs[64][PT_];
  __shared__ unsigned short dOs[64][PT_];
  __shared__ unsigned short QT[64][PT_];
  __shared__ unsigned short dOT[64][PT_];
  __shared__ unsigned short Ps[4][16][PT_];
  __shared__ float sM[64], sL[64], sD[64];
  int tid = threadIdx.x;
  int h = blockIdx.y, b = blockIdx.z;
  int w = tid >> 6, lane = tid & 63;
  int lr = lane & 15, lg = lane >> 4;
  int k0w = blockIdx.x * 64 + w * 16;
  size_t sbase = ((size_t)b * NH_ + h) * S_;

  bh8 kf[2], vf[2];
  {
    int kr = k0w + lr; if (kr >= S_) kr = S_ - 1;
    const unsigned short* kp = &QKV[((size_t)(b * S_ + kr) * 24 + 8 + h) * 64 + lg * 8];
    kf[0] = *(const bh8*)kp;        kf[1] = *(const bh8*)(kp + 32);
    vf[0] = *(const bh8*)(kp + 512); vf[1] = *(const bh8*)(kp + 544);
  }
  f32x4 accK[4] = {}, accV[4] = {};

  for (int qt = 0; qt < S_; qt += 64) {
    __syncthreads();
    {
      int r = tid >> 2, c0 = (tid & 3) * 16;
      int src = qt + r;
      bool vld = src < S_;
      size_t ts = (size_t)b * S_ + (vld ? src : S_ - 1);
      const unsigned short* qp = &QKV[(ts * 24 + h) * 64 + c0];
      const unsigned short* dp = &dO[ts * H_ + h * 64 + c0];
      bfu p0, p1, p2{}, p3{};
      p0.v = *(const bh8*)qp;
      p1.v = *(const bh8*)(qp + 8);
      if (vld) {
        p2.v = *(const bh8*)dp;
        p3.v = *(const bh8*)(dp + 8);
      }
      sts16(&Qs[r][c0], p0);  sts16(&Qs[r][c0 + 8], p1);
      sts16(&dOs[r][c0], p2); sts16(&dOs[r][c0 + 8], p3);
    }
    {
      int d0 = (tid & 15) * 4, q0r = (tid >> 4) * 4;
      us4 rq[4], rd[4];
#pragma unroll
      for (int j = 0; j < 4; ++j) {
        int src = qt + q0r + j;
        bool vld = src < S_;
        size_t ts = (size_t)b * S_ + (vld ? src : S_ - 1);
        rq[j] = *(const us4*)&QKV[(ts * 24 + h) * 64 + d0];
        us4 td = *(const us4*)&dO[ts * H_ + h * 64 + d0];
        if (!vld) td = us4{0, 0, 0, 0};
        rd[j] = td;
      }
#pragma unroll
      for (int dd = 0; dd < 4; ++dd) {
        us4 pq = {rq[0][dd], rq[1][dd], rq[2][dd], rq[3][dd]};
        us4 pd = {rd[0][dd], rd[1][dd], rd[2][dd], rd[3][dd]};
        *(us4*)&QT[d0 + dd][q0r] = pq;
        *(us4*)&dOT[d0 + dd][q0r] = pd;
      }
    }
    if (tid < 64) {
      int src = qt + tid;
      bool vld = src < S_;
      int sc = vld ? src : S_ - 1;
      sM[tid] = MB[sbase + sc];
      sL[tid] = LB[sbase + sc];
      sD[tid] = vld ? DB[sbase + sc] : 0.f;
    }
    __syncthreads();
    f32x4 aS[4] = {}, aD[4] = {};
#pragma unroll
    for (int ks = 0; ks < 2; ++ks)
#pragma unroll
      for (int fq = 0; fq < 4; ++fq) {
        aS[fq] = __builtin_amdgcn_mfma_f32_16x16x32_bf16(kf[ks], lds16(&Qs[fq * 16 + lr][ks * 32 + lg * 8]), aS[fq], 0, 0, 0);
        aD[fq] = __builtin_amdgcn_mfma_f32_16x16x32_bf16(vf[ks], lds16(&dOs[fq * 16 + lr][ks * 32 + lg * 8]), aD[fq], 0, 0, 0);
      }
    float pv[4][4];
#pragma unroll
    for (int fq = 0; fq < 4; ++fq) {
      float mq = sM[fq * 16 + lr], lq = sL[fq * 16 + lr];
#pragma unroll
      for (int i = 0; i < 4; ++i) {
        float p = __expf(aS[fq][i] * SCALE_ - mq) * lq;
        pv[fq][i] = p;
        Ps[w][lg * 4 + i][fq * 16 + lr] = f2bf(p);
      }
    }
#pragma unroll
    for (int qs = 0; qs < 2; ++qs) {
      bh8 ap = lds16(&Ps[w][lr][qs * 32 + lg * 8]);
#pragma unroll
      for (int fd = 0; fd < 4; ++fd)
        accV[fd] = __builtin_amdgcn_mfma_f32_16x16x32_bf16(ap, lds16(&dOT[fd * 16 + lr][qs * 32 + lg * 8]), accV[fd], 0, 0, 0);
    }
#pragma unroll
    for (int fq = 0; fq < 4; ++fq) {
      float dq = sD[fq * 16 + lr];
#pragma unroll
      for (int i = 0; i < 4; ++i)
        Ps[w][lg * 4 + i][fq * 16 + lr] = f2bf(pv[fq][i] * (aD[fq][i] - dq));
    }
#pragma unroll
    for (int qs = 0; qs < 2; ++qs) {
      bh8 ap = lds16(&Ps[w][lr][qs * 32 + lg * 8]);
#pragma unroll
      for (int fd = 0; fd < 4; ++fd)
        accK[fd] = __builtin_amdgcn_mfma_f32_16x16x32_bf16(ap, lds16(&QT[fd * 16 + lr][qs * 32 + lg * 8]), accK[fd], 0, 0, 0);
    }
  }
#pragma unroll
  for (int i = 0; i < 4; ++i) {
    int k = k0w + lg * 4 + i;
    if (k < S_) {
      size_t obase = ((size_t)(b * S_ + k) * 24 + 8 + h) * 64;
      float c0 = Cs[k * 32 + lr], s0 = Sn[k * 32 + lr];
      float c1 = Cs[k * 32 + 16 + lr], s1 = Sn[k * 32 + 16 + lr];
#pragma unroll
      for (int fd = 0; fd < 4; ++fd) {
        float x = SCALE_ * accK[fd][i];
        float p = SCALE_ * accK[fd ^ 2][i];
        float cc = (fd & 1) ? c1 : c0;
        float ss = (fd & 1) ? s1 : s0;
        float out = (fd < 2) ? (x * cc + p * ss) : (x * cc - p * ss);  // inverse rotation
        dQKV[obase + fd * 16 + lr] = f2bf(out);
        dQKV[obase + 512 + fd * 16 + lr] = f2bf(accV[fd][i]);
      }
    }
  }
}

// ---------------- RMS norm fwd/bwd (dual fp32+bf16 outputs) ----------------

__global__ __launch_bounds__(256) void k_rms_fwd(const float* __restrict__ X, float* __restrict__ Y,
                                                 unsigned short* __restrict__ Y16) {
  int t = blockIdx.x, tid = threadIdx.x;
  float x0 = X[(size_t)t * H_ + tid], x1 = X[(size_t)t * H_ + tid + 256];
  __shared__ float red[256];
  red[tid] = x0 * x0 + x1 * x1;
  __syncthreads();
  for (int s = 128; s > 0; s >>= 1) {
    if (tid < s) red[tid] += red[tid + s];
    __syncthreads();
  }
  float r = rsqrtf(red[0] / H_ + EPS_);
  float y0 = x0 * r, y1 = x1 * r;
  Y[(size_t)t * H_ + tid] = y0;
  Y[(size_t)t * H_ + tid + 256] = y1;
  Y16[(size_t)t * H_ + tid] = f2bf(y0);
  Y16[(size_t)t * H_ + tid + 256] = f2bf(y1);
}

__global__ __launch_bounds__(256) void k_rms_bwd(const float* __restrict__ X,
                                                 const float* __restrict__ GY,
                                                 float* __restrict__ GX,
                                                 unsigned short* __restrict__ GX16) {
  int t = blockIdx.x, tid = threadIdx.x;
  float x0 = X[(size_t)t * H_ + tid], x1 = X[(size_t)t * H_ + tid + 256];
  float g0 = GY[(size_t)t * H_ + tid], g1 = GY[(size_t)t * H_ + tid + 256];
  __shared__ float r1[256], r2[256];
  r1[tid] = x0 * x0 + x1 * x1;
  r2[tid] = x0 * g0 + x1 * g1;
  __syncthreads();
  for (int s = 128; s > 0; s >>= 1) {
    if (tid < s) { r1[tid] += r1[tid + s]; r2[tid] += r2[tid + s]; }
    __syncthreads();
  }
  float r = rsqrtf(r1[0] / H_ + EPS_);
  float coef = r * r * r * r2[0] / (float)H_;
  float o0 = r * g0 - coef * x0, o1 = r * g1 - coef * x1;
  GX[(size_t)t * H_ + tid] = o0;
  GX[(size_t)t * H_ + tid + 256] = o1;
  GX16[(size_t)t * H_ + tid] = f2bf(o0);
  GX16[(size_t)t * H_ + tid + 256] = f2bf(o1);
}

// ---------------- logits update ----------------

__global__ __launch_bounds__(64) void k_logits_update(const float* __restrict__ G,
                                                      const float* __restrict__ E,
                                                      const float* __restrict__ P,
                                                      const float* __restrict__ alpha,
                                                      float* __restrict__ logits) {
  int t = blockIdx.x, lane = threadIdx.x;
  float dp[V_];
#pragma unroll
  for (int v = 0; v < V_; ++v) dp[v] = 0.f;
  for (int hh = lane; hh < H_; hh += 64) {
    float gh = G[(size_t)t * H_ + hh];
#pragma unroll
    for (int v = 0; v < V_; ++v) dp[v] += gh * E[v * H_ + hh];
  }
#pragma unroll
  for (int v = 0; v < V_; ++v) dp[v] = wave_sum64(dp[v]) * ESCALE_;
  float dot = 0.f;
  float pv[V_];
#pragma unroll
  for (int v = 0; v < V_; ++v) {
    pv[v] = P[t * V_ + v];
    dot += pv[v] * dp[v];
  }
  float a = fmaxf(alpha[0], 1e-4f);
  if (lane < V_) logits[t * V_ + lane] -= a * pv[lane] * (dp[lane] - dot);
}

// ---------------- host-side orchestration ----------------
// TM=128 GEMM tile for N>=1536 (qkv, gu, dact); TM=64 otherwise.
// L0 checkpoint: Q016/AO016/MB0/LB0 (attn) + X20 (fp32 pre-rms-2 residual) + U016 (bf16 u).
// L0 backward does a LITE recompute: k_h0 -> X1, o-GEMM (X1 += AO016*Wo), gu-GEMM from U016;
// skips rms_fwd + down-GEMM entirely (X20 checkpointed).

struct Ctx {
  unsigned short *Q16, *Q016, *dQ16, *GU16, *DO16, *AO16, *AO016, *X116, *UDX16, *U016;
  float *X1, *X2, *X20, *G, *UDX, *P, *MB, *LB, *DB, *MB0, *LB0, *CS, *SN;
  const unsigned short *WTqkv[2], *WTo[2], *WTgu[2], *WTd[2];
  const unsigned short *WSqkv[2], *WSo[2], *WSgu[2], *WSd[2];
  hipStream_t st;
};

static void block_forward(Ctx& c, int l, const float* hin, const unsigned short* hin16,
                          float* hout, unsigned short* qb, unsigned short* ao,
                          float* mb, float* lb, float* x2buf, unsigned short* u16buf) {
  // qkv GEMM (TM=128, fused RoPE, bf16 out)
  k_gemm<128, 0, 0, 1, 1, 0><<<dim3(3 * H_ / 128, (NTOK + 127) / 128), 256, 0, c.st>>>(
      hin16, c.WTqkv[l], nullptr, nullptr, qb, nullptr, c.CS, c.SN, NTOK, 3 * H_, H_, H_);
  k_attn_fwd3<<<dim3((S_ + 63) / 64, NH_, B_), 256, 0, c.st>>>(qb, ao, mb, lb);
  k_gemm<64, 0, 1, 0, 0, 0><<<dim3(H_ / 128, (NTOK + 63) / 64), 256, 0, c.st>>>(
      ao, c.WTo[l], hin, c.X1, nullptr, nullptr, nullptr, nullptr, NTOK, H_, H_, H_);
  k_rms_fwd<<<NTOK, 256, 0, c.st>>>(c.X1, c.UDX, u16buf);
  k_gemm<128, 0, 0, 1, 0, 0><<<dim3(2 * INNER_ / 128, (NTOK + 127) / 128), 256, 0, c.st>>>(
      u16buf, c.WTgu[l], nullptr, nullptr, c.GU16, nullptr, nullptr, nullptr, NTOK, 2 * INNER_, H_, H_);
  k_gemm<64, 1, 1, 0, 0, 0><<<dim3(H_ / 128, (NTOK + 63) / 64), 256, 0, c.st>>>(
      c.GU16, c.WTd[l], c.UDX, x2buf, nullptr, nullptr, nullptr, nullptr, NTOK, H_, INNER_, 2 * INNER_);
  if (hout) k_rms_fwd<<<NTOK, 256, 0, c.st>>>(x2buf, hout, c.UDX16);
}

static void block_backward(Ctx& c, int l, const float* hin, const unsigned short* hin16,
                           unsigned short* qb, unsigned short* ao, float* mb, float* lb,
                           bool full) {
  const float* x2src;
  if (full) {
    block_forward(c, l, hin, hin16, nullptr, qb, ao, mb, lb, c.X2, c.UDX16);
    x2src = c.X2;
  } else {
    // LITE recompute (L0): X1 = h0 + AO016*Wo ; GU16 = U016*Wgu. Skip rms_fwd + down.
    k_gemm<64, 0, 1, 0, 0, 0><<<dim3(H_ / 128, (NTOK + 63) / 64), 256, 0, c.st>>>(
        ao, c.WTo[l], hin, c.X1, nullptr, nullptr, nullptr, nullptr, NTOK, H_, H_, H_);
    k_gemm<128, 0, 0, 1, 0, 0><<<dim3(2 * INNER_ / 128, (NTOK + 127) / 128), 256, 0, c.st>>>(
        c.U016, c.WTgu[l], nullptr, nullptr, c.GU16, nullptr, nullptr, nullptr, NTOK, 2 * INNER_, H_, H_);
    x2src = c.X20;
  }
  k_rms_bwd<<<NTOK, 256, 0, c.st>>>(x2src, c.G, c.UDX, c.UDX16);
  // dact GEMM (TM=128) with fused SiLU-bwd
  k_gemm<128, 0, 0, 0, 0, 1><<<dim3(INNER_ / 128, (NTOK + 127) / 128), 256, 0, c.st>>>(
      c.UDX16, c.WSd[l], nullptr, nullptr, nullptr, c.GU16, nullptr, nullptr, NTOK, INNER_, H_, H_);
  k_gemm<64, 0, 1, 0, 0, 0><<<dim3(H_ / 128, (NTOK + 63) / 64), 256, 0, c.st>>>(
      c.GU16, c.WSgu[l], c.UDX, c.G, nullptr, nullptr, nullptr, nullptr, NTOK, H_, 2 * INNER_, 2 * INNER_);
  k_rms_bwd<<<NTOK, 256, 0, c.st>>>(c.X1, c.G, c.UDX, c.UDX16);
  k_gemm<64, 0, 0, 1, 0, 0><<<dim3(H_ / 128, (NTOK + 63) / 64), 256, 0, c.st>>>(
      c.UDX16, c.WSo[l], nullptr, nullptr, c.DO16, nullptr, nullptr, nullptr, NTOK, H_, H_, H_);
  dim3 agrid((S_ + 63) / 64, NH_, B_);
  k_delta<<<agrid, 256, 0, c.st>>>(ao, c.DO16, c.DB);
  k_attn_bwd_dq3<<<agrid, 256, 0, c.st>>>(qb, c.DO16, mb, lb, c.DB, c.CS, c.SN, c.dQ16);
  k_attn_bwd_kv3<<<agrid, 256, 0, c.st>>>(qb, c.DO16, mb, lb, c.DB, c.CS, c.SN, c.dQ16);
  k_gemm<64, 0, 1, 0, 0, 0><<<dim3(H_ / 128, (NTOK + 63) / 64), 256, 0, c.st>>>(
      c.dQ16, c.WSqkv[l], c.UDX, c.G, nullptr, nullptr, nullptr, nullptr, NTOK, H_, 3 * H_, 3 * H_);
}

extern "C" void kernel_launch(void* const* d_in, const int* in_sizes, int n_in,
                              void* d_out, int out_size, void* d_ws, size_t ws_size,
                              hipStream_t stream) {
  const int* inputs = (const int*)d_in[0];
  const float* E = (const float*)d_in[2];
  const float* ew = (const float*)d_in[3];
  const float* qkvw = (const float*)d_in[4];
  const float* ow = (const float*)d_in[5];
  const float* guw = (const float*)d_in[6];
  const float* dw = (const float*)d_in[7];
  const float* alpha = (const float*)d_in[8];
  float* logits = (float*)d_out;

  const size_t WT_FLOATS = 3407872;
  const size_t NEED =
      3 * ((size_t)NTOK * 3 * H_ / 2) +  // Q16, Q016, dQ16
      ((size_t)NTOK * INNER_) +          // GU16
      5 * ((size_t)NTOK * H_) +          // X1, X2, X20, G, UDX (fp32)
      6 * ((size_t)NTOK * H_ / 2) +      // AO16, AO016, DO16, X116, UDX16, U016
      ((size_t)NTOK * V_) +              // P
      5 * ((size_t)B_ * NH_ * S_) +      // stats
      2 * ((size_t)S_ * 32) +            // CS, SN
      2 * WT_FLOATS;                     // WT + WS
  if (ws_size < NEED * sizeof(float)) {
    k_zero<<<(NTOK * V_ + 255) / 256, 256, 0, stream>>>(logits, NTOK * V_);
    return;
  }

  float* f = (float*)d_ws;
  Ctx c;
  c.st = stream;
  c.Q16 = (unsigned short*)f;  f += (size_t)NTOK * 3 * H_ / 2;
  c.Q016 = (unsigned short*)f; f += (size_t)NTOK * 3 * H_ / 2;
  c.dQ16 = (unsigned short*)f; f += (size_t)NTOK * 3 * H_ / 2;
  c.GU16 = (unsigned short*)f; f += (size_t)NTOK * INNER_;
  c.X1 = f;   f += (size_t)NTOK * H_;
  c.X2 = f;   f += (size_t)NTOK * H_;
  c.X20 = f;  f += (size_t)NTOK * H_;
  c.G = f;    f += (size_t)NTOK * H_;
  c.UDX = f;  f += (size_t)NTOK * H_;
  c.AO16 = (unsigned short*)f;  f += (size_t)NTOK * H_ / 2;
  c.AO016 = (unsigned short*)f; f += (size_t)NTOK * H_ / 2;
  c.DO16 = (unsigned short*)f;  f += (size_t)NTOK * H_ / 2;
  c.X116 = (unsigned short*)f;  f += (size_t)NTOK * H_ / 2;
  c.UDX16 = (unsigned short*)f; f += (size_t)NTOK * H_ / 2;
  c.U016 = (unsigned short*)f;  f += (size_t)NTOK * H_ / 2;
  c.P = f;    f += (size_t)NTOK * V_;
  c.MB = f;   f += (size_t)B_ * NH_ * S_;
  c.LB = f;   f += (size_t)B_ * NH_ * S_;
  c.DB = f;   f += (size_t)B_ * NH_ * S_;
  c.MB0 = f;  f += (size_t)B_ * NH_ * S_;
  c.LB0 = f;  f += (size_t)B_ * NH_ * S_;
  c.CS = f;   f += (size_t)S_ * 32;
  c.SN = f;   f += (size_t)S_ * 32;
  unsigned short* wt = (unsigned short*)f;

  const size_t LQKV = (size_t)H_ * 3 * H_;
  const size_t LO = (size_t)H_ * H_;
  const size_t LGU = (size_t)H_ * 2 * INNER_;
  const size_t LD = (size_t)INNER_ * H_;

  // transposed bf16 weights (forward)
  for (int l = 0; l < 2; ++l) {
    c.WTqkv[l] = wt;
    k_wt<<<dim3(3 * H_ / 32, H_ / 32), dim3(32, 8), 0, stream>>>(qkvw + l * LQKV, wt, H_, 3 * H_);
    wt += LQKV;
    c.WTo[l] = wt;
    k_wt<<<dim3(H_ / 32, H_ / 32), dim3(32, 8), 0, stream>>>(ow + l * LO, wt, H_, H_);
    wt += LO;
    c.WTgu[l] = wt;
    k_wt<<<dim3(2 * INNER_ / 32, H_ / 32), dim3(32, 8), 0, stream>>>(guw + l * LGU, wt, H_, 2 * INNER_);
    wt += LGU;
    c.WTd[l] = wt;
    k_wt<<<dim3(H_ / 32, INNER_ / 32), dim3(32, 8), 0, stream>>>(dw + l * LD, wt, INNER_, H_);
    wt += LD;
  }
  // stored-orientation bf16 weights (backward)
  {
    unsigned short* ws = wt;
    k_cast8<<<(int)((2 * LQKV / 8 + 255) / 256), 256, 0, stream>>>(qkvw, ws, (int)(2 * LQKV / 8));
    c.WSqkv[0] = ws; c.WSqkv[1] = ws + LQKV; ws += 2 * LQKV;
    k_cast8<<<(int)((2 * LO / 8 + 255) / 256), 256, 0, stream>>>(ow, ws, (int)(2 * LO / 8));
    c.WSo[0] = ws; c.WSo[1] = ws + LO; ws += 2 * LO;
    k_cast8<<<(int)((2 * LGU / 8 + 255) / 256), 256, 0, stream>>>(guw, ws, (int)(2 * LGU / 8));
    c.WSgu[0] = ws; c.WSgu[1] = ws + LGU; ws += 2 * LGU;
    k_cast8<<<(int)((2 * LD / 8 + 255) / 256), 256, 0, stream>>>(dw, ws, (int)(2 * LD / 8));
    c.WSd[0] = ws; c.WSd[1] = ws + LD;
  }

  k_zero<<<(NTOK * V_ + 255) / 256, 256, 0, stream>>>(logits, NTOK * V_);
  k_rope_tables<<<(S_ * 32 + 255) / 256, 256, 0, stream>>>(c.CS, c.SN);

  for (int step = 0; step < STEPS_; ++step) {
    k_softmax_logits<<<(NTOK + 255) / 256, 256, 0, stream>>>(logits, c.P);
    k_h0<<<NTOK, 256, 0, stream>>>(c.P, E, inputs, c.X1, c.X116);
    // forward L0 with full checkpoint: attn state + X20 + U016; h1 -> UDX/UDX16
    block_forward(c, 0, c.X1, c.X116, c.UDX, c.Q016, c.AO016, c.MB0, c.LB0, c.X20, c.U016);
    k_gfill<<<(NTOK * H_ + 255) / 256, 256, 0, stream>>>(ew, c.G);
    // backward L1: full forward (first time for L1)
    block_backward(c, 1, c.UDX, c.UDX16, c.Q16, c.AO16, c.MB, c.LB, true);
    // backward L0: lite recompute from checkpoints
    k_h0<<<NTOK, 256, 0, stream>>>(c.P, E, inputs, c.X1, c.X116);
    block_backward(c, 0, c.X1, c.X116, c.Q016, c.AO016, c.MB0, c.LB0, false);
    k_logits_update<<<NTOK, 64, 0, stream>>>(c.G, E, c.P, alpha, logits);
  }
}